// Round 5
// baseline (674.521 us; speedup 1.0000x reference)
//
#include <hip/hip_runtime.h>
#include <hip/hip_bf16.h>
#include <math.h>

typedef __hip_bfloat16 bf16;
typedef __attribute__((ext_vector_type(8))) short short8;   // 8 bf16 (4 VGPRs)
typedef __attribute__((ext_vector_type(4))) float f32x4;
#define DEVINL __device__ __forceinline__

constexpr int Bc  = 2;
constexpr int Nc  = 768;
constexpr int Dc  = 512;
constexpr int Hc  = 8;
constexpr int DKc = 64;
constexpr int BHc = Bc * Hc;
constexpr float SCALE    = 0.125f;   // 1/sqrt(64)
constexpr float EPSF     = 1e-6f;
constexpr float BETA_NOT = 0.5f;

DEVINL float ldf(const float* p, long i) { return p[i]; }
DEVINL float ldf(const bf16* p, long i) { return __bfloat162float(p[i]); }
DEVINL void stf(float* p, long i, float v) { p[i] = v; }
DEVINL void stf(bf16* p, long i, float v) { p[i] = __float2bfloat16(v); }

DEVINL float sigf(float x) { return __fdividef(1.f, 1.f + __expf(-x)); }

// ---------------------------------------------------------------------------
// Dtype sniffer (round-1 notes). Deterministic per launch.
// ---------------------------------------------------------------------------
DEVINL int sniff_is_fp32(const void* xraw) {
    const unsigned short* p = (const unsigned short*)xraw;
    float mx = 0.f;
#pragma unroll 1
    for (int j = 0; j < 128; ++j) {
        float v = __uint_as_float(((unsigned)p[j]) << 16);
        mx = fmaxf(mx, fabsf(v));
    }
    return mx > 1000.f ? 1 : 0;
}

DEVINL float cvt_elem(const void* s, long j, int is32) {
    return is32 ? ((const float*)s)[j]
                : __bfloat162float(((const bf16*)s)[j]);
}

__global__ __launch_bounds__(256) void convert_all(
    const void* x, const void* w1, const void* w2, const void* pw,
    const void* c1w, const void* c1b, const void* c2w, const void* c2b,
    const void* ch,
    bf16* xb, bf16* w1b, bf16* w2b, float* pwf, float* smallf)
{
    const int is32 = sniff_is_fp32(x);
    const long i = (long)blockIdx.x * 256 + threadIdx.x;
    if (i < (long)Bc * Nc * Dc) {
        xb[i]  = __float2bfloat16(cvt_elem(x,  i, is32));
        w1b[i] = __float2bfloat16(cvt_elem(w1, i, is32));
        w2b[i] = __float2bfloat16(cvt_elem(w2, i, is32));
    }
    if (i < (long)Dc * Dc) pwf[i] = cvt_elem(pw, i, is32);
    if (i < 96)       smallf[i] = cvt_elem(c1w, i,        is32);
    else if (i < 112) smallf[i] = cvt_elem(c1b, i - 96,   is32);
    else if (i < 176) smallf[i] = cvt_elem(c2w, i - 112,  is32);
    else if (i < 180) smallf[i] = cvt_elem(c2b, i - 176,  is32);
    else if (i == 180) smallf[180] = cvt_elem(ch, 0, is32);
}

__global__ __launch_bounds__(256) void fill_sentinel(unsigned short* o) {
    const long i = (long)blockIdx.x * 256 + threadIdx.x;
    if (i < (long)Bc * Nc * Dc) o[i] = 0x40E0;  // bf16 7.0
}

// ---------------------------------------------------------------------------
// Generic bf16 transpose, 64x64 tiles: dst[c][r] = src[r][c]; src is (R,C).
// ---------------------------------------------------------------------------
__global__ __launch_bounds__(256) void transpose_bf16(
    const unsigned short* __restrict__ src, unsigned short* __restrict__ dst,
    int R, int C, long sS, long sD)
{
    __shared__ unsigned short tile[64][68];
    const unsigned short* s = src + (long)blockIdx.z * sS;
    unsigned short* d = dst + (long)blockIdx.z * sD;
    const int r0 = blockIdx.y * 64, c0 = blockIdx.x * 64;
    const int t = threadIdx.x;
    const int lr = t >> 4, lc4 = (t & 15) * 4;
#pragma unroll
    for (int i = 0; i < 4; ++i) {
        int r = lr + i * 16;
        *(uint2*)&tile[r][lc4] = *(const uint2*)&s[(long)(r0 + r) * C + c0 + lc4];
    }
    __syncthreads();
#pragma unroll
    for (int i = 0; i < 4; ++i) {
        int r = lr + i * 16;
        unsigned short v[4];
#pragma unroll
        for (int j = 0; j < 4; ++j) v[j] = tile[lc4 + j][r];
        *(uint2*)&d[(long)(c0 + r) * R + r0 + lc4] = *(uint2*)v;
    }
}

// ---------------------------------------------------------------------------
// MFMA bf16 NT GEMM (validated): C = A(M,K) @ B^T(stored (N,K)).
// 128x128 tile, BK=32, 4 waves 2x2, 4x4 16x16x32 tiles/wave.
// ---------------------------------------------------------------------------
template <int EPI, typename TC>
__global__ __launch_bounds__(256) void gemm_nt_mfma(
    const bf16* __restrict__ Ag, const bf16* __restrict__ Btg,
    TC* __restrict__ Cg, int M, int N, int K,
    long sA, long sB, long sC, float alpha)
{
    __shared__ unsigned short Asm[128 * 40];
    __shared__ unsigned short Bsm[128 * 40];

    const int tid  = threadIdx.x;
    const int wave = tid >> 6;
    const int lane = tid & 63;
    const int q    = lane >> 4;
    const int ln   = lane & 15;
    const int wm   = wave & 1;
    const int wn   = wave >> 1;

    const bf16* A  = Ag  + (long)blockIdx.z * sA + (long)(blockIdx.y * 128) * K;
    const bf16* Bt = Btg + (long)blockIdx.z * sB + (long)(blockIdx.x * 128) * K;
    TC*         C  = Cg  + (long)blockIdx.z * sC;

    const int r_s0 = tid >> 2, c_s = tid & 3;
    const int r_s1 = r_s0 + 64;
    const bf16* pa0 = A  + (long)r_s0 * K + c_s * 8;
    const bf16* pa1 = A  + (long)r_s1 * K + c_s * 8;
    const bf16* pb0 = Bt + (long)r_s0 * K + c_s * 8;
    const bf16* pb1 = Bt + (long)r_s1 * K + c_s * 8;
    const int w_s0 = r_s0 * 40 + c_s * 8;
    const int w_s1 = r_s1 * 40 + c_s * 8;

    f32x4 acc[4][4];
#pragma unroll
    for (int i = 0; i < 4; ++i)
#pragma unroll
        for (int j = 0; j < 4; ++j)
            acc[i][j] = (f32x4){0.f, 0.f, 0.f, 0.f};

    for (int k0 = 0; k0 < K; k0 += 32) {
        const uint4 va0 = *(const uint4*)(pa0 + k0);
        const uint4 va1 = *(const uint4*)(pa1 + k0);
        const uint4 vb0 = *(const uint4*)(pb0 + k0);
        const uint4 vb1 = *(const uint4*)(pb1 + k0);
        __syncthreads();
        *(uint4*)&Asm[w_s0] = va0;
        *(uint4*)&Asm[w_s1] = va1;
        *(uint4*)&Bsm[w_s0] = vb0;
        *(uint4*)&Bsm[w_s1] = vb1;
        __syncthreads();

        short8 af[4], bfr[4];
#pragma unroll
        for (int mt = 0; mt < 4; ++mt) {
            int m = wm * 64 + mt * 16 + ln;
            af[mt] = *(const short8*)&Asm[m * 40 + q * 8];
        }
#pragma unroll
        for (int nt = 0; nt < 4; ++nt) {
            int n = wn * 64 + nt * 16 + ln;
            bfr[nt] = *(const short8*)&Bsm[n * 40 + q * 8];
        }
#pragma unroll
        for (int mt = 0; mt < 4; ++mt)
#pragma unroll
            for (int nt = 0; nt < 4; ++nt)
                acc[mt][nt] = __builtin_amdgcn_mfma_f32_16x16x32_bf16(
                    af[mt], bfr[nt], acc[mt][nt], 0, 0, 0);
    }

#pragma unroll
    for (int mt = 0; mt < 4; ++mt) {
#pragma unroll
        for (int nt = 0; nt < 4; ++nt) {
            const int col = blockIdx.x * 128 + wn * 64 + nt * 16 + ln;
            const int rowb = blockIdx.y * 128 + wm * 64 + mt * 16 + q * 4;
#pragma unroll
            for (int r = 0; r < 4; ++r) {
                float v = acc[mt][nt][r] * alpha;
                if (EPI == 1) v = __logf(fmaxf(v, 0.f) + EPSF);
                stf(C, (long)(rowb + r) * N + col, v);
            }
        }
    }
}

// ---------------------------------------------------------------------------
// MFMA bf16 NT GEMM, narrow: C(M,64) = A(M,K) @ Bt(64,K)^T, batched.
// Tile 128x64, BK=64, 4 waves each own 32 m-rows. LDS row stride 72 shorts
// (144 B = 9*16 B aligned; 36-bank row stride -> 2-way only = free).
// ---------------------------------------------------------------------------
template <typename TC>
__global__ __launch_bounds__(256) void gemm_nt_n64(
    const bf16* __restrict__ Ag, const bf16* __restrict__ Btg,
    TC* __restrict__ Cg, int M, int K, long sA, long sB, long sC)
{
    __shared__ unsigned short Asm[128 * 72];
    __shared__ unsigned short Bsm[64 * 72];

    const int tid  = threadIdx.x;
    const int wave = tid >> 6;
    const int lane = tid & 63;
    const int q    = lane >> 4;
    const int ln   = lane & 15;

    const bf16* A  = Ag  + (long)blockIdx.z * sA + (long)(blockIdx.y * 128) * K;
    const bf16* Bt = Btg + (long)blockIdx.z * sB;
    TC*         C  = Cg  + (long)blockIdx.z * sC;

    // staging: rows of 64 k = 8 chunks of 8 shorts; thread -> (row, k8)
    const int sr = tid >> 3, k8 = tid & 7;    // sr 0..31
    const bf16* pa[4];
    const bf16* pb[2];
    int wa[4], wb[2];
#pragma unroll
    for (int i = 0; i < 4; ++i) {
        pa[i] = A + (long)(sr + i * 32) * K + k8 * 8;
        wa[i] = (sr + i * 32) * 72 + k8 * 8;
    }
#pragma unroll
    for (int i = 0; i < 2; ++i) {
        pb[i] = Bt + (long)(sr + i * 32) * K + k8 * 8;
        wb[i] = (sr + i * 32) * 72 + k8 * 8;
    }

    f32x4 acc[2][4];
#pragma unroll
    for (int i = 0; i < 2; ++i)
#pragma unroll
        for (int j = 0; j < 4; ++j)
            acc[i][j] = (f32x4){0.f, 0.f, 0.f, 0.f};

    for (int k0 = 0; k0 < K; k0 += 64) {
        uint4 va[4], vb[2];
#pragma unroll
        for (int i = 0; i < 4; ++i) va[i] = *(const uint4*)(pa[i] + k0);
#pragma unroll
        for (int i = 0; i < 2; ++i) vb[i] = *(const uint4*)(pb[i] + k0);
        __syncthreads();
#pragma unroll
        for (int i = 0; i < 4; ++i) *(uint4*)&Asm[wa[i]] = va[i];
#pragma unroll
        for (int i = 0; i < 2; ++i) *(uint4*)&Bsm[wb[i]] = vb[i];
        __syncthreads();

#pragma unroll
        for (int kc = 0; kc < 2; ++kc) {
            short8 af[2], bfr[4];
#pragma unroll
            for (int mt = 0; mt < 2; ++mt) {
                int m = wave * 32 + mt * 16 + ln;
                af[mt] = *(const short8*)&Asm[m * 72 + kc * 32 + q * 8];
            }
#pragma unroll
            for (int nt = 0; nt < 4; ++nt) {
                int n = nt * 16 + ln;
                bfr[nt] = *(const short8*)&Bsm[n * 72 + kc * 32 + q * 8];
            }
#pragma unroll
            for (int mt = 0; mt < 2; ++mt)
#pragma unroll
                for (int nt = 0; nt < 4; ++nt)
                    acc[mt][nt] = __builtin_amdgcn_mfma_f32_16x16x32_bf16(
                        af[mt], bfr[nt], acc[mt][nt], 0, 0, 0);
        }
    }

#pragma unroll
    for (int mt = 0; mt < 2; ++mt) {
#pragma unroll
        for (int nt = 0; nt < 4; ++nt) {
            const int col  = nt * 16 + ln;
            const int rowb = blockIdx.y * 128 + wave * 32 + mt * 16 + q * 4;
#pragma unroll
            for (int r = 0; r < 4; ++r)
                stf(C, (long)(rowb + r) * 64 + col, acc[mt][nt][r]);
        }
    }
}

// ---------------------------------------------------------------------------
// QKV via MFMA: X(1536,512)bf16 @ Wt(1536,512)bf16 -> scatter bf16 q/k/v
// (B,H,N,DK). (bf16 epilogue: all consumers are now MFMA kernels.)
// ---------------------------------------------------------------------------
__global__ __launch_bounds__(256) void qkv_mfma(
    const bf16* __restrict__ X, const bf16* __restrict__ Wt,
    bf16* __restrict__ Q, bf16* __restrict__ Ko, bf16* __restrict__ V)
{
    constexpr int K = Dc;  // 512
    __shared__ unsigned short Asm[128 * 40];
    __shared__ unsigned short Bsm[128 * 40];

    const int tid  = threadIdx.x;
    const int wave = tid >> 6;
    const int lane = tid & 63;
    const int q    = lane >> 4;
    const int ln   = lane & 15;
    const int wm   = wave & 1;
    const int wn   = wave >> 1;

    const bf16* A  = X  + (long)(blockIdx.y * 128) * K;
    const bf16* Bt = Wt + (long)(blockIdx.x * 128) * K;

    const int r_s0 = tid >> 2, c_s = tid & 3;
    const int r_s1 = r_s0 + 64;
    const bf16* pa0 = A  + (long)r_s0 * K + c_s * 8;
    const bf16* pa1 = A  + (long)r_s1 * K + c_s * 8;
    const bf16* pb0 = Bt + (long)r_s0 * K + c_s * 8;
    const bf16* pb1 = Bt + (long)r_s1 * K + c_s * 8;
    const int w_s0 = r_s0 * 40 + c_s * 8;
    const int w_s1 = r_s1 * 40 + c_s * 8;

    f32x4 acc[4][4];
#pragma unroll
    for (int i = 0; i < 4; ++i)
#pragma unroll
        for (int j = 0; j < 4; ++j)
            acc[i][j] = (f32x4){0.f, 0.f, 0.f, 0.f};

    for (int k0 = 0; k0 < K; k0 += 32) {
        const uint4 va0 = *(const uint4*)(pa0 + k0);
        const uint4 va1 = *(const uint4*)(pa1 + k0);
        const uint4 vb0 = *(const uint4*)(pb0 + k0);
        const uint4 vb1 = *(const uint4*)(pb1 + k0);
        __syncthreads();
        *(uint4*)&Asm[w_s0] = va0;
        *(uint4*)&Asm[w_s1] = va1;
        *(uint4*)&Bsm[w_s0] = vb0;
        *(uint4*)&Bsm[w_s1] = vb1;
        __syncthreads();

        short8 af[4], bfr[4];
#pragma unroll
        for (int mt = 0; mt < 4; ++mt) {
            int m = wm * 64 + mt * 16 + ln;
            af[mt] = *(const short8*)&Asm[m * 40 + q * 8];
        }
#pragma unroll
        for (int nt = 0; nt < 4; ++nt) {
            int n = wn * 64 + nt * 16 + ln;
            bfr[nt] = *(const short8*)&Bsm[n * 40 + q * 8];
        }
#pragma unroll
        for (int mt = 0; mt < 4; ++mt)
#pragma unroll
            for (int nt = 0; nt < 4; ++nt)
                acc[mt][nt] = __builtin_amdgcn_mfma_f32_16x16x32_bf16(
                    af[mt], bfr[nt], acc[mt][nt], 0, 0, 0);
    }

#pragma unroll
    for (int mt = 0; mt < 4; ++mt) {
#pragma unroll
        for (int nt = 0; nt < 4; ++nt) {
            const int col  = blockIdx.x * 128 + wn * 64 + nt * 16 + ln;
            const int rowb = blockIdx.y * 128 + wm * 64 + mt * 16 + q * 4;
            const int t = col >> 9;
            const int h = (col >> 6) & 7;
            const int dk = col & 63;
            bf16* dst = (t == 0) ? Q : (t == 1) ? Ko : V;
#pragma unroll
            for (int r = 0; r < 4; ++r) {
                const int row = rowb + r;
                const int b = row >= Nc ? 1 : 0;
                const int n = row - b * Nc;
                dst[(((long)b * Hc + h) * Nc + n) * DKc + dk] =
                    __float2bfloat16(acc[mt][nt][r]);
            }
        }
    }
}

// ---------------------------------------------------------------------------
// Generic fp32 64x64-tile GEMM (used only for the final projection now).
// ---------------------------------------------------------------------------
template <typename TA, typename TB, typename TC, int EPI>
__global__ __launch_bounds__(256) void gemm_tile(
    const TA* __restrict__ Ag, const TB* __restrict__ Bg, TC* __restrict__ Cg,
    int M, int Nm, int K, int lda, int ldb, int ldc,
    long sA, long sB, long sC, float alpha)
{
    __shared__ float As[16][68];
    __shared__ float Bs[16][68];

    const int bz = blockIdx.z;
    const TA* A = Ag + (long)bz * sA;
    const TB* B = Bg + (long)bz * sB;
    TC*       C = Cg + (long)bz * sC;

    const int r0 = blockIdx.y * 64;
    const int c0 = blockIdx.x * 64;
    const int tid = threadIdx.x;
    const int tx = tid & 15, ty = tid >> 4;

    float acc[4][4] = {};

    for (int k0 = 0; k0 < K; k0 += 16) {
        {
            int kk = tid & 15;
            int rbase = tid >> 4;
#pragma unroll
            for (int i = 0; i < 4; ++i) {
                int row = rbase + i * 16;
                As[kk][row] = ldf(A, (long)(r0 + row) * lda + k0 + kk);
            }
        }
        {
            int cc = tid & 63;
            int kb = tid >> 6;
#pragma unroll
            for (int i = 0; i < 4; ++i) {
                int kk = kb + i * 4;
                Bs[kk][cc] = ldf(B, (long)(k0 + kk) * ldb + c0 + cc);
            }
        }
        __syncthreads();
#pragma unroll
        for (int kk = 0; kk < 16; ++kk) {
            float4 a4 = *(const float4*)&As[kk][ty * 4];
            float4 b4 = *(const float4*)&Bs[kk][tx * 4];
            float av[4] = {a4.x, a4.y, a4.z, a4.w};
            float bv[4] = {b4.x, b4.y, b4.z, b4.w};
#pragma unroll
            for (int i = 0; i < 4; ++i)
#pragma unroll
                for (int j = 0; j < 4; ++j)
                    acc[i][j] = fmaf(av[i], bv[j], acc[i][j]);
        }
        __syncthreads();
    }

#pragma unroll
    for (int i = 0; i < 4; ++i) {
        int row = r0 + ty * 4 + i;
#pragma unroll
        for (int j = 0; j < 4; ++j) {
            int col = c0 + tx * 4 + j;
            float v = acc[i][j] * alpha;
            if (EPI == 1) v = __logf(fmaxf(v, 0.f) + EPSF);
            stf(C, (long)row * ldc + col, v);
        }
    }
}

// ---------------------------------------------------------------------------
// Row softmax over width 768 (validated).
// ---------------------------------------------------------------------------
template <typename TO>
__global__ __launch_bounds__(256) void softmax_rows(const float* src, TO* dst)
{
    __shared__ float red[4];
    const long row = blockIdx.x;
    const float* s = src + row * Nc;
    TO* d = dst + row * Nc;
    const int tid = threadIdx.x;

    float v[3];
    float m = -1e30f;
#pragma unroll
    for (int i = 0; i < 3; ++i) { v[i] = s[tid + i * 256]; m = fmaxf(m, v[i]); }

#pragma unroll
    for (int off = 32; off > 0; off >>= 1) m = fmaxf(m, __shfl_down(m, off, 64));
    if ((tid & 63) == 0) red[tid >> 6] = m;
    __syncthreads();
    if (tid == 0) {
        float mm = red[0];
        for (int w = 1; w < 4; ++w) mm = fmaxf(mm, red[w]);
        red[0] = mm;
    }
    __syncthreads();
    m = red[0];
    __syncthreads();

    float e[3];
    float sum = 0.f;
#pragma unroll
    for (int i = 0; i < 3; ++i) { e[i] = __expf(v[i] - m); sum += e[i]; }
#pragma unroll
    for (int off = 32; off > 0; off >>= 1) sum += __shfl_down(sum, off, 64);
    if ((tid & 63) == 0) red[tid >> 6] = sum;
    __syncthreads();
    if (tid == 0) red[0] = red[0] + red[1] + red[2] + red[3];
    __syncthreads();
    const float inv = 1.f / fmaxf(red[0], 1e-30f);
#pragma unroll
    for (int i = 0; i < 3; ++i) stf(d, tid + i * 256, e[i] * inv);
}

// ---------------------------------------------------------------------------
// Gate network + Smix, 4 elements/thread. Weights read via UNIFORM global
// loads (s_load / scalar cache) — NOT LDS (round-4 lesson: 176 ds_read/thread
// serialized the MLP).
// ---------------------------------------------------------------------------
__global__ __launch_bounds__(256) void gates_smix(
    const float* __restrict__ S1g, const float* __restrict__ S2g,
    const bf16* __restrict__ Crg, const bf16* __restrict__ Clg,
    float* __restrict__ Smixg, const float* __restrict__ gw)
{
    __shared__ float t1t[64][21], t2t[64][21];

    const long mat = (long)blockIdx.z * Nc * Nc;
    const float* S1 = S1g + mat;
    const float* S2 = S2g + mat;
    const unsigned short* Cr = (const unsigned short*)Crg + mat;
    const unsigned short* Cl = (const unsigned short*)Clg + mat;
    float* Smix = Smixg + mat;

    const int tid = threadIdx.x;
    const int m0 = blockIdx.x * 64, n0 = blockIdx.y * 16;
    {   // transposed tiles: S[m0..m0+63][n0..n0+15], coalesced float4 loads
        const int r = tid >> 2, c4 = (tid & 3) * 4;
        const float4 a = *(const float4*)&S1[(long)(m0 + r) * Nc + n0 + c4];
        const float4 b = *(const float4*)&S2[(long)(m0 + r) * Nc + n0 + c4];
        t1t[r][c4] = a.x; t1t[r][c4 + 1] = a.y; t1t[r][c4 + 2] = a.z; t1t[r][c4 + 3] = a.w;
        t2t[r][c4] = b.x; t2t[r][c4 + 1] = b.y; t2t[r][c4 + 2] = b.z; t2t[r][c4 + 3] = b.w;
    }
    __syncthreads();

    const int ty = tid >> 4, tx = tid & 15;
    const int n = n0 + ty;
    const long idx = (long)n * Nc + m0 + tx * 4;

    const float4 s1v = *(const float4*)&S1[idx];
    const float4 s2v = *(const float4*)&S2[idx];
    const uint2 cru = *(const uint2*)&Cr[idx];
    const uint2 clu = *(const uint2*)&Cl[idx];

    float s1a[4] = {s1v.x, s1v.y, s1v.z, s1v.w};
    float s2a[4] = {s2v.x, s2v.y, s2v.z, s2v.w};
    float cra[4] = {__uint_as_float((cru.x & 0xffffu) << 16),
                    __uint_as_float(cru.x & 0xffff0000u),
                    __uint_as_float((cru.y & 0xffffu) << 16),
                    __uint_as_float(cru.y & 0xffff0000u)};
    float cla[4] = {__uint_as_float((clu.x & 0xffffu) << 16),
                    __uint_as_float(clu.x & 0xffff0000u),
                    __uint_as_float((clu.y & 0xffffu) << 16),
                    __uint_as_float(clu.y & 0xffff0000u)};
    float s1t[4], s2t[4];
#pragma unroll
    for (int j = 0; j < 4; ++j) {
        s1t[j] = t1t[tx * 4 + j][ty];
        s2t[j] = t2t[tx * 4 + j][ty];
    }

    float g[4][4];
#pragma unroll
    for (int o = 0; o < 4; ++o)
#pragma unroll
        for (int j = 0; j < 4; ++j) g[o][j] = gw[176 + o];

#pragma unroll
    for (int u = 0; u < 16; ++u) {
        const float wf0 = gw[u * 6 + 0], wf1 = gw[u * 6 + 1], wf2 = gw[u * 6 + 2];
        const float wf3 = gw[u * 6 + 3], wf4 = gw[u * 6 + 4], wf5 = gw[u * 6 + 5];
        const float bu = gw[96 + u];
        float hid[4];
#pragma unroll
        for (int j = 0; j < 4; ++j) {
            float h = bu;
            h = fmaf(s1a[j], wf0, h);
            h = fmaf(s2a[j], wf1, h);
            h = fmaf(s1t[j], wf2, h);
            h = fmaf(s2t[j], wf3, h);
            h = fmaf(cra[j], wf4, h);
            h = fmaf(cla[j], wf5, h);
            // gelu_tanh(h) = h * sigmoid(2z), z = 0.79788456(h + 0.044715 h^3)
            const float hh = h * h;
            const float inner = fmaf(hh, 0.0356774081f, 0.7978845608f);
            const float z = h * inner;
            const float e = __expf(-2.f * z);
            hid[j] = h * __fdividef(1.f, 1.f + e);
        }
#pragma unroll
        for (int o = 0; o < 4; ++o) {
            const float w2o = gw[112 + o * 16 + u];
#pragma unroll
            for (int j = 0; j < 4; ++j) g[o][j] = fmaf(hid[j], w2o, g[o][j]);
        }
    }

    float out[4];
#pragma unroll
    for (int j = 0; j < 4; ++j) {
        const float ga = sigf(g[0][j]);
        const float go = sigf(g[1][j]);
        const float gn = sigf(g[2][j]);
        const float gc = sigf(g[3][j]);
        const float s1 = s1a[j], s2 = s2a[j];
        const float mx = fmaxf(s1, s2);
        const float lae = mx + __logf(1.f + __expf(-fabsf(s1 - s2)));
        out[j] = s1 + ga * s2 + go * (lae - s1) - gn * (BETA_NOT * s2) + gc * cra[j];
    }
    *(float4*)&Smix[idx] = (float4){out[0], out[1], out[2], out[3]};
}

// ---------------------------------------------------------------------------
__global__ __launch_bounds__(256) void combine_y(
    const float* __restrict__ y1, const float* __restrict__ y2,
    const float* __restrict__ smallf, float* __restrict__ y)
{
    const long i = (long)blockIdx.x * 256 + threadIdx.x;
    const int dk = (int)(i & 63);
    const long t = i >> 6;
    const int n = (int)(t % Nc);
    const long t2 = t / Nc;
    const int h = (int)(t2 & 7);
    const int b = (int)(t2 >> 3);
    const float w = 1.f / (1.f + __expf(-smallf[180]));
    const float v = y1[i] + w * y2[i];
    y[((long)(b * Nc + n)) * Dc + h * DKc + dk] = v;
}

__global__ __launch_bounds__(256) void store_out(
    const float* __restrict__ yo, const void* xraw, void* out)
{
    const int is32 = sniff_is_fp32(xraw);
    const long i = (long)blockIdx.x * 256 + threadIdx.x;
    if (i < (long)Bc * Nc * Dc) {
        if (is32) ((float*)out)[i] = yo[i];
        else      ((bf16*)out)[i] = __float2bfloat16(yo[i]);
    }
}

// ---------------------------------------------------------------------------
extern "C" void kernel_launch(void* const* d_in, const int* in_sizes, int n_in,
                              void* d_out, int out_size, void* d_ws, size_t ws_size,
                              hipStream_t stream)
{
    const size_t HD   = (size_t)BHc * Nc * DKc;   // 786432
    const size_t HDh  = HD / 2;                   // float-slots for HD bf16
    const size_t MAT  = (size_t)Nc * Nc;          // 589824
    const size_t MATS = (size_t)BHc * MAT;        // 9437184
    const long   HSTR = (long)Nc * DKc;           // 49152 per-head stride

    float* ws = (float*)d_ws;
    size_t off = 0;
    auto alloc = [&](size_t n) { float* p = ws + off; off += n; return p; };

    bf16* xb  = (bf16*)alloc(HDh);
    bf16* w1b = (bf16*)alloc(HDh);
    bf16* w2b = (bf16*)alloc(HDh);
    bf16* w1t = (bf16*)alloc(HDh);
    bf16* w2t = (bf16*)alloc(HDh);
    float* pwf    = alloc((size_t)Dc * Dc);
    float* smallf = alloc(192);
    bf16* q1b = (bf16*)alloc(HDh); bf16* k1b = (bf16*)alloc(HDh); bf16* v1b = (bf16*)alloc(HDh);
    bf16* q2b = (bf16*)alloc(HDh); bf16* k2b = (bf16*)alloc(HDh); bf16* v2b = (bf16*)alloc(HDh);
    bf16* v1t = (bf16*)alloc(HDh);
    bf16* v2t = (bf16*)alloc(HDh);
    bf16* trb = (bf16*)alloc(HDh);
    bf16* trt = (bf16*)alloc(HDh);
    float* S1   = alloc(MATS);
    float* S2   = alloc(MATS);
    float* Smix = alloc(MATS);
    bf16* A1b = (bf16*)alloc(MATS / 2);
    bf16* A2b = (bf16*)alloc(MATS / 2);
    bf16* Crb = (bf16*)alloc(MATS / 2);
    bf16* Clb = (bf16*)alloc(MATS / 2);
    float* yb1 = alloc(HD);
    float* yb2 = alloc(HD);
    float* yc  = alloc(HD);
    float* yout = alloc(HD);

    // aliases into dead regions
    bf16* A1tb = (bf16*)Smix;            // dead until gates writes Smix
    bf16* A2tb = ((bf16*)Smix) + MATS;
    bf16* Ab   = (bf16*)S1;              // S1 dead after gates

    const size_t NEED_BYTES = off * sizeof(float);   // ~226 MB
    if (ws_size < NEED_BYTES) {
        fill_sentinel<<<dim3(3072), 256, 0, stream>>>((unsigned short*)d_out);
        return;
    }

    // 0. normalize inputs
    convert_all<<<dim3(3072), 256, 0, stream>>>(
        d_in[0], d_in[1], d_in[2], d_in[3], d_in[4], d_in[5], d_in[6], d_in[7],
        d_in[8], xb, w1b, w2b, pwf, smallf);

    // 1. W transposes, QKV via MFMA (bf16 out), v transposes
    transpose_bf16<<<dim3(24, 8, 1), 256, 0, stream>>>(
        (const unsigned short*)w1b, (unsigned short*)w1t, Dc, 3 * Dc, 0, 0);
    transpose_bf16<<<dim3(24, 8, 1), 256, 0, stream>>>(
        (const unsigned short*)w2b, (unsigned short*)w2t, Dc, 3 * Dc, 0, 0);
    qkv_mfma<<<dim3(12, 12, 1), 256, 0, stream>>>(xb, w1t, q1b, k1b, v1b);
    qkv_mfma<<<dim3(12, 12, 1), 256, 0, stream>>>(xb, w2t, q2b, k2b, v2b);
    transpose_bf16<<<dim3(1, 12, BHc), 256, 0, stream>>>(
        (const unsigned short*)v1b, (unsigned short*)v1t, Nc, DKc, HSTR, HSTR);
    transpose_bf16<<<dim3(1, 12, BHc), 256, 0, stream>>>(
        (const unsigned short*)v2b, (unsigned short*)v2t, Nc, DKc, HSTR, HSTR);

    // 2. S = scale * q @ k^T per head via MFMA (fp32 out)
    gemm_nt_mfma<0, float><<<dim3(6, 6, BHc), 256, 0, stream>>>(
        q1b, k1b, S1, Nc, Nc, DKc, HSTR, HSTR, (long)MAT, SCALE);
    gemm_nt_mfma<0, float><<<dim3(6, 6, BHc), 256, 0, stream>>>(
        q2b, k2b, S2, Nc, Nc, DKc, HSTR, HSTR, (long)MAT, SCALE);

    // 3. A1/A2 = softmax(S) -> bf16, transposes into Smix alias
    softmax_rows<bf16><<<BHc * Nc, 256, 0, stream>>>(S1, A1b);
    softmax_rows<bf16><<<BHc * Nc, 256, 0, stream>>>(S2, A2b);
    transpose_bf16<<<dim3(12, 12, BHc), 256, 0, stream>>>(
        (const unsigned short*)A1b, (unsigned short*)A1tb, Nc, Nc, (long)MAT, (long)MAT);
    transpose_bf16<<<dim3(12, 12, BHc), 256, 0, stream>>>(
        (const unsigned short*)A2b, (unsigned short*)A2tb, Nc, Nc, (long)MAT, (long)MAT);

    // 4. Cr/Cl via bf16 MFMA + log epilogue
    gemm_nt_mfma<1, bf16><<<dim3(6, 6, BHc), 256, 0, stream>>>(
        A1b, A2tb, Crb, Nc, Nc, Nc, (long)MAT, (long)MAT, (long)MAT, 1.f);
    gemm_nt_mfma<1, bf16><<<dim3(6, 6, BHc), 256, 0, stream>>>(
        A2b, A1tb, Clb, Nc, Nc, Nc, (long)MAT, (long)MAT, (long)MAT, 1.f);

    // 5. gates + Smix (uniform-load weights)
    gates_smix<<<dim3(12, 48, BHc), 256, 0, stream>>>(S1, S2, Crb, Clb, Smix, smallf);

    // 6. A = softmax(Smix) -> bf16 (into S1 alias; S1 is dead post-gates)
    softmax_rows<bf16><<<BHc * Nc, 256, 0, stream>>>(Smix, Ab);

    // 7. transport = A2 @ v2 (bf16 out), then transpose for the next NT GEMM
    gemm_nt_n64<bf16><<<dim3(1, 6, BHc), 256, 0, stream>>>(
        A2b, v2t, trb, Nc, Nc, (long)MAT, HSTR, HSTR);
    transpose_bf16<<<dim3(1, 12, BHc), 256, 0, stream>>>(
        (const unsigned short*)trb, (unsigned short*)trt, Nc, DKc, HSTR, HSTR);

    // 8. y_base = A @ v1 ; y_chain = A1 @ transport (fp32 out)
    gemm_nt_n64<float><<<dim3(1, 6, BHc), 256, 0, stream>>>(
        Ab, v1t, yb1, Nc, Nc, (long)MAT, HSTR, HSTR);
    gemm_nt_n64<float><<<dim3(1, 6, BHc), 256, 0, stream>>>(
        A1b, trt, yb2, Nc, Nc, (long)MAT, HSTR, HSTR);

    // 9. combine + layout
    combine_y<<<dim3(3072), 256, 0, stream>>>(yb1, yb2, smallf, yc);

    // 10. proj + dtype-aware store
    gemm_tile<float, float, float, 0><<<dim3(8, 24, 1), 256, 0, stream>>>(
        yc, pwf, yout, Bc * Nc, Dc, Dc, Dc, Dc, Dc, 0, 0, 0, 1.f);
    store_out<<<dim3(3072), 256, 0, stream>>>(yout, d_in[0], d_out);
}

// Round 6
// 593.361 us; speedup vs baseline: 1.1368x; 1.1368x over previous
//
#include <hip/hip_runtime.h>
#include <hip/hip_bf16.h>
#include <math.h>

typedef __hip_bfloat16 bf16;
typedef __attribute__((ext_vector_type(8))) short short8;   // 8 bf16 (4 VGPRs)
typedef __attribute__((ext_vector_type(4))) float f32x4;
#define DEVINL __device__ __forceinline__

constexpr int Bc  = 2;
constexpr int Nc  = 768;
constexpr int Dc  = 512;
constexpr int Hc  = 8;
constexpr int DKc = 64;
constexpr int BHc = Bc * Hc;
constexpr float SCALE    = 0.125f;   // 1/sqrt(64)
constexpr float EPSF     = 1e-6f;
constexpr float BETA_NOT = 0.5f;

DEVINL float ldf(const float* p, long i) { return p[i]; }
DEVINL float ldf(const bf16* p, long i) { return __bfloat162float(p[i]); }
DEVINL void stf(float* p, long i, float v) { p[i] = v; }
DEVINL void stf(bf16* p, long i, float v) { p[i] = __float2bfloat16(v); }

DEVINL float sigf(float x) { return __fdividef(1.f, 1.f + __expf(-x)); }

// async global->LDS, 16B per lane; LDS dest = wave-uniform base + lane*16.
DEVINL void gl_lds16(const void* g, void* l) {
    __builtin_amdgcn_global_load_lds(
        (const __attribute__((address_space(1))) void*)g,
        (__attribute__((address_space(3))) void*)l, 16, 0, 0);
}

// ---------------------------------------------------------------------------
// Dtype sniffer (round-1 notes). Deterministic per launch.
// ---------------------------------------------------------------------------
DEVINL int sniff_is_fp32(const void* xraw) {
    const unsigned short* p = (const unsigned short*)xraw;
    float mx = 0.f;
#pragma unroll 1
    for (int j = 0; j < 128; ++j) {
        float v = __uint_as_float(((unsigned)p[j]) << 16);
        mx = fmaxf(mx, fabsf(v));
    }
    return mx > 1000.f ? 1 : 0;
}

DEVINL float cvt_elem(const void* s, long j, int is32) {
    return is32 ? ((const float*)s)[j]
                : __bfloat162float(((const bf16*)s)[j]);
}

__global__ __launch_bounds__(256) void convert_all(
    const void* x, const void* w1, const void* w2, const void* pw,
    const void* c1w, const void* c1b, const void* c2w, const void* c2b,
    const void* ch,
    bf16* xb, bf16* w1b, bf16* w2b, float* pwf, float* smallf)
{
    const int is32 = sniff_is_fp32(x);
    const long i = (long)blockIdx.x * 256 + threadIdx.x;
    if (i < (long)Bc * Nc * Dc) {
        xb[i]  = __float2bfloat16(cvt_elem(x,  i, is32));
        w1b[i] = __float2bfloat16(cvt_elem(w1, i, is32));
        w2b[i] = __float2bfloat16(cvt_elem(w2, i, is32));
    }
    if (i < (long)Dc * Dc) pwf[i] = cvt_elem(pw, i, is32);
    if (i < 96)       smallf[i] = cvt_elem(c1w, i,        is32);
    else if (i < 112) smallf[i] = cvt_elem(c1b, i - 96,   is32);
    else if (i < 176) smallf[i] = cvt_elem(c2w, i - 112,  is32);
    else if (i < 180) smallf[i] = cvt_elem(c2b, i - 176,  is32);
    else if (i == 180) smallf[180] = cvt_elem(ch, 0, is32);
}

__global__ __launch_bounds__(256) void fill_sentinel(unsigned short* o) {
    const long i = (long)blockIdx.x * 256 + threadIdx.x;
    if (i < (long)Bc * Nc * Dc) o[i] = 0x40E0;  // bf16 7.0
}

// ---------------------------------------------------------------------------
// Generic bf16 transpose, 64x64 tiles: dst[c][r] = src[r][c]; src is (R,C).
// ---------------------------------------------------------------------------
__global__ __launch_bounds__(256) void transpose_bf16(
    const unsigned short* __restrict__ src, unsigned short* __restrict__ dst,
    int R, int C, long sS, long sD)
{
    __shared__ unsigned short tile[64][68];
    const unsigned short* s = src + (long)blockIdx.z * sS;
    unsigned short* d = dst + (long)blockIdx.z * sD;
    const int r0 = blockIdx.y * 64, c0 = blockIdx.x * 64;
    const int t = threadIdx.x;
    const int lr = t >> 4, lc4 = (t & 15) * 4;
#pragma unroll
    for (int i = 0; i < 4; ++i) {
        int r = lr + i * 16;
        *(uint2*)&tile[r][lc4] = *(const uint2*)&s[(long)(r0 + r) * C + c0 + lc4];
    }
    __syncthreads();
#pragma unroll
    for (int i = 0; i < 4; ++i) {
        int r = lr + i * 16;
        unsigned short v[4];
#pragma unroll
        for (int j = 0; j < 4; ++j) v[j] = tile[lc4 + j][r];
        *(uint2*)&d[(long)(c0 + r) * R + r0 + lc4] = *(uint2*)v;
    }
}

// ---------------------------------------------------------------------------
// MFMA bf16 NT GEMM with global_load_lds staging: C = A(M,K) @ Bt(N,K)^T.
// 128x128 tile, BK=32. LDS rows UNPADDED 32 shorts (64 B) so a wave's lanes
// land lane-linearly (base + lane*16B); frag ds_read_b128 is 2-way aliased
// only (free, m136). Wave w stages rows [w*32, w*32+32) of A and B.
// ---------------------------------------------------------------------------
template <int EPI, typename TC>
__global__ __launch_bounds__(256) void gemm_nt_mfma(
    const bf16* __restrict__ Ag, const bf16* __restrict__ Btg,
    TC* __restrict__ Cg, int M, int N, int K,
    long sA, long sB, long sC, float alpha)
{
    __shared__ unsigned short Asm[128 * 32];
    __shared__ unsigned short Bsm[128 * 32];

    const int tid  = threadIdx.x;
    const int wv   = tid >> 6;
    const int lane = tid & 63;
    const int q    = lane >> 4;
    const int ln   = lane & 15;
    const int wm   = wv & 1;
    const int wn   = wv >> 1;

    const bf16* A  = Ag  + (long)blockIdx.z * sA + (long)(blockIdx.y * 128) * K;
    const bf16* Bt = Btg + (long)blockIdx.z * sB + (long)(blockIdx.x * 128) * K;
    TC*         C  = Cg  + (long)blockIdx.z * sC;

    const int sr = lane >> 2, sc = lane & 3;
    const bf16* gA0 = A  + (long)(wv * 32 + sr)      * K + sc * 8;
    const bf16* gA1 = A  + (long)(wv * 32 + 16 + sr) * K + sc * 8;
    const bf16* gB0 = Bt + (long)(wv * 32 + sr)      * K + sc * 8;
    const bf16* gB1 = Bt + (long)(wv * 32 + 16 + sr) * K + sc * 8;
    unsigned short* lA0 = &Asm[(wv * 32)      * 32];
    unsigned short* lA1 = &Asm[(wv * 32 + 16) * 32];
    unsigned short* lB0 = &Bsm[(wv * 32)      * 32];
    unsigned short* lB1 = &Bsm[(wv * 32 + 16) * 32];

    f32x4 acc[4][4];
#pragma unroll
    for (int i = 0; i < 4; ++i)
#pragma unroll
        for (int j = 0; j < 4; ++j)
            acc[i][j] = (f32x4){0.f, 0.f, 0.f, 0.f};

    for (int k0 = 0; k0 < K; k0 += 32) {
        __syncthreads();   // previous iteration's frag reads complete
        gl_lds16(gA0 + k0, lA0);
        gl_lds16(gA1 + k0, lA1);
        gl_lds16(gB0 + k0, lB0);
        gl_lds16(gB1 + k0, lB1);
        __syncthreads();   // drains vmcnt before barrier (compiler-inserted)

        short8 af[4], bfr[4];
#pragma unroll
        for (int mt = 0; mt < 4; ++mt) {
            int m = wm * 64 + mt * 16 + ln;
            af[mt] = *(const short8*)&Asm[m * 32 + q * 8];
        }
#pragma unroll
        for (int nt = 0; nt < 4; ++nt) {
            int n = wn * 64 + nt * 16 + ln;
            bfr[nt] = *(const short8*)&Bsm[n * 32 + q * 8];
        }
#pragma unroll
        for (int mt = 0; mt < 4; ++mt)
#pragma unroll
            for (int nt = 0; nt < 4; ++nt)
                acc[mt][nt] = __builtin_amdgcn_mfma_f32_16x16x32_bf16(
                    af[mt], bfr[nt], acc[mt][nt], 0, 0, 0);
    }

#pragma unroll
    for (int mt = 0; mt < 4; ++mt) {
#pragma unroll
        for (int nt = 0; nt < 4; ++nt) {
            const int col = blockIdx.x * 128 + wn * 64 + nt * 16 + ln;
            const int rowb = blockIdx.y * 128 + wm * 64 + mt * 16 + q * 4;
#pragma unroll
            for (int r = 0; r < 4; ++r) {
                float v = acc[mt][nt][r] * alpha;
                if (EPI == 1) v = __logf(fmaxf(v, 0.f) + EPSF);
                stf(C, (long)(rowb + r) * N + col, v);
            }
        }
    }
}

// ---------------------------------------------------------------------------
// QKV via MFMA, merged sets (z: 0 = set1, 1 = set2), global_load_lds staging.
// X(1536,512)bf16 @ Wt(1536,512)bf16 -> scatter bf16 q/k/v (B,H,N,DK).
// ---------------------------------------------------------------------------
__global__ __launch_bounds__(256) void qkv_mfma(
    const bf16* __restrict__ X,
    const bf16* __restrict__ w1t, const bf16* __restrict__ w2t,
    bf16* __restrict__ q1, bf16* __restrict__ k1, bf16* __restrict__ v1,
    bf16* __restrict__ q2, bf16* __restrict__ k2, bf16* __restrict__ v2)
{
    constexpr int K = Dc;  // 512
    __shared__ unsigned short Asm[128 * 32];
    __shared__ unsigned short Bsm[128 * 32];

    const int tid  = threadIdx.x;
    const int wv   = tid >> 6;
    const int lane = tid & 63;
    const int q    = lane >> 4;
    const int ln   = lane & 15;
    const int wm   = wv & 1;
    const int wn   = wv >> 1;
    const int set  = blockIdx.z;

    const bf16* Wt = set ? w2t : w1t;
    bf16* Q  = set ? q2 : q1;
    bf16* Ko = set ? k2 : k1;
    bf16* V  = set ? v2 : v1;

    const bf16* A  = X  + (long)(blockIdx.y * 128) * K;
    const bf16* Bt = Wt + (long)(blockIdx.x * 128) * K;

    const int sr = lane >> 2, sc = lane & 3;
    const bf16* gA0 = A  + (long)(wv * 32 + sr)      * K + sc * 8;
    const bf16* gA1 = A  + (long)(wv * 32 + 16 + sr) * K + sc * 8;
    const bf16* gB0 = Bt + (long)(wv * 32 + sr)      * K + sc * 8;
    const bf16* gB1 = Bt + (long)(wv * 32 + 16 + sr) * K + sc * 8;
    unsigned short* lA0 = &Asm[(wv * 32)      * 32];
    unsigned short* lA1 = &Asm[(wv * 32 + 16) * 32];
    unsigned short* lB0 = &Bsm[(wv * 32)      * 32];
    unsigned short* lB1 = &Bsm[(wv * 32 + 16) * 32];

    f32x4 acc[4][4];
#pragma unroll
    for (int i = 0; i < 4; ++i)
#pragma unroll
        for (int j = 0; j < 4; ++j)
            acc[i][j] = (f32x4){0.f, 0.f, 0.f, 0.f};

    for (int k0 = 0; k0 < K; k0 += 32) {
        __syncthreads();
        gl_lds16(gA0 + k0, lA0);
        gl_lds16(gA1 + k0, lA1);
        gl_lds16(gB0 + k0, lB0);
        gl_lds16(gB1 + k0, lB1);
        __syncthreads();

        short8 af[4], bfr[4];
#pragma unroll
        for (int mt = 0; mt < 4; ++mt) {
            int m = wm * 64 + mt * 16 + ln;
            af[mt] = *(const short8*)&Asm[m * 32 + q * 8];
        }
#pragma unroll
        for (int nt = 0; nt < 4; ++nt) {
            int n = wn * 64 + nt * 16 + ln;
            bfr[nt] = *(const short8*)&Bsm[n * 32 + q * 8];
        }
#pragma unroll
        for (int mt = 0; mt < 4; ++mt)
#pragma unroll
            for (int nt = 0; nt < 4; ++nt)
                acc[mt][nt] = __builtin_amdgcn_mfma_f32_16x16x32_bf16(
                    af[mt], bfr[nt], acc[mt][nt], 0, 0, 0);
    }

#pragma unroll
    for (int mt = 0; mt < 4; ++mt) {
#pragma unroll
        for (int nt = 0; nt < 4; ++nt) {
            const int col  = blockIdx.x * 128 + wn * 64 + nt * 16 + ln;
            const int rowb = blockIdx.y * 128 + wm * 64 + mt * 16 + q * 4;
            const int t = col >> 9;
            const int h = (col >> 6) & 7;
            const int dk = col & 63;
            bf16* dst = (t == 0) ? Q : (t == 1) ? Ko : V;
#pragma unroll
            for (int r = 0; r < 4; ++r) {
                const int row = rowb + r;
                const int b = row >= Nc ? 1 : 0;
                const int n = row - b * Nc;
                dst[(((long)b * Hc + h) * Nc + n) * DKc + dk] =
                    __float2bfloat16(acc[mt][nt][r]);
            }
        }
    }
}

// ---------------------------------------------------------------------------
// MFMA bf16 NT GEMM, narrow (validated round 5): C(M,64) = A(M,K) @ Bt(64,K)^T.
// ---------------------------------------------------------------------------
template <typename TC>
__global__ __launch_bounds__(256) void gemm_nt_n64(
    const bf16* __restrict__ Ag, const bf16* __restrict__ Btg,
    TC* __restrict__ Cg, int M, int K, long sA, long sB, long sC)
{
    __shared__ unsigned short Asm[128 * 72];
    __shared__ unsigned short Bsm[64 * 72];

    const int tid  = threadIdx.x;
    const int wave = tid >> 6;
    const int lane = tid & 63;
    const int q    = lane >> 4;
    const int ln   = lane & 15;

    const bf16* A  = Ag  + (long)blockIdx.z * sA + (long)(blockIdx.y * 128) * K;
    const bf16* Bt = Btg + (long)blockIdx.z * sB;
    TC*         C  = Cg  + (long)blockIdx.z * sC;

    const int sr = tid >> 3, k8 = tid & 7;
    const bf16* pa[4];
    const bf16* pb[2];
    int wa[4], wb[2];
#pragma unroll
    for (int i = 0; i < 4; ++i) {
        pa[i] = A + (long)(sr + i * 32) * K + k8 * 8;
        wa[i] = (sr + i * 32) * 72 + k8 * 8;
    }
#pragma unroll
    for (int i = 0; i < 2; ++i) {
        pb[i] = Bt + (long)(sr + i * 32) * K + k8 * 8;
        wb[i] = (sr + i * 32) * 72 + k8 * 8;
    }

    f32x4 acc[2][4];
#pragma unroll
    for (int i = 0; i < 2; ++i)
#pragma unroll
        for (int j = 0; j < 4; ++j)
            acc[i][j] = (f32x4){0.f, 0.f, 0.f, 0.f};

    for (int k0 = 0; k0 < K; k0 += 64) {
        uint4 va[4], vb[2];
#pragma unroll
        for (int i = 0; i < 4; ++i) va[i] = *(const uint4*)(pa[i] + k0);
#pragma unroll
        for (int i = 0; i < 2; ++i) vb[i] = *(const uint4*)(pb[i] + k0);
        __syncthreads();
#pragma unroll
        for (int i = 0; i < 4; ++i) *(uint4*)&Asm[wa[i]] = va[i];
#pragma unroll
        for (int i = 0; i < 2; ++i) *(uint4*)&Bsm[wb[i]] = vb[i];
        __syncthreads();

#pragma unroll
        for (int kc = 0; kc < 2; ++kc) {
            short8 af[2], bfr[4];
#pragma unroll
            for (int mt = 0; mt < 2; ++mt) {
                int m = wave * 32 + mt * 16 + ln;
                af[mt] = *(const short8*)&Asm[m * 72 + kc * 32 + q * 8];
            }
#pragma unroll
            for (int nt = 0; nt < 4; ++nt) {
                int n = nt * 16 + ln;
                bfr[nt] = *(const short8*)&Bsm[n * 72 + kc * 32 + q * 8];
            }
#pragma unroll
            for (int mt = 0; mt < 2; ++mt)
#pragma unroll
                for (int nt = 0; nt < 4; ++nt)
                    acc[mt][nt] = __builtin_amdgcn_mfma_f32_16x16x32_bf16(
                        af[mt], bfr[nt], acc[mt][nt], 0, 0, 0);
        }
    }

#pragma unroll
    for (int mt = 0; mt < 2; ++mt) {
#pragma unroll
        for (int nt = 0; nt < 4; ++nt) {
            const int col  = nt * 16 + ln;
            const int rowb = blockIdx.y * 128 + wave * 32 + mt * 16 + q * 4;
#pragma unroll
            for (int r = 0; r < 4; ++r)
                stf(C, (long)(rowb + r) * 64 + col, acc[mt][nt][r]);
        }
    }
}

// ---------------------------------------------------------------------------
// Row softmax over width 768 (validated).
// ---------------------------------------------------------------------------
template <typename TO>
__global__ __launch_bounds__(256) void softmax_rows(const float* src, TO* dst)
{
    __shared__ float red[4];
    const long row = blockIdx.x;
    const float* s = src + row * Nc;
    TO* d = dst + row * Nc;
    const int tid = threadIdx.x;

    float v[3];
    float m = -1e30f;
#pragma unroll
    for (int i = 0; i < 3; ++i) { v[i] = s[tid + i * 256]; m = fmaxf(m, v[i]); }

#pragma unroll
    for (int off = 32; off > 0; off >>= 1) m = fmaxf(m, __shfl_down(m, off, 64));
    if ((tid & 63) == 0) red[tid >> 6] = m;
    __syncthreads();
    if (tid == 0) {
        float mm = red[0];
        for (int w = 1; w < 4; ++w) mm = fmaxf(mm, red[w]);
        red[0] = mm;
    }
    __syncthreads();
    m = red[0];
    __syncthreads();

    float e[3];
    float sum = 0.f;
#pragma unroll
    for (int i = 0; i < 3; ++i) { e[i] = __expf(v[i] - m); sum += e[i]; }
#pragma unroll
    for (int off = 32; off > 0; off >>= 1) sum += __shfl_down(sum, off, 64);
    if ((tid & 63) == 0) red[tid >> 6] = sum;
    __syncthreads();
    if (tid == 0) red[0] = red[0] + red[1] + red[2] + red[3];
    __syncthreads();
    const float inv = 1.f / fmaxf(red[0], 1e-30f);
#pragma unroll
    for (int i = 0; i < 3; ++i) stf(d, tid + i * 256, e[i] * inv);
}

// ---------------------------------------------------------------------------
// Gate network + Smix — EXACT round-4 version (162 µs validated; LDS weights,
// VGPR~100). Round-5 s_load variant regressed (VGPR 36 -> state spilled).
// ---------------------------------------------------------------------------
__global__ __launch_bounds__(256) void gates_smix(
    const float* __restrict__ S1g, const float* __restrict__ S2g,
    const bf16* __restrict__ Crg, const bf16* __restrict__ Clg,
    float* __restrict__ Smixg, const float* __restrict__ smallf)
{
    __shared__ float t1t[64][21], t2t[64][21];
    __shared__ float cs[192];

    const long mat = (long)blockIdx.z * Nc * Nc;
    const float* S1 = S1g + mat;
    const float* S2 = S2g + mat;
    const unsigned short* Cr = (const unsigned short*)Crg + mat;
    const unsigned short* Cl = (const unsigned short*)Clg + mat;
    float* Smix = Smixg + mat;

    const int tid = threadIdx.x;
    if (tid < 192) cs[tid] = smallf[tid];

    const int m0 = blockIdx.x * 64, n0 = blockIdx.y * 16;
    {
        const int r = tid >> 2, c4 = (tid & 3) * 4;
        const float4 a = *(const float4*)&S1[(long)(m0 + r) * Nc + n0 + c4];
        const float4 b = *(const float4*)&S2[(long)(m0 + r) * Nc + n0 + c4];
        t1t[r][c4] = a.x; t1t[r][c4 + 1] = a.y; t1t[r][c4 + 2] = a.z; t1t[r][c4 + 3] = a.w;
        t2t[r][c4] = b.x; t2t[r][c4 + 1] = b.y; t2t[r][c4 + 2] = b.z; t2t[r][c4 + 3] = b.w;
    }
    __syncthreads();

    const float* cw1 = cs;       const float* cb1 = cs + 96;
    const float* cw2 = cs + 112; const float* cb2 = cs + 176;

    const int ty = tid >> 4, tx = tid & 15;
    const int n = n0 + ty;
    const long idx = (long)n * Nc + m0 + tx * 4;

    const float4 s1v = *(const float4*)&S1[idx];
    const float4 s2v = *(const float4*)&S2[idx];
    const uint2 cru = *(const uint2*)&Cr[idx];
    const uint2 clu = *(const uint2*)&Cl[idx];

    float s1a[4] = {s1v.x, s1v.y, s1v.z, s1v.w};
    float s2a[4] = {s2v.x, s2v.y, s2v.z, s2v.w};
    float cra[4] = {__uint_as_float((cru.x & 0xffffu) << 16),
                    __uint_as_float(cru.x & 0xffff0000u),
                    __uint_as_float((cru.y & 0xffffu) << 16),
                    __uint_as_float(cru.y & 0xffff0000u)};
    float cla[4] = {__uint_as_float((clu.x & 0xffffu) << 16),
                    __uint_as_float(clu.x & 0xffff0000u),
                    __uint_as_float((clu.y & 0xffffu) << 16),
                    __uint_as_float(clu.y & 0xffff0000u)};
    float s1t[4], s2t[4];
#pragma unroll
    for (int j = 0; j < 4; ++j) {
        s1t[j] = t1t[tx * 4 + j][ty];
        s2t[j] = t2t[tx * 4 + j][ty];
    }

    float g[4][4];
#pragma unroll
    for (int o = 0; o < 4; ++o)
#pragma unroll
        for (int j = 0; j < 4; ++j) g[o][j] = cb2[o];

#pragma unroll
    for (int u = 0; u < 16; ++u) {
        const float wf0 = cw1[u * 6 + 0], wf1 = cw1[u * 6 + 1], wf2 = cw1[u * 6 + 2];
        const float wf3 = cw1[u * 6 + 3], wf4 = cw1[u * 6 + 4], wf5 = cw1[u * 6 + 5];
        const float bu = cb1[u];
        float hid[4];
#pragma unroll
        for (int j = 0; j < 4; ++j) {
            float h = bu;
            h = fmaf(s1a[j], wf0, h);
            h = fmaf(s2a[j], wf1, h);
            h = fmaf(s1t[j], wf2, h);
            h = fmaf(s2t[j], wf3, h);
            h = fmaf(cra[j], wf4, h);
            h = fmaf(cla[j], wf5, h);
            const float hh = h * h;
            const float inner = fmaf(hh, 0.0356774081f, 0.7978845608f);
            const float z = h * inner;
            const float e = __expf(-2.f * z);
            hid[j] = h * __fdividef(1.f, 1.f + e);
        }
#pragma unroll
        for (int o = 0; o < 4; ++o) {
            const float w2o = cw2[o * 16 + u];
#pragma unroll
            for (int j = 0; j < 4; ++j) g[o][j] = fmaf(hid[j], w2o, g[o][j]);
        }
    }

    float out[4];
#pragma unroll
    for (int j = 0; j < 4; ++j) {
        const float ga = sigf(g[0][j]);
        const float go = sigf(g[1][j]);
        const float gn = sigf(g[2][j]);
        const float gc = sigf(g[3][j]);
        const float s1 = s1a[j], s2 = s2a[j];
        const float mx = fmaxf(s1, s2);
        const float lae = mx + __logf(1.f + __expf(-fabsf(s1 - s2)));
        out[j] = s1 + ga * s2 + go * (lae - s1) - gn * (BETA_NOT * s2) + gc * cra[j];
    }
    *(float4*)&Smix[idx] = (float4){out[0], out[1], out[2], out[3]};
}

// ---------------------------------------------------------------------------
// Fused projection: A = permute(yb1 + w*yb2) (B,H,N,DK)->(BN,D); C = A @ pwf;
// dtype-aware store straight to d_out. fp32 64x64 tile.
// ---------------------------------------------------------------------------
__global__ __launch_bounds__(256) void proj_fused(
    const float* __restrict__ yb1, const float* __restrict__ yb2,
    const float* __restrict__ pwf, const float* __restrict__ smallf,
    const void* __restrict__ xraw, void* __restrict__ out)
{
    __shared__ float As[16][68];
    __shared__ float Bs[16][68];
    __shared__ int is32s;

    const int tid = threadIdx.x;
    if (tid == 0) is32s = sniff_is_fp32(xraw);
    const float w = sigf(smallf[180]);

    const int r0 = blockIdx.y * 64;
    const int c0 = blockIdx.x * 64;
    const int tx = tid & 15, ty = tid >> 4;

    float acc[4][4] = {};

    for (int k0 = 0; k0 < Dc; k0 += 16) {
        {   // A tile with fused permute + combine (16 consecutive dk = coalesced)
            const int kk = tid & 15;
            const int rbase = tid >> 4;
            const int k = k0 + kk;
            const int h = k >> 6, dk = k & 63;
#pragma unroll
            for (int i = 0; i < 4; ++i) {
                const int row = r0 + rbase + i * 16;
                const int b = row >= Nc ? 1 : 0;
                const int n = row - b * Nc;
                const long src = (((long)b * Hc + h) * Nc + n) * DKc + dk;
                As[kk][rbase + i * 16] = yb1[src] + w * yb2[src];
            }
        }
        {
            const int cc = tid & 63;
            const int kb = tid >> 6;
#pragma unroll
            for (int i = 0; i < 4; ++i) {
                const int kk = kb + i * 4;
                Bs[kk][cc] = pwf[(long)(k0 + kk) * Dc + c0 + cc];
            }
        }
        __syncthreads();
#pragma unroll
        for (int kk = 0; kk < 16; ++kk) {
            float4 a4 = *(const float4*)&As[kk][ty * 4];
            float4 b4 = *(const float4*)&Bs[kk][tx * 4];
            float av[4] = {a4.x, a4.y, a4.z, a4.w};
            float bv[4] = {b4.x, b4.y, b4.z, b4.w};
#pragma unroll
            for (int i = 0; i < 4; ++i)
#pragma unroll
                for (int j = 0; j < 4; ++j)
                    acc[i][j] = fmaf(av[i], bv[j], acc[i][j]);
        }
        __syncthreads();
    }

    const int is32 = is32s;
#pragma unroll
    for (int i = 0; i < 4; ++i) {
        const int row = r0 + ty * 4 + i;
#pragma unroll
        for (int j = 0; j < 4; ++j) {
            const int col = c0 + tx * 4 + j;
            const long o = (long)row * Dc + col;
            if (is32) ((float*)out)[o] = acc[i][j];
            else      ((bf16*)out)[o] = __float2bfloat16(acc[i][j]);
        }
    }
}

// ---------------------------------------------------------------------------
extern "C" void kernel_launch(void* const* d_in, const int* in_sizes, int n_in,
                              void* d_out, int out_size, void* d_ws, size_t ws_size,
                              hipStream_t stream)
{
    const size_t HD   = (size_t)BHc * Nc * DKc;   // 786432
    const size_t HDh  = HD / 2;                   // float-slots for HD bf16
    const size_t MAT  = (size_t)Nc * Nc;          // 589824
    const size_t MATS = (size_t)BHc * MAT;        // 9437184
    const long   HSTR = (long)Nc * DKc;           // 49152 per-head stride

    float* ws = (float*)d_ws;
    size_t off = 0;
    auto alloc = [&](size_t n) { float* p = ws + off; off += n; return p; };

    bf16* xb  = (bf16*)alloc(HDh);
    bf16* w1b = (bf16*)alloc(HDh);   // w1b/w2b adjacent -> merged transpose
    bf16* w2b = (bf16*)alloc(HDh);
    bf16* w1t = (bf16*)alloc(HDh);
    bf16* w2t = (bf16*)alloc(HDh);
    float* pwf    = alloc((size_t)Dc * Dc);
    float* smallf = alloc(192);
    bf16* q1b = (bf16*)alloc(HDh); bf16* k1b = (bf16*)alloc(HDh);
    bf16* q2b = (bf16*)alloc(HDh); bf16* k2b = (bf16*)alloc(HDh);
    bf16* v1b = (bf16*)alloc(HDh); bf16* v2b = (bf16*)alloc(HDh);  // adjacent
    bf16* v1t = (bf16*)alloc(HDh); bf16* v2t = (bf16*)alloc(HDh);  // adjacent
    bf16* trb = (bf16*)alloc(HDh);
    bf16* trt = (bf16*)alloc(HDh);
    float* S1   = alloc(MATS);       // S1/S2 adjacent -> merged softmax
    float* S2   = alloc(MATS);
    float* Smix = alloc(MATS);
    bf16* A1b = (bf16*)alloc(MATS / 2);  // A1b/A2b adjacent
    bf16* A2b = (bf16*)alloc(MATS / 2);
    bf16* Crb = (bf16*)alloc(MATS / 2);
    bf16* Clb = (bf16*)alloc(MATS / 2);
    float* yb1 = alloc(HD);
    float* yb2 = alloc(HD);

    // aliases into dead regions
    bf16* A1tb = (bf16*)Smix;            // dead until gates writes Smix
    bf16* A2tb = ((bf16*)Smix) + MATS;   // A1tb/A2tb adjacent
    bf16* Ab   = (bf16*)S1;              // S1 dead after gates

    const size_t NEED_BYTES = off * sizeof(float);
    if (ws_size < NEED_BYTES) {
        fill_sentinel<<<dim3(3072), 256, 0, stream>>>((unsigned short*)d_out);
        return;
    }

    // 0. normalize inputs
    convert_all<<<dim3(3072), 256, 0, stream>>>(
        d_in[0], d_in[1], d_in[2], d_in[3], d_in[4], d_in[5], d_in[6], d_in[7],
        d_in[8], xb, w1b, w2b, pwf, smallf);

    // 1. merged W transposes; merged QKV (z = set); merged v transposes
    transpose_bf16<<<dim3(24, 8, 2), 256, 0, stream>>>(
        (const unsigned short*)w1b, (unsigned short*)w1t, Dc, 3 * Dc, (long)HD, (long)HD);
    qkv_mfma<<<dim3(12, 12, 2), 256, 0, stream>>>(
        xb, w1t, w2t, q1b, k1b, v1b, q2b, k2b, v2b);
    transpose_bf16<<<dim3(1, 12, 2 * BHc), 256, 0, stream>>>(
        (const unsigned short*)v1b, (unsigned short*)v1t, Nc, DKc, HSTR, HSTR);

    // 2. S = scale * q @ k^T per head (MFMA, fp32 out)
    gemm_nt_mfma<0, float><<<dim3(6, 6, BHc), 256, 0, stream>>>(
        q1b, k1b, S1, Nc, Nc, DKc, HSTR, HSTR, (long)MAT, SCALE);
    gemm_nt_mfma<0, float><<<dim3(6, 6, BHc), 256, 0, stream>>>(
        q2b, k2b, S2, Nc, Nc, DKc, HSTR, HSTR, (long)MAT, SCALE);

    // 3. merged softmax over S1|S2 -> A1b|A2b; merged transposes -> A1tb|A2tb
    softmax_rows<bf16><<<2 * BHc * Nc, 256, 0, stream>>>(S1, A1b);
    transpose_bf16<<<dim3(12, 12, 2 * BHc), 256, 0, stream>>>(
        (const unsigned short*)A1b, (unsigned short*)A1tb, Nc, Nc, (long)MAT, (long)MAT);

    // 4. Cr/Cl via bf16 MFMA + log epilogue
    gemm_nt_mfma<1, bf16><<<dim3(6, 6, BHc), 256, 0, stream>>>(
        A1b, A2tb, Crb, Nc, Nc, Nc, (long)MAT, (long)MAT, (long)MAT, 1.f);
    gemm_nt_mfma<1, bf16><<<dim3(6, 6, BHc), 256, 0, stream>>>(
        A2b, A1tb, Clb, Nc, Nc, Nc, (long)MAT, (long)MAT, (long)MAT, 1.f);

    // 5. gates + Smix
    gates_smix<<<dim3(12, 48, BHc), 256, 0, stream>>>(S1, S2, Crb, Clb, Smix, smallf);

    // 6. A = softmax(Smix) -> bf16 (into S1 alias)
    softmax_rows<bf16><<<BHc * Nc, 256, 0, stream>>>(Smix, Ab);

    // 7. transport = A2 @ v2, transpose for next NT GEMM
    gemm_nt_n64<bf16><<<dim3(1, 6, BHc), 256, 0, stream>>>(
        A2b, v2t, trb, Nc, Nc, (long)MAT, HSTR, HSTR);
    transpose_bf16<<<dim3(1, 12, BHc), 256, 0, stream>>>(
        (const unsigned short*)trb, (unsigned short*)trt, Nc, DKc, HSTR, HSTR);

    // 8. y_base = A @ v1 ; y_chain = A1 @ transport
    gemm_nt_n64<float><<<dim3(1, 6, BHc), 256, 0, stream>>>(
        Ab, v1t, yb1, Nc, Nc, (long)MAT, HSTR, HSTR);
    gemm_nt_n64<float><<<dim3(1, 6, BHc), 256, 0, stream>>>(
        A1b, trt, yb2, Nc, Nc, (long)MAT, HSTR, HSTR);

    // 9+10. fused combine + permute + proj + dtype-aware store
    proj_fused<<<dim3(8, 24, 1), 256, 0, stream>>>(
        yb1, yb2, pwf, smallf, d_in[0], d_out);
}

// Round 7
// 562.705 us; speedup vs baseline: 1.1987x; 1.0545x over previous
//
#include <hip/hip_runtime.h>
#include <hip/hip_bf16.h>
#include <math.h>

typedef __hip_bfloat16 bf16;
typedef __attribute__((ext_vector_type(8))) short short8;   // 8 bf16 (4 VGPRs)
typedef __attribute__((ext_vector_type(4))) float f32x4;
#define DEVINL __device__ __forceinline__

constexpr int Bc  = 2;
constexpr int Nc  = 768;
constexpr int Dc  = 512;
constexpr int Hc  = 8;
constexpr int DKc = 64;
constexpr int BHc = Bc * Hc;
constexpr float SCALE    = 0.125f;   // 1/sqrt(64)
constexpr float EPSF     = 1e-6f;
constexpr float BETA_NOT = 0.5f;

DEVINL float ldf(const float* p, long i) { return p[i]; }
DEVINL float ldf(const bf16* p, long i) { return __bfloat162float(p[i]); }
DEVINL void stf(float* p, long i, float v) { p[i] = v; }
DEVINL void stf(bf16* p, long i, float v) { p[i] = __float2bfloat16(v); }

DEVINL float sigf(float x) { return __fdividef(1.f, 1.f + __expf(-x)); }

// async global->LDS, 16B per lane; LDS dest = wave-uniform base + lane*16.
DEVINL void gl_lds16(const void* g, void* l) {
    __builtin_amdgcn_global_load_lds(
        (const __attribute__((address_space(1))) void*)g,
        (__attribute__((address_space(3))) void*)l, 16, 0, 0);
}

// ---------------------------------------------------------------------------
// Dtype sniffer (round-1 notes). Deterministic per launch.
// ---------------------------------------------------------------------------
DEVINL int sniff_is_fp32(const void* xraw) {
    const unsigned short* p = (const unsigned short*)xraw;
    float mx = 0.f;
#pragma unroll 1
    for (int j = 0; j < 128; ++j) {
        float v = __uint_as_float(((unsigned)p[j]) << 16);
        mx = fmaxf(mx, fabsf(v));
    }
    return mx > 1000.f ? 1 : 0;
}

DEVINL float cvt_elem(const void* s, long j, int is32) {
    return is32 ? ((const float*)s)[j]
                : __bfloat162float(((const bf16*)s)[j]);
}

__global__ __launch_bounds__(256) void convert_all(
    const void* x, const void* w1, const void* w2, const void* pw,
    const void* c1w, const void* c1b, const void* c2w, const void* c2b,
    const void* ch,
    bf16* xb, bf16* w1b, bf16* w2b, bf16* pwb, float* smallf)
{
    const int is32 = sniff_is_fp32(x);
    const long i = (long)blockIdx.x * 256 + threadIdx.x;
    if (i < (long)Bc * Nc * Dc) {
        xb[i]  = __float2bfloat16(cvt_elem(x,  i, is32));
        w1b[i] = __float2bfloat16(cvt_elem(w1, i, is32));
        w2b[i] = __float2bfloat16(cvt_elem(w2, i, is32));
    }
    if (i < (long)Dc * Dc) pwb[i] = __float2bfloat16(cvt_elem(pw, i, is32));
    if (i < 96)       smallf[i] = cvt_elem(c1w, i,        is32);
    else if (i < 112) smallf[i] = cvt_elem(c1b, i - 96,   is32);
    else if (i < 176) smallf[i] = cvt_elem(c2w, i - 112,  is32);
    else if (i < 180) smallf[i] = cvt_elem(c2b, i - 176,  is32);
    else if (i == 180) smallf[180] = cvt_elem(ch, 0, is32);
}

__global__ __launch_bounds__(256) void fill_sentinel(unsigned short* o) {
    const long i = (long)blockIdx.x * 256 + threadIdx.x;
    if (i < (long)Bc * Nc * Dc) o[i] = 0x40E0;  // bf16 7.0
}

// ---------------------------------------------------------------------------
// Generic bf16 transpose, 64x64 tiles: dst[c][r] = src[r][c]; src is (R,C).
// ---------------------------------------------------------------------------
__global__ __launch_bounds__(256) void transpose_bf16(
    const unsigned short* __restrict__ src, unsigned short* __restrict__ dst,
    int R, int C, long sS, long sD)
{
    __shared__ unsigned short tile[64][68];
    const unsigned short* s = src + (long)blockIdx.z * sS;
    unsigned short* d = dst + (long)blockIdx.z * sD;
    const int r0 = blockIdx.y * 64, c0 = blockIdx.x * 64;
    const int t = threadIdx.x;
    const int lr = t >> 4, lc4 = (t & 15) * 4;
#pragma unroll
    for (int i = 0; i < 4; ++i) {
        int r = lr + i * 16;
        *(uint2*)&tile[r][lc4] = *(const uint2*)&s[(long)(r0 + r) * C + c0 + lc4];
    }
    __syncthreads();
#pragma unroll
    for (int i = 0; i < 4; ++i) {
        int r = lr + i * 16;
        unsigned short v[4];
#pragma unroll
        for (int j = 0; j < 4; ++j) v[j] = tile[lc4 + j][r];
        *(uint2*)&d[(long)(c0 + r) * R + r0 + lc4] = *(uint2*)v;
    }
}

// ---------------------------------------------------------------------------
// MFMA bf16 NT GEMM with global_load_lds staging (validated round 6):
// C = A(M,K) @ Bt(N,K)^T. 128x128 tile, BK=32.
// ---------------------------------------------------------------------------
template <int EPI, typename TC>
__global__ __launch_bounds__(256) void gemm_nt_mfma(
    const bf16* __restrict__ Ag, const bf16* __restrict__ Btg,
    TC* __restrict__ Cg, int M, int N, int K,
    long sA, long sB, long sC, float alpha)
{
    __shared__ unsigned short Asm[128 * 32];
    __shared__ unsigned short Bsm[128 * 32];

    const int tid  = threadIdx.x;
    const int wv   = tid >> 6;
    const int lane = tid & 63;
    const int q    = lane >> 4;
    const int ln   = lane & 15;
    const int wm   = wv & 1;
    const int wn   = wv >> 1;

    const bf16* A  = Ag  + (long)blockIdx.z * sA + (long)(blockIdx.y * 128) * K;
    const bf16* Bt = Btg + (long)blockIdx.z * sB + (long)(blockIdx.x * 128) * K;
    TC*         C  = Cg  + (long)blockIdx.z * sC;

    const int sr = lane >> 2, sc = lane & 3;
    const bf16* gA0 = A  + (long)(wv * 32 + sr)      * K + sc * 8;
    const bf16* gA1 = A  + (long)(wv * 32 + 16 + sr) * K + sc * 8;
    const bf16* gB0 = Bt + (long)(wv * 32 + sr)      * K + sc * 8;
    const bf16* gB1 = Bt + (long)(wv * 32 + 16 + sr) * K + sc * 8;
    unsigned short* lA0 = &Asm[(wv * 32)      * 32];
    unsigned short* lA1 = &Asm[(wv * 32 + 16) * 32];
    unsigned short* lB0 = &Bsm[(wv * 32)      * 32];
    unsigned short* lB1 = &Bsm[(wv * 32 + 16) * 32];

    f32x4 acc[4][4];
#pragma unroll
    for (int i = 0; i < 4; ++i)
#pragma unroll
        for (int j = 0; j < 4; ++j)
            acc[i][j] = (f32x4){0.f, 0.f, 0.f, 0.f};

    for (int k0 = 0; k0 < K; k0 += 32) {
        __syncthreads();
        gl_lds16(gA0 + k0, lA0);
        gl_lds16(gA1 + k0, lA1);
        gl_lds16(gB0 + k0, lB0);
        gl_lds16(gB1 + k0, lB1);
        __syncthreads();

        short8 af[4], bfr[4];
#pragma unroll
        for (int mt = 0; mt < 4; ++mt) {
            int m = wm * 64 + mt * 16 + ln;
            af[mt] = *(const short8*)&Asm[m * 32 + q * 8];
        }
#pragma unroll
        for (int nt = 0; nt < 4; ++nt) {
            int n = wn * 64 + nt * 16 + ln;
            bfr[nt] = *(const short8*)&Bsm[n * 32 + q * 8];
        }
#pragma unroll
        for (int mt = 0; mt < 4; ++mt)
#pragma unroll
            for (int nt = 0; nt < 4; ++nt)
                acc[mt][nt] = __builtin_amdgcn_mfma_f32_16x16x32_bf16(
                    af[mt], bfr[nt], acc[mt][nt], 0, 0, 0);
    }

#pragma unroll
    for (int mt = 0; mt < 4; ++mt) {
#pragma unroll
        for (int nt = 0; nt < 4; ++nt) {
            const int col = blockIdx.x * 128 + wn * 64 + nt * 16 + ln;
            const int rowb = blockIdx.y * 128 + wm * 64 + mt * 16 + q * 4;
#pragma unroll
            for (int r = 0; r < 4; ++r) {
                float v = acc[mt][nt][r] * alpha;
                if (EPI == 1) v = __logf(fmaxf(v, 0.f) + EPSF);
                stf(C, (long)(rowb + r) * N + col, v);
            }
        }
    }
}

// ---------------------------------------------------------------------------
// QKV via MFMA, merged sets (validated round 6).
// ---------------------------------------------------------------------------
__global__ __launch_bounds__(256) void qkv_mfma(
    const bf16* __restrict__ X,
    const bf16* __restrict__ w1t, const bf16* __restrict__ w2t,
    bf16* __restrict__ q1, bf16* __restrict__ k1, bf16* __restrict__ v1,
    bf16* __restrict__ q2, bf16* __restrict__ k2, bf16* __restrict__ v2)
{
    constexpr int K = Dc;  // 512
    __shared__ unsigned short Asm[128 * 32];
    __shared__ unsigned short Bsm[128 * 32];

    const int tid  = threadIdx.x;
    const int wv   = tid >> 6;
    const int lane = tid & 63;
    const int q    = lane >> 4;
    const int ln   = lane & 15;
    const int wm   = wv & 1;
    const int wn   = wv >> 1;
    const int set  = blockIdx.z;

    const bf16* Wt = set ? w2t : w1t;
    bf16* Q  = set ? q2 : q1;
    bf16* Ko = set ? k2 : k1;
    bf16* V  = set ? v2 : v1;

    const bf16* A  = X  + (long)(blockIdx.y * 128) * K;
    const bf16* Bt = Wt + (long)(blockIdx.x * 128) * K;

    const int sr = lane >> 2, sc = lane & 3;
    const bf16* gA0 = A  + (long)(wv * 32 + sr)      * K + sc * 8;
    const bf16* gA1 = A  + (long)(wv * 32 + 16 + sr) * K + sc * 8;
    const bf16* gB0 = Bt + (long)(wv * 32 + sr)      * K + sc * 8;
    const bf16* gB1 = Bt + (long)(wv * 32 + 16 + sr) * K + sc * 8;
    unsigned short* lA0 = &Asm[(wv * 32)      * 32];
    unsigned short* lA1 = &Asm[(wv * 32 + 16) * 32];
    unsigned short* lB0 = &Bsm[(wv * 32)      * 32];
    unsigned short* lB1 = &Bsm[(wv * 32 + 16) * 32];

    f32x4 acc[4][4];
#pragma unroll
    for (int i = 0; i < 4; ++i)
#pragma unroll
        for (int j = 0; j < 4; ++j)
            acc[i][j] = (f32x4){0.f, 0.f, 0.f, 0.f};

    for (int k0 = 0; k0 < K; k0 += 32) {
        __syncthreads();
        gl_lds16(gA0 + k0, lA0);
        gl_lds16(gA1 + k0, lA1);
        gl_lds16(gB0 + k0, lB0);
        gl_lds16(gB1 + k0, lB1);
        __syncthreads();

        short8 af[4], bfr[4];
#pragma unroll
        for (int mt = 0; mt < 4; ++mt) {
            int m = wm * 64 + mt * 16 + ln;
            af[mt] = *(const short8*)&Asm[m * 32 + q * 8];
        }
#pragma unroll
        for (int nt = 0; nt < 4; ++nt) {
            int n = wn * 64 + nt * 16 + ln;
            bfr[nt] = *(const short8*)&Bsm[n * 32 + q * 8];
        }
#pragma unroll
        for (int mt = 0; mt < 4; ++mt)
#pragma unroll
            for (int nt = 0; nt < 4; ++nt)
                acc[mt][nt] = __builtin_amdgcn_mfma_f32_16x16x32_bf16(
                    af[mt], bfr[nt], acc[mt][nt], 0, 0, 0);
    }

#pragma unroll
    for (int mt = 0; mt < 4; ++mt) {
#pragma unroll
        for (int nt = 0; nt < 4; ++nt) {
            const int col  = blockIdx.x * 128 + wn * 64 + nt * 16 + ln;
            const int rowb = blockIdx.y * 128 + wm * 64 + mt * 16 + q * 4;
            const int t = col >> 9;
            const int h = (col >> 6) & 7;
            const int dk = col & 63;
            bf16* dst = (t == 0) ? Q : (t == 1) ? Ko : V;
#pragma unroll
            for (int r = 0; r < 4; ++r) {
                const int row = rowb + r;
                const int b = row >= Nc ? 1 : 0;
                const int n = row - b * Nc;
                dst[(((long)b * Hc + h) * Nc + n) * DKc + dk] =
                    __float2bfloat16(acc[mt][nt][r]);
            }
        }
    }
}

// ---------------------------------------------------------------------------
// MFMA bf16 NT GEMM, narrow (validated): C(M,64) = A(M,K) @ Bt(64,K)^T.
// ---------------------------------------------------------------------------
template <typename TC>
__global__ __launch_bounds__(256) void gemm_nt_n64(
    const bf16* __restrict__ Ag, const bf16* __restrict__ Btg,
    TC* __restrict__ Cg, int M, int K, long sA, long sB, long sC)
{
    __shared__ unsigned short Asm[128 * 72];
    __shared__ unsigned short Bsm[64 * 72];

    const int tid  = threadIdx.x;
    const int wave = tid >> 6;
    const int lane = tid & 63;
    const int q    = lane >> 4;
    const int ln   = lane & 15;

    const bf16* A  = Ag  + (long)blockIdx.z * sA + (long)(blockIdx.y * 128) * K;
    const bf16* Bt = Btg + (long)blockIdx.z * sB;
    TC*         C  = Cg  + (long)blockIdx.z * sC;

    const int sr = tid >> 3, k8 = tid & 7;
    const bf16* pa[4];
    const bf16* pb[2];
    int wa[4], wb[2];
#pragma unroll
    for (int i = 0; i < 4; ++i) {
        pa[i] = A + (long)(sr + i * 32) * K + k8 * 8;
        wa[i] = (sr + i * 32) * 72 + k8 * 8;
    }
#pragma unroll
    for (int i = 0; i < 2; ++i) {
        pb[i] = Bt + (long)(sr + i * 32) * K + k8 * 8;
        wb[i] = (sr + i * 32) * 72 + k8 * 8;
    }

    f32x4 acc[2][4];
#pragma unroll
    for (int i = 0; i < 2; ++i)
#pragma unroll
        for (int j = 0; j < 4; ++j)
            acc[i][j] = (f32x4){0.f, 0.f, 0.f, 0.f};

    for (int k0 = 0; k0 < K; k0 += 64) {
        uint4 va[4], vb[2];
#pragma unroll
        for (int i = 0; i < 4; ++i) va[i] = *(const uint4*)(pa[i] + k0);
#pragma unroll
        for (int i = 0; i < 2; ++i) vb[i] = *(const uint4*)(pb[i] + k0);
        __syncthreads();
#pragma unroll
        for (int i = 0; i < 4; ++i) *(uint4*)&Asm[wa[i]] = va[i];
#pragma unroll
        for (int i = 0; i < 2; ++i) *(uint4*)&Bsm[wb[i]] = vb[i];
        __syncthreads();

#pragma unroll
        for (int kc = 0; kc < 2; ++kc) {
            short8 af[2], bfr[4];
#pragma unroll
            for (int mt = 0; mt < 2; ++mt) {
                int m = wave * 32 + mt * 16 + ln;
                af[mt] = *(const short8*)&Asm[m * 72 + kc * 32 + q * 8];
            }
#pragma unroll
            for (int nt = 0; nt < 4; ++nt) {
                int n = nt * 16 + ln;
                bfr[nt] = *(const short8*)&Bsm[n * 72 + kc * 32 + q * 8];
            }
#pragma unroll
            for (int mt = 0; mt < 2; ++mt)
#pragma unroll
                for (int nt = 0; nt < 4; ++nt)
                    acc[mt][nt] = __builtin_amdgcn_mfma_f32_16x16x32_bf16(
                        af[mt], bfr[nt], acc[mt][nt], 0, 0, 0);
        }
    }

#pragma unroll
    for (int mt = 0; mt < 2; ++mt) {
#pragma unroll
        for (int nt = 0; nt < 4; ++nt) {
            const int col  = nt * 16 + ln;
            const int rowb = blockIdx.y * 128 + wave * 32 + mt * 16 + q * 4;
#pragma unroll
            for (int r = 0; r < 4; ++r)
                stf(C, (long)(rowb + r) * 64 + col, acc[mt][nt][r]);
        }
    }
}

// ---------------------------------------------------------------------------
// Row softmax over width 768 (validated).
// ---------------------------------------------------------------------------
template <typename TO>
__global__ __launch_bounds__(256) void softmax_rows(const float* src, TO* dst)
{
    __shared__ float red[4];
    const long row = blockIdx.x;
    const float* s = src + row * Nc;
    TO* d = dst + row * Nc;
    const int tid = threadIdx.x;

    float v[3];
    float m = -1e30f;
#pragma unroll
    for (int i = 0; i < 3; ++i) { v[i] = s[tid + i * 256]; m = fmaxf(m, v[i]); }

#pragma unroll
    for (int off = 32; off > 0; off >>= 1) m = fmaxf(m, __shfl_down(m, off, 64));
    if ((tid & 63) == 0) red[tid >> 6] = m;
    __syncthreads();
    if (tid == 0) {
        float mm = red[0];
        for (int w = 1; w < 4; ++w) mm = fmaxf(mm, red[w]);
        red[0] = mm;
    }
    __syncthreads();
    m = red[0];
    __syncthreads();

    float e[3];
    float sum = 0.f;
#pragma unroll
    for (int i = 0; i < 3; ++i) { e[i] = __expf(v[i] - m); sum += e[i]; }
#pragma unroll
    for (int off = 32; off > 0; off >>= 1) sum += __shfl_down(sum, off, 64);
    if ((tid & 63) == 0) red[tid >> 6] = sum;
    __syncthreads();
    if (tid == 0) red[0] = red[0] + red[1] + red[2] + red[3];
    __syncthreads();
    const float inv = 1.f / fmaxf(red[0], 1e-30f);
#pragma unroll
    for (int i = 0; i < 3; ++i) stf(d, tid + i * 256, e[i] * inv);
}

// ---------------------------------------------------------------------------
// Gate network + Smix — EXACT round-3 version (152 µs measured: 1 elem/thread,
// LDS weights, VGPR~28, occupancy ~80%). Rounds 4-6 ILP/s_load variants were
// 162-184 µs: occupancy loss beats ILP gain for this exp-heavy body.
// ---------------------------------------------------------------------------
__global__ __launch_bounds__(256) void gates_smix(
    const float* __restrict__ S1g, const float* __restrict__ S2g,
    const bf16* __restrict__ Crg, const bf16* __restrict__ Clg,
    float* __restrict__ Smixg, const float* __restrict__ smallf)
{
    __shared__ float t1t[16][17], t2t[16][17];
    __shared__ float cs[192];

    const int bh = blockIdx.z;
    const long mat = (long)bh * Nc * Nc;
    const float* S1 = S1g + mat;
    const float* S2 = S2g + mat;
    const bf16*  Cr = Crg + mat;
    const bf16*  Cl = Clg + mat;
    float* Smix = Smixg + mat;

    const int tid = threadIdx.x;
    if (tid < 192) cs[tid] = smallf[tid];

    const int n0 = blockIdx.y * 16, m0 = blockIdx.x * 16;
    const int tx = tid & 15, ty = tid >> 4;

    t1t[ty][tx] = S1[(long)(m0 + ty) * Nc + n0 + tx];
    t2t[ty][tx] = S2[(long)(m0 + ty) * Nc + n0 + tx];
    __syncthreads();

    const float* cw1 = cs;       const float* cb1 = cs + 96;
    const float* cw2 = cs + 112; const float* cb2 = cs + 176;

    const int n = n0 + ty, mcol = m0 + tx;
    const long idx = (long)n * Nc + mcol;
    const float s1 = S1[idx], s2 = S2[idx];
    const float s1t = t1t[tx][ty], s2t = t2t[tx][ty];
    const float cr = __bfloat162float(Cr[idx]), cl = __bfloat162float(Cl[idx]);

    const float feat[6] = {s1, s2, s1t, s2t, cr, cl};
    float g[4];
#pragma unroll
    for (int o = 0; o < 4; ++o) g[o] = cb2[o];

#pragma unroll
    for (int c16 = 0; c16 < 16; ++c16) {
        float h = cb1[c16];
#pragma unroll
        for (int c = 0; c < 6; ++c) h = fmaf(feat[c], cw1[c16 * 6 + c], h);
        float targ = 0.7978845608028654f * (h + 0.044715f * h * h * h);
        targ = fminf(fmaxf(targ, -15.f), 15.f);
        float e2 = __expf(2.f * targ);
        float th = (e2 - 1.f) / (e2 + 1.f);
        float hid = 0.5f * h * (1.f + th);
#pragma unroll
        for (int o = 0; o < 4; ++o) g[o] = fmaf(hid, cw2[o * 16 + c16], g[o]);
    }
#pragma unroll
    for (int o = 0; o < 4; ++o) g[o] = 1.f / (1.f + __expf(-g[o]));

    const float mx = fmaxf(s1, s2);
    const float lae = mx + __logf(1.f + __expf(-fabsf(s1 - s2)));
    Smix[idx] = s1 + g[0] * s2 + g[1] * (lae - s1) - g[2] * (BETA_NOT * s2) + g[3] * cr;
}

// ---------------------------------------------------------------------------
// y = y_base + sigmoid(chain)*y_chain, (b,h,n,dk) -> (b,n,h*dk), bf16 in/out.
// ---------------------------------------------------------------------------
__global__ __launch_bounds__(256) void combine_y(
    const bf16* __restrict__ y1, const bf16* __restrict__ y2,
    const float* __restrict__ smallf, bf16* __restrict__ y)
{
    const long i = (long)blockIdx.x * 256 + threadIdx.x;
    const int dk = (int)(i & 63);
    const long t = i >> 6;
    const int n = (int)(t % Nc);
    const long t2 = t / Nc;
    const int h = (int)(t2 & 7);
    const int b = (int)(t2 >> 3);
    const float w = 1.f / (1.f + __expf(-smallf[180]));
    const float v = __bfloat162float(y1[i]) + w * __bfloat162float(y2[i]);
    y[((long)(b * Nc + n)) * Dc + h * DKc + dk] = __float2bfloat16(v);
}

// ---------------------------------------------------------------------------
// Final projection via MFMA: out = yc(1536,512) @ pwt(512,512)^T(NT), with
// dtype-aware store to d_out. Same 128-tile gl_lds engine.
// ---------------------------------------------------------------------------
__global__ __launch_bounds__(256) void proj_mfma(
    const bf16* __restrict__ yc, const bf16* __restrict__ pwt,
    const void* __restrict__ xraw, void* __restrict__ out)
{
    constexpr int K = Dc;  // 512
    constexpr int N = Dc;  // 512
    __shared__ unsigned short Asm[128 * 32];
    __shared__ unsigned short Bsm[128 * 32];
    __shared__ int is32s;

    const int tid  = threadIdx.x;
    if (tid == 0) is32s = sniff_is_fp32(xraw);
    const int wv   = tid >> 6;
    const int lane = tid & 63;
    const int q    = lane >> 4;
    const int ln   = lane & 15;
    const int wm   = wv & 1;
    const int wn   = wv >> 1;

    const bf16* A  = yc  + (long)(blockIdx.y * 128) * K;
    const bf16* Bt = pwt + (long)(blockIdx.x * 128) * K;

    const int sr = lane >> 2, sc = lane & 3;
    const bf16* gA0 = A  + (long)(wv * 32 + sr)      * K + sc * 8;
    const bf16* gA1 = A  + (long)(wv * 32 + 16 + sr) * K + sc * 8;
    const bf16* gB0 = Bt + (long)(wv * 32 + sr)      * K + sc * 8;
    const bf16* gB1 = Bt + (long)(wv * 32 + 16 + sr) * K + sc * 8;
    unsigned short* lA0 = &Asm[(wv * 32)      * 32];
    unsigned short* lA1 = &Asm[(wv * 32 + 16) * 32];
    unsigned short* lB0 = &Bsm[(wv * 32)      * 32];
    unsigned short* lB1 = &Bsm[(wv * 32 + 16) * 32];

    f32x4 acc[4][4];
#pragma unroll
    for (int i = 0; i < 4; ++i)
#pragma unroll
        for (int j = 0; j < 4; ++j)
            acc[i][j] = (f32x4){0.f, 0.f, 0.f, 0.f};

    for (int k0 = 0; k0 < K; k0 += 32) {
        __syncthreads();
        gl_lds16(gA0 + k0, lA0);
        gl_lds16(gA1 + k0, lA1);
        gl_lds16(gB0 + k0, lB0);
        gl_lds16(gB1 + k0, lB1);
        __syncthreads();

        short8 af[4], bfr[4];
#pragma unroll
        for (int mt = 0; mt < 4; ++mt) {
            int m = wm * 64 + mt * 16 + ln;
            af[mt] = *(const short8*)&Asm[m * 32 + q * 8];
        }
#pragma unroll
        for (int nt = 0; nt < 4; ++nt) {
            int n = wn * 64 + nt * 16 + ln;
            bfr[nt] = *(const short8*)&Bsm[n * 32 + q * 8];
        }
#pragma unroll
        for (int mt = 0; mt < 4; ++mt)
#pragma unroll
            for (int nt = 0; nt < 4; ++nt)
                acc[mt][nt] = __builtin_amdgcn_mfma_f32_16x16x32_bf16(
                    af[mt], bfr[nt], acc[mt][nt], 0, 0, 0);
    }

    const int is32 = is32s;
#pragma unroll
    for (int mt = 0; mt < 4; ++mt) {
#pragma unroll
        for (int nt = 0; nt < 4; ++nt) {
            const int col = blockIdx.x * 128 + wn * 64 + nt * 16 + ln;
            const int rowb = blockIdx.y * 128 + wm * 64 + mt * 16 + q * 4;
#pragma unroll
            for (int r = 0; r < 4; ++r) {
                const long o = (long)(rowb + r) * N + col;
                if (is32) ((float*)out)[o] = acc[mt][nt][r];
                else      ((bf16*)out)[o] = __float2bfloat16(acc[mt][nt][r]);
            }
        }
    }
}

// ---------------------------------------------------------------------------
extern "C" void kernel_launch(void* const* d_in, const int* in_sizes, int n_in,
                              void* d_out, int out_size, void* d_ws, size_t ws_size,
                              hipStream_t stream)
{
    const size_t HD   = (size_t)BHc * Nc * DKc;   // 786432
    const size_t HDh  = HD / 2;                   // float-slots for HD bf16
    const size_t MAT  = (size_t)Nc * Nc;          // 589824
    const size_t MATS = (size_t)BHc * MAT;        // 9437184
    const long   HSTR = (long)Nc * DKc;           // 49152 per-head stride

    float* ws = (float*)d_ws;
    size_t off = 0;
    auto alloc = [&](size_t n) { float* p = ws + off; off += n; return p; };

    bf16* xb  = (bf16*)alloc(HDh);
    bf16* w1b = (bf16*)alloc(HDh);   // w1b/w2b adjacent -> merged transpose
    bf16* w2b = (bf16*)alloc(HDh);
    bf16* w1t = (bf16*)alloc(HDh);
    bf16* w2t = (bf16*)alloc(HDh);
    bf16* pwb = (bf16*)alloc((size_t)Dc * Dc / 2);
    bf16* pwt = (bf16*)alloc((size_t)Dc * Dc / 2);
    float* smallf = alloc(192);
    bf16* q1b = (bf16*)alloc(HDh); bf16* k1b = (bf16*)alloc(HDh);
    bf16* q2b = (bf16*)alloc(HDh); bf16* k2b = (bf16*)alloc(HDh);
    bf16* v1b = (bf16*)alloc(HDh); bf16* v2b = (bf16*)alloc(HDh);  // adjacent
    bf16* v1t = (bf16*)alloc(HDh); bf16* v2t = (bf16*)alloc(HDh);  // adjacent
    bf16* trb = (bf16*)alloc(HDh);
    bf16* trt = (bf16*)alloc(HDh);
    float* S1   = alloc(MATS);       // S1/S2 adjacent -> merged softmax
    float* S2   = alloc(MATS);
    float* Smix = alloc(MATS);
    bf16* A1b = (bf16*)alloc(MATS / 2);  // A1b/A2b adjacent
    bf16* A2b = (bf16*)alloc(MATS / 2);
    bf16* Crb = (bf16*)alloc(MATS / 2);
    bf16* Clb = (bf16*)alloc(MATS / 2);
    bf16* yb1 = (bf16*)alloc(HDh);
    bf16* yb2 = (bf16*)alloc(HDh);
    bf16* yc  = (bf16*)alloc(HDh);

    // aliases into dead regions
    bf16* A1tb = (bf16*)Smix;            // dead until gates writes Smix
    bf16* A2tb = ((bf16*)Smix) + MATS;   // A1tb/A2tb adjacent
    bf16* Ab   = (bf16*)S1;              // S1 dead after gates

    const size_t NEED_BYTES = off * sizeof(float);
    if (ws_size < NEED_BYTES) {
        fill_sentinel<<<dim3(3072), 256, 0, stream>>>((unsigned short*)d_out);
        return;
    }

    // 0. normalize inputs
    convert_all<<<dim3(3072), 256, 0, stream>>>(
        d_in[0], d_in[1], d_in[2], d_in[3], d_in[4], d_in[5], d_in[6], d_in[7],
        d_in[8], xb, w1b, w2b, pwb, smallf);

    // 1. merged W transposes; pw transpose; merged QKV; merged v transposes
    transpose_bf16<<<dim3(24, 8, 2), 256, 0, stream>>>(
        (const unsigned short*)w1b, (unsigned short*)w1t, Dc, 3 * Dc, (long)HD, (long)HD);
    transpose_bf16<<<dim3(8, 8, 1), 256, 0, stream>>>(
        (const unsigned short*)pwb, (unsigned short*)pwt, Dc, Dc, 0, 0);
    qkv_mfma<<<dim3(12, 12, 2), 256, 0, stream>>>(
        xb, w1t, w2t, q1b, k1b, v1b, q2b, k2b, v2b);
    transpose_bf16<<<dim3(1, 12, 2 * BHc), 256, 0, stream>>>(
        (const unsigned short*)v1b, (unsigned short*)v1t, Nc, DKc, HSTR, HSTR);

    // 2. S = scale * q @ k^T per head (MFMA, fp32 out)
    gemm_nt_mfma<0, float><<<dim3(6, 6, BHc), 256, 0, stream>>>(
        q1b, k1b, S1, Nc, Nc, DKc, HSTR, HSTR, (long)MAT, SCALE);
    gemm_nt_mfma<0, float><<<dim3(6, 6, BHc), 256, 0, stream>>>(
        q2b, k2b, S2, Nc, Nc, DKc, HSTR, HSTR, (long)MAT, SCALE);

    // 3. merged softmax S1|S2 -> A1b|A2b; merged transposes -> A1tb|A2tb
    softmax_rows<bf16><<<2 * BHc * Nc, 256, 0, stream>>>(S1, A1b);
    transpose_bf16<<<dim3(12, 12, 2 * BHc), 256, 0, stream>>>(
        (const unsigned short*)A1b, (unsigned short*)A1tb, Nc, Nc, (long)MAT, (long)MAT);

    // 4. Cr/Cl via bf16 MFMA + log epilogue
    gemm_nt_mfma<1, bf16><<<dim3(6, 6, BHc), 256, 0, stream>>>(
        A1b, A2tb, Crb, Nc, Nc, Nc, (long)MAT, (long)MAT, (long)MAT, 1.f);
    gemm_nt_mfma<1, bf16><<<dim3(6, 6, BHc), 256, 0, stream>>>(
        A2b, A1tb, Clb, Nc, Nc, Nc, (long)MAT, (long)MAT, (long)MAT, 1.f);

    // 5. gates + Smix (round-3 exact kernel)
    gates_smix<<<dim3(48, 48, BHc), 256, 0, stream>>>(S1, S2, Crb, Clb, Smix, smallf);

    // 6. A = softmax(Smix) -> bf16 (into S1 alias)
    softmax_rows<bf16><<<BHc * Nc, 256, 0, stream>>>(Smix, Ab);

    // 7. transport = A2 @ v2, transpose for next NT GEMM
    gemm_nt_n64<bf16><<<dim3(1, 6, BHc), 256, 0, stream>>>(
        A2b, v2t, trb, Nc, Nc, (long)MAT, HSTR, HSTR);
    transpose_bf16<<<dim3(1, 12, BHc), 256, 0, stream>>>(
        (const unsigned short*)trb, (unsigned short*)trt, Nc, DKc, HSTR, HSTR);

    // 8. y_base = A @ v1 ; y_chain = A1 @ transport (bf16 out)
    gemm_nt_n64<bf16><<<dim3(1, 6, BHc), 256, 0, stream>>>(
        Ab, v1t, yb1, Nc, Nc, (long)MAT, HSTR, HSTR);
    gemm_nt_n64<bf16><<<dim3(1, 6, BHc), 256, 0, stream>>>(
        A1b, trt, yb2, Nc, Nc, (long)MAT, HSTR, HSTR);

    // 9. combine + layout (bf16)
    combine_y<<<dim3(3072), 256, 0, stream>>>(yb1, yb2, smallf, yc);

    // 10. proj via MFMA + dtype-aware store
    proj_mfma<<<dim3(4, 12, 1), 256, 0, stream>>>(yc, pwt, d_in[0], d_out);
}

// Round 8
// 552.333 us; speedup vs baseline: 1.2212x; 1.0188x over previous
//
#include <hip/hip_runtime.h>
#include <hip/hip_bf16.h>
#include <math.h>

typedef __hip_bfloat16 bf16;
typedef __attribute__((ext_vector_type(8))) short short8;   // 8 bf16 (4 VGPRs)
typedef __attribute__((ext_vector_type(4))) float f32x4;
#define DEVINL __device__ __forceinline__

constexpr int Bc  = 2;
constexpr int Nc  = 768;
constexpr int Dc  = 512;
constexpr int Hc  = 8;
constexpr int DKc = 64;
constexpr int BHc = Bc * Hc;
constexpr float SCALE    = 0.125f;   // 1/sqrt(64)
constexpr float EPSF     = 1e-6f;
constexpr float BETA_NOT = 0.5f;

DEVINL float ldf(const float* p, long i) { return p[i]; }
DEVINL float ldf(const bf16* p, long i) { return __bfloat162float(p[i]); }
DEVINL void stf(float* p, long i, float v) { p[i] = v; }
DEVINL void stf(bf16* p, long i, float v) { p[i] = __float2bfloat16(v); }

DEVINL float sigf(float x) { return __fdividef(1.f, 1.f + __expf(-x)); }

// async global->LDS, 16B per lane; LDS dest = wave-uniform base + lane*16.
DEVINL void gl_lds16(const void* g, void* l) {
    __builtin_amdgcn_global_load_lds(
        (const __attribute__((address_space(1))) void*)g,
        (__attribute__((address_space(3))) void*)l, 16, 0, 0);
}

// ---------------------------------------------------------------------------
// Dtype sniffer (round-1 notes). Deterministic per launch.
// ---------------------------------------------------------------------------
DEVINL int sniff_is_fp32(const void* xraw) {
    const unsigned short* p = (const unsigned short*)xraw;
    float mx = 0.f;
#pragma unroll 1
    for (int j = 0; j < 128; ++j) {
        float v = __uint_as_float(((unsigned)p[j]) << 16);
        mx = fmaxf(mx, fabsf(v));
    }
    return mx > 1000.f ? 1 : 0;
}

DEVINL float cvt_elem(const void* s, long j, int is32) {
    return is32 ? ((const float*)s)[j]
                : __bfloat162float(((const bf16*)s)[j]);
}

__global__ __launch_bounds__(256) void convert_all(
    const void* x, const void* w1, const void* w2, const void* pw,
    const void* c1w, const void* c1b, const void* c2w, const void* c2b,
    const void* ch,
    bf16* xb, bf16* w1b, bf16* w2b, bf16* pwb, float* smallf)
{
    const int is32 = sniff_is_fp32(x);
    const long i = (long)blockIdx.x * 256 + threadIdx.x;
    if (i < (long)Bc * Nc * Dc) {
        xb[i]  = __float2bfloat16(cvt_elem(x,  i, is32));
        w1b[i] = __float2bfloat16(cvt_elem(w1, i, is32));
        w2b[i] = __float2bfloat16(cvt_elem(w2, i, is32));
    }
    if (i < (long)Dc * Dc) pwb[i] = __float2bfloat16(cvt_elem(pw, i, is32));
    if (i < 96)       smallf[i] = cvt_elem(c1w, i,        is32);
    else if (i < 112) smallf[i] = cvt_elem(c1b, i - 96,   is32);
    else if (i < 176) smallf[i] = cvt_elem(c2w, i - 112,  is32);
    else if (i < 180) smallf[i] = cvt_elem(c2b, i - 176,  is32);
    else if (i == 180) smallf[180] = cvt_elem(ch, 0, is32);
}

__global__ __launch_bounds__(256) void fill_sentinel(unsigned short* o) {
    const long i = (long)blockIdx.x * 256 + threadIdx.x;
    if (i < (long)Bc * Nc * Dc) o[i] = 0x40E0;  // bf16 7.0
}

// ---------------------------------------------------------------------------
// Generic bf16 transpose, 64x64 tiles: dst[c][r] = src[r][c]; src is (R,C).
// ---------------------------------------------------------------------------
__global__ __launch_bounds__(256) void transpose_bf16(
    const unsigned short* __restrict__ src, unsigned short* __restrict__ dst,
    int R, int C, long sS, long sD)
{
    __shared__ unsigned short tile[64][68];
    const unsigned short* s = src + (long)blockIdx.z * sS;
    unsigned short* d = dst + (long)blockIdx.z * sD;
    const int r0 = blockIdx.y * 64, c0 = blockIdx.x * 64;
    const int t = threadIdx.x;
    const int lr = t >> 4, lc4 = (t & 15) * 4;
#pragma unroll
    for (int i = 0; i < 4; ++i) {
        int r = lr + i * 16;
        *(uint2*)&tile[r][lc4] = *(const uint2*)&s[(long)(r0 + r) * C + c0 + lc4];
    }
    __syncthreads();
#pragma unroll
    for (int i = 0; i < 4; ++i) {
        int r = lr + i * 16;
        unsigned short v[4];
#pragma unroll
        for (int j = 0; j < 4; ++j) v[j] = tile[lc4 + j][r];
        *(uint2*)&d[(long)(c0 + r) * R + r0 + lc4] = *(uint2*)v;
    }
}

// ---------------------------------------------------------------------------
// MFMA bf16 NT GEMM with global_load_lds staging (validated round 6):
// C = A(M,K) @ Bt(N,K)^T. 128x128 tile, BK=32.
// ---------------------------------------------------------------------------
template <int EPI, typename TC>
__global__ __launch_bounds__(256) void gemm_nt_mfma(
    const bf16* __restrict__ Ag, const bf16* __restrict__ Btg,
    TC* __restrict__ Cg, int M, int N, int K,
    long sA, long sB, long sC, float alpha)
{
    __shared__ unsigned short Asm[128 * 32];
    __shared__ unsigned short Bsm[128 * 32];

    const int tid  = threadIdx.x;
    const int wv   = tid >> 6;
    const int lane = tid & 63;
    const int q    = lane >> 4;
    const int ln   = lane & 15;
    const int wm   = wv & 1;
    const int wn   = wv >> 1;

    const bf16* A  = Ag  + (long)blockIdx.z * sA + (long)(blockIdx.y * 128) * K;
    const bf16* Bt = Btg + (long)blockIdx.z * sB + (long)(blockIdx.x * 128) * K;
    TC*         C  = Cg  + (long)blockIdx.z * sC;

    const int sr = lane >> 2, sc = lane & 3;
    const bf16* gA0 = A  + (long)(wv * 32 + sr)      * K + sc * 8;
    const bf16* gA1 = A  + (long)(wv * 32 + 16 + sr) * K + sc * 8;
    const bf16* gB0 = Bt + (long)(wv * 32 + sr)      * K + sc * 8;
    const bf16* gB1 = Bt + (long)(wv * 32 + 16 + sr) * K + sc * 8;
    unsigned short* lA0 = &Asm[(wv * 32)      * 32];
    unsigned short* lA1 = &Asm[(wv * 32 + 16) * 32];
    unsigned short* lB0 = &Bsm[(wv * 32)      * 32];
    unsigned short* lB1 = &Bsm[(wv * 32 + 16) * 32];

    f32x4 acc[4][4];
#pragma unroll
    for (int i = 0; i < 4; ++i)
#pragma unroll
        for (int j = 0; j < 4; ++j)
            acc[i][j] = (f32x4){0.f, 0.f, 0.f, 0.f};

    for (int k0 = 0; k0 < K; k0 += 32) {
        __syncthreads();
        gl_lds16(gA0 + k0, lA0);
        gl_lds16(gA1 + k0, lA1);
        gl_lds16(gB0 + k0, lB0);
        gl_lds16(gB1 + k0, lB1);
        __syncthreads();

        short8 af[4], bfr[4];
#pragma unroll
        for (int mt = 0; mt < 4; ++mt) {
            int m = wm * 64 + mt * 16 + ln;
            af[mt] = *(const short8*)&Asm[m * 32 + q * 8];
        }
#pragma unroll
        for (int nt = 0; nt < 4; ++nt) {
            int n = wn * 64 + nt * 16 + ln;
            bfr[nt] = *(const short8*)&Bsm[n * 32 + q * 8];
        }
#pragma unroll
        for (int mt = 0; mt < 4; ++mt)
#pragma unroll
            for (int nt = 0; nt < 4; ++nt)
                acc[mt][nt] = __builtin_amdgcn_mfma_f32_16x16x32_bf16(
                    af[mt], bfr[nt], acc[mt][nt], 0, 0, 0);
    }

#pragma unroll
    for (int mt = 0; mt < 4; ++mt) {
#pragma unroll
        for (int nt = 0; nt < 4; ++nt) {
            const int col = blockIdx.x * 128 + wn * 64 + nt * 16 + ln;
            const int rowb = blockIdx.y * 128 + wm * 64 + mt * 16 + q * 4;
#pragma unroll
            for (int r = 0; r < 4; ++r) {
                float v = acc[mt][nt][r] * alpha;
                if (EPI == 1) v = __logf(fmaxf(v, 0.f) + EPSF);
                stf(C, (long)(rowb + r) * N + col, v);
            }
        }
    }
}

// ---------------------------------------------------------------------------
// QKV via MFMA, merged sets (validated round 6).
// ---------------------------------------------------------------------------
__global__ __launch_bounds__(256) void qkv_mfma(
    const bf16* __restrict__ X,
    const bf16* __restrict__ w1t, const bf16* __restrict__ w2t,
    bf16* __restrict__ q1, bf16* __restrict__ k1, bf16* __restrict__ v1,
    bf16* __restrict__ q2, bf16* __restrict__ k2, bf16* __restrict__ v2)
{
    constexpr int K = Dc;  // 512
    __shared__ unsigned short Asm[128 * 32];
    __shared__ unsigned short Bsm[128 * 32];

    const int tid  = threadIdx.x;
    const int wv   = tid >> 6;
    const int lane = tid & 63;
    const int q    = lane >> 4;
    const int ln   = lane & 15;
    const int wm   = wv & 1;
    const int wn   = wv >> 1;
    const int set  = blockIdx.z;

    const bf16* Wt = set ? w2t : w1t;
    bf16* Q  = set ? q2 : q1;
    bf16* Ko = set ? k2 : k1;
    bf16* V  = set ? v2 : v1;

    const bf16* A  = X  + (long)(blockIdx.y * 128) * K;
    const bf16* Bt = Wt + (long)(blockIdx.x * 128) * K;

    const int sr = lane >> 2, sc = lane & 3;
    const bf16* gA0 = A  + (long)(wv * 32 + sr)      * K + sc * 8;
    const bf16* gA1 = A  + (long)(wv * 32 + 16 + sr) * K + sc * 8;
    const bf16* gB0 = Bt + (long)(wv * 32 + sr)      * K + sc * 8;
    const bf16* gB1 = Bt + (long)(wv * 32 + 16 + sr) * K + sc * 8;
    unsigned short* lA0 = &Asm[(wv * 32)      * 32];
    unsigned short* lA1 = &Asm[(wv * 32 + 16) * 32];
    unsigned short* lB0 = &Bsm[(wv * 32)      * 32];
    unsigned short* lB1 = &Bsm[(wv * 32 + 16) * 32];

    f32x4 acc[4][4];
#pragma unroll
    for (int i = 0; i < 4; ++i)
#pragma unroll
        for (int j = 0; j < 4; ++j)
            acc[i][j] = (f32x4){0.f, 0.f, 0.f, 0.f};

    for (int k0 = 0; k0 < K; k0 += 32) {
        __syncthreads();
        gl_lds16(gA0 + k0, lA0);
        gl_lds16(gA1 + k0, lA1);
        gl_lds16(gB0 + k0, lB0);
        gl_lds16(gB1 + k0, lB1);
        __syncthreads();

        short8 af[4], bfr[4];
#pragma unroll
        for (int mt = 0; mt < 4; ++mt) {
            int m = wm * 64 + mt * 16 + ln;
            af[mt] = *(const short8*)&Asm[m * 32 + q * 8];
        }
#pragma unroll
        for (int nt = 0; nt < 4; ++nt) {
            int n = wn * 64 + nt * 16 + ln;
            bfr[nt] = *(const short8*)&Bsm[n * 32 + q * 8];
        }
#pragma unroll
        for (int mt = 0; mt < 4; ++mt)
#pragma unroll
            for (int nt = 0; nt < 4; ++nt)
                acc[mt][nt] = __builtin_amdgcn_mfma_f32_16x16x32_bf16(
                    af[mt], bfr[nt], acc[mt][nt], 0, 0, 0);
    }

#pragma unroll
    for (int mt = 0; mt < 4; ++mt) {
#pragma unroll
        for (int nt = 0; nt < 4; ++nt) {
            const int col  = blockIdx.x * 128 + wn * 64 + nt * 16 + ln;
            const int rowb = blockIdx.y * 128 + wm * 64 + mt * 16 + q * 4;
            const int t = col >> 9;
            const int h = (col >> 6) & 7;
            const int dk = col & 63;
            bf16* dst = (t == 0) ? Q : (t == 1) ? Ko : V;
#pragma unroll
            for (int r = 0; r < 4; ++r) {
                const int row = rowb + r;
                const int b = row >= Nc ? 1 : 0;
                const int n = row - b * Nc;
                dst[(((long)b * Hc + h) * Nc + n) * DKc + dk] =
                    __float2bfloat16(acc[mt][nt][r]);
            }
        }
    }
}

// ---------------------------------------------------------------------------
// MFMA bf16 NT GEMM, narrow (validated): C(M,64) = A(M,K) @ Bt(64,K)^T.
// ---------------------------------------------------------------------------
template <typename TC>
__global__ __launch_bounds__(256) void gemm_nt_n64(
    const bf16* __restrict__ Ag, const bf16* __restrict__ Btg,
    TC* __restrict__ Cg, int M, int K, long sA, long sB, long sC)
{
    __shared__ unsigned short Asm[128 * 72];
    __shared__ unsigned short Bsm[64 * 72];

    const int tid  = threadIdx.x;
    const int wave = tid >> 6;
    const int lane = tid & 63;
    const int q    = lane >> 4;
    const int ln   = lane & 15;

    const bf16* A  = Ag  + (long)blockIdx.z * sA + (long)(blockIdx.y * 128) * K;
    const bf16* Bt = Btg + (long)blockIdx.z * sB;
    TC*         C  = Cg  + (long)blockIdx.z * sC;

    const int sr = tid >> 3, k8 = tid & 7;
    const bf16* pa[4];
    const bf16* pb[2];
    int wa[4], wb[2];
#pragma unroll
    for (int i = 0; i < 4; ++i) {
        pa[i] = A + (long)(sr + i * 32) * K + k8 * 8;
        wa[i] = (sr + i * 32) * 72 + k8 * 8;
    }
#pragma unroll
    for (int i = 0; i < 2; ++i) {
        pb[i] = Bt + (long)(sr + i * 32) * K + k8 * 8;
        wb[i] = (sr + i * 32) * 72 + k8 * 8;
    }

    f32x4 acc[2][4];
#pragma unroll
    for (int i = 0; i < 2; ++i)
#pragma unroll
        for (int j = 0; j < 4; ++j)
            acc[i][j] = (f32x4){0.f, 0.f, 0.f, 0.f};

    for (int k0 = 0; k0 < K; k0 += 64) {
        uint4 va[4], vb[2];
#pragma unroll
        for (int i = 0; i < 4; ++i) va[i] = *(const uint4*)(pa[i] + k0);
#pragma unroll
        for (int i = 0; i < 2; ++i) vb[i] = *(const uint4*)(pb[i] + k0);
        __syncthreads();
#pragma unroll
        for (int i = 0; i < 4; ++i) *(uint4*)&Asm[wa[i]] = va[i];
#pragma unroll
        for (int i = 0; i < 2; ++i) *(uint4*)&Bsm[wb[i]] = vb[i];
        __syncthreads();

#pragma unroll
        for (int kc = 0; kc < 2; ++kc) {
            short8 af[2], bfr[4];
#pragma unroll
            for (int mt = 0; mt < 2; ++mt) {
                int m = wave * 32 + mt * 16 + ln;
                af[mt] = *(const short8*)&Asm[m * 72 + kc * 32 + q * 8];
            }
#pragma unroll
            for (int nt = 0; nt < 4; ++nt) {
                int n = nt * 16 + ln;
                bfr[nt] = *(const short8*)&Bsm[n * 72 + kc * 32 + q * 8];
            }
#pragma unroll
            for (int mt = 0; mt < 2; ++mt)
#pragma unroll
                for (int nt = 0; nt < 4; ++nt)
                    acc[mt][nt] = __builtin_amdgcn_mfma_f32_16x16x32_bf16(
                        af[mt], bfr[nt], acc[mt][nt], 0, 0, 0);
        }
    }

#pragma unroll
    for (int mt = 0; mt < 2; ++mt) {
#pragma unroll
        for (int nt = 0; nt < 4; ++nt) {
            const int col  = nt * 16 + ln;
            const int rowb = blockIdx.y * 128 + wave * 32 + mt * 16 + q * 4;
#pragma unroll
            for (int r = 0; r < 4; ++r)
                stf(C, (long)(rowb + r) * 64 + col, acc[mt][nt][r]);
        }
    }
}

// ---------------------------------------------------------------------------
// Row softmax over width 768 (validated).
// ---------------------------------------------------------------------------
template <typename TO>
__global__ __launch_bounds__(256) void softmax_rows(const float* src, TO* dst)
{
    __shared__ float red[4];
    const long row = blockIdx.x;
    const float* s = src + row * Nc;
    TO* d = dst + row * Nc;
    const int tid = threadIdx.x;

    float v[3];
    float m = -1e30f;
#pragma unroll
    for (int i = 0; i < 3; ++i) { v[i] = s[tid + i * 256]; m = fmaxf(m, v[i]); }

#pragma unroll
    for (int off = 32; off > 0; off >>= 1) m = fmaxf(m, __shfl_down(m, off, 64));
    if ((tid & 63) == 0) red[tid >> 6] = m;
    __syncthreads();
    if (tid == 0) {
        float mm = red[0];
        for (int w = 1; w < 4; ++w) mm = fmaxf(mm, red[w]);
        red[0] = mm;
    }
    __syncthreads();
    m = red[0];
    __syncthreads();

    float e[3];
    float sum = 0.f;
#pragma unroll
    for (int i = 0; i < 3; ++i) { e[i] = __expf(v[i] - m); sum += e[i]; }
#pragma unroll
    for (int off = 32; off > 0; off >>= 1) sum += __shfl_down(sum, off, 64);
    if ((tid & 63) == 0) red[tid >> 6] = sum;
    __syncthreads();
    if (tid == 0) red[0] = red[0] + red[1] + red[2] + red[3];
    __syncthreads();
    const float inv = 1.f / fmaxf(red[0], 1e-30f);
#pragma unroll
    for (int i = 0; i < 3; ++i) stf(d, tid + i * 256, e[i] * inv);
}

// ---------------------------------------------------------------------------
// Gate network + Smix — round-3 STRUCTURE (1 elem/thread, LDS weights,
// VGPR~28, occ ~80% — the validated optimum) with round-4 MATH (fast div,
// sigmoid-form gelu — absmax-validated in rounds 4-6). Precise fp32 div was
// ~10 instrs x20 per element; __fdividef is 2.
// ---------------------------------------------------------------------------
__global__ __launch_bounds__(256) void gates_smix(
    const float* __restrict__ S1g, const float* __restrict__ S2g,
    const bf16* __restrict__ Crg, const bf16* __restrict__ Clg,
    float* __restrict__ Smixg, const float* __restrict__ smallf)
{
    __shared__ float t1t[16][17], t2t[16][17];
    __shared__ float cs[192];

    const int bh = blockIdx.z;
    const long mat = (long)bh * Nc * Nc;
    const float* S1 = S1g + mat;
    const float* S2 = S2g + mat;
    const bf16*  Cr = Crg + mat;
    const bf16*  Cl = Clg + mat;
    float* Smix = Smixg + mat;

    const int tid = threadIdx.x;
    if (tid < 192) cs[tid] = smallf[tid];

    const int n0 = blockIdx.y * 16, m0 = blockIdx.x * 16;
    const int tx = tid & 15, ty = tid >> 4;

    t1t[ty][tx] = S1[(long)(m0 + ty) * Nc + n0 + tx];
    t2t[ty][tx] = S2[(long)(m0 + ty) * Nc + n0 + tx];
    __syncthreads();

    const float* cw1 = cs;       const float* cb1 = cs + 96;
    const float* cw2 = cs + 112; const float* cb2 = cs + 176;

    const int n = n0 + ty, mcol = m0 + tx;
    const long idx = (long)n * Nc + mcol;
    const float s1 = S1[idx], s2 = S2[idx];
    const float s1t = t1t[tx][ty], s2t = t2t[tx][ty];
    const float cr = __bfloat162float(Cr[idx]), cl = __bfloat162float(Cl[idx]);

    const float feat[6] = {s1, s2, s1t, s2t, cr, cl};
    float g[4];
#pragma unroll
    for (int o = 0; o < 4; ++o) g[o] = cb2[o];

#pragma unroll
    for (int c16 = 0; c16 < 16; ++c16) {
        float h = cb1[c16];
#pragma unroll
        for (int c = 0; c < 6; ++c) h = fmaf(feat[c], cw1[c16 * 6 + c], h);
        // gelu_tanh(h) = h * sigmoid(2z), z = 0.79788456(h + 0.044715 h^3);
        // constants pre-folded with the -2: z2 = -2z
        const float hh = h * h;
        const float z2 = h * fmaf(hh, -0.0713548162f, -1.5957691216f);
        const float e = __expf(z2);           // e->inf => hid->0, no NaN
        const float hid = h * __fdividef(1.f, 1.f + e);
#pragma unroll
        for (int o = 0; o < 4; ++o) g[o] = fmaf(hid, cw2[o * 16 + c16], g[o]);
    }
#pragma unroll
    for (int o = 0; o < 4; ++o) g[o] = sigf(g[o]);

    const float mx = fmaxf(s1, s2);
    const float lae = mx + __logf(1.f + __expf(-fabsf(s1 - s2)));
    Smix[idx] = s1 + g[0] * s2 + g[1] * (lae - s1) - g[2] * (BETA_NOT * s2) + g[3] * cr;
}

// ---------------------------------------------------------------------------
// y = y_base + sigmoid(chain)*y_chain, (b,h,n,dk) -> (b,n,h*dk), bf16 in/out.
// ---------------------------------------------------------------------------
__global__ __launch_bounds__(256) void combine_y(
    const bf16* __restrict__ y1, const bf16* __restrict__ y2,
    const float* __restrict__ smallf, bf16* __restrict__ y)
{
    const long i = (long)blockIdx.x * 256 + threadIdx.x;
    const int dk = (int)(i & 63);
    const long t = i >> 6;
    const int n = (int)(t % Nc);
    const long t2 = t / Nc;
    const int h = (int)(t2 & 7);
    const int b = (int)(t2 >> 3);
    const float w = 1.f / (1.f + __expf(-smallf[180]));
    const float v = __bfloat162float(y1[i]) + w * __bfloat162float(y2[i]);
    y[((long)(b * Nc + n)) * Dc + h * DKc + dk] = __float2bfloat16(v);
}

// ---------------------------------------------------------------------------
// Final projection via MFMA (validated round 7).
// ---------------------------------------------------------------------------
__global__ __launch_bounds__(256) void proj_mfma(
    const bf16* __restrict__ yc, const bf16* __restrict__ pwt,
    const void* __restrict__ xraw, void* __restrict__ out)
{
    constexpr int K = Dc;  // 512
    constexpr int N = Dc;  // 512
    __shared__ unsigned short Asm[128 * 32];
    __shared__ unsigned short Bsm[128 * 32];
    __shared__ int is32s;

    const int tid  = threadIdx.x;
    if (tid == 0) is32s = sniff_is_fp32(xraw);
    const int wv   = tid >> 6;
    const int lane = tid & 63;
    const int q    = lane >> 4;
    const int ln   = lane & 15;
    const int wm   = wv & 1;
    const int wn   = wv >> 1;

    const bf16* A  = yc  + (long)(blockIdx.y * 128) * K;
    const bf16* Bt = pwt + (long)(blockIdx.x * 128) * K;

    const int sr = lane >> 2, sc = lane & 3;
    const bf16* gA0 = A  + (long)(wv * 32 + sr)      * K + sc * 8;
    const bf16* gA1 = A  + (long)(wv * 32 + 16 + sr) * K + sc * 8;
    const bf16* gB0 = Bt + (long)(wv * 32 + sr)      * K + sc * 8;
    const bf16* gB1 = Bt + (long)(wv * 32 + 16 + sr) * K + sc * 8;
    unsigned short* lA0 = &Asm[(wv * 32)      * 32];
    unsigned short* lA1 = &Asm[(wv * 32 + 16) * 32];
    unsigned short* lB0 = &Bsm[(wv * 32)      * 32];
    unsigned short* lB1 = &Bsm[(wv * 32 + 16) * 32];

    f32x4 acc[4][4];
#pragma unroll
    for (int i = 0; i < 4; ++i)
#pragma unroll
        for (int j = 0; j < 4; ++j)
            acc[i][j] = (f32x4){0.f, 0.f, 0.f, 0.f};

    for (int k0 = 0; k0 < K; k0 += 32) {
        __syncthreads();
        gl_lds16(gA0 + k0, lA0);
        gl_lds16(gA1 + k0, lA1);
        gl_lds16(gB0 + k0, lB0);
        gl_lds16(gB1 + k0, lB1);
        __syncthreads();

        short8 af[4], bfr[4];
#pragma unroll
        for (int mt = 0; mt < 4; ++mt) {
            int m = wm * 64 + mt * 16 + ln;
            af[mt] = *(const short8*)&Asm[m * 32 + q * 8];
        }
#pragma unroll
        for (int nt = 0; nt < 4; ++nt) {
            int n = wn * 64 + nt * 16 + ln;
            bfr[nt] = *(const short8*)&Bsm[n * 32 + q * 8];
        }
#pragma unroll
        for (int mt = 0; mt < 4; ++mt)
#pragma unroll
            for (int nt = 0; nt < 4; ++nt)
                acc[mt][nt] = __builtin_amdgcn_mfma_f32_16x16x32_bf16(
                    af[mt], bfr[nt], acc[mt][nt], 0, 0, 0);
    }

    const int is32 = is32s;
#pragma unroll
    for (int mt = 0; mt < 4; ++mt) {
#pragma unroll
        for (int nt = 0; nt < 4; ++nt) {
            const int col = blockIdx.x * 128 + wn * 64 + nt * 16 + ln;
            const int rowb = blockIdx.y * 128 + wm * 64 + mt * 16 + q * 4;
#pragma unroll
            for (int r = 0; r < 4; ++r) {
                const long o = (long)(rowb + r) * N + col;
                if (is32) ((float*)out)[o] = acc[mt][nt][r];
                else      ((bf16*)out)[o] = __float2bfloat16(acc[mt][nt][r]);
            }
        }
    }
}

// ---------------------------------------------------------------------------
extern "C" void kernel_launch(void* const* d_in, const int* in_sizes, int n_in,
                              void* d_out, int out_size, void* d_ws, size_t ws_size,
                              hipStream_t stream)
{
    const size_t HD   = (size_t)BHc * Nc * DKc;   // 786432
    const size_t HDh  = HD / 2;                   // float-slots for HD bf16
    const size_t MAT  = (size_t)Nc * Nc;          // 589824
    const size_t MATS = (size_t)BHc * MAT;        // 9437184
    const long   HSTR = (long)Nc * DKc;           // 49152 per-head stride

    float* ws = (float*)d_ws;
    size_t off = 0;
    auto alloc = [&](size_t n) { float* p = ws + off; off += n; return p; };

    bf16* xb  = (bf16*)alloc(HDh);
    bf16* w1b = (bf16*)alloc(HDh);   // w1b/w2b adjacent -> merged transpose
    bf16* w2b = (bf16*)alloc(HDh);
    bf16* w1t = (bf16*)alloc(HDh);
    bf16* w2t = (bf16*)alloc(HDh);
    bf16* pwb = (bf16*)alloc((size_t)Dc * Dc / 2);
    bf16* pwt = (bf16*)alloc((size_t)Dc * Dc / 2);
    float* smallf = alloc(192);
    // q1|q2 and k1|k2 adjacent -> single merged S-GEMM launch (32 heads)
    bf16* q1b = (bf16*)alloc(HDh); bf16* q2b = (bf16*)alloc(HDh);
    bf16* k1b = (bf16*)alloc(HDh); bf16* k2b = (bf16*)alloc(HDh);
    bf16* v1b = (bf16*)alloc(HDh); bf16* v2b = (bf16*)alloc(HDh);  // adjacent
    bf16* v1t = (bf16*)alloc(HDh); bf16* v2t = (bf16*)alloc(HDh);  // adjacent
    bf16* trb = (bf16*)alloc(HDh);
    bf16* trt = (bf16*)alloc(HDh);
    float* S1   = alloc(MATS);       // S1/S2 adjacent -> merged softmax + S-GEMM
    float* S2   = alloc(MATS);
    float* Smix = alloc(MATS);
    bf16* A1b = (bf16*)alloc(MATS / 2);  // A1b/A2b adjacent
    bf16* A2b = (bf16*)alloc(MATS / 2);
    bf16* Crb = (bf16*)alloc(MATS / 2);
    bf16* Clb = (bf16*)alloc(MATS / 2);
    bf16* yb1 = (bf16*)alloc(HDh);
    bf16* yb2 = (bf16*)alloc(HDh);
    bf16* yc  = (bf16*)alloc(HDh);

    // aliases into dead regions
    bf16* A1tb = (bf16*)Smix;            // dead until gates writes Smix
    bf16* A2tb = ((bf16*)Smix) + MATS;   // A1tb/A2tb adjacent
    bf16* Ab   = (bf16*)S1;              // S1 dead after gates

    const size_t NEED_BYTES = off * sizeof(float);
    if (ws_size < NEED_BYTES) {
        fill_sentinel<<<dim3(3072), 256, 0, stream>>>((unsigned short*)d_out);
        return;
    }

    // 0. normalize inputs
    convert_all<<<dim3(3072), 256, 0, stream>>>(
        d_in[0], d_in[1], d_in[2], d_in[3], d_in[4], d_in[5], d_in[6], d_in[7],
        d_in[8], xb, w1b, w2b, pwb, smallf);

    // 1. merged W transposes; pw transpose; merged QKV; merged v transposes
    transpose_bf16<<<dim3(24, 8, 2), 256, 0, stream>>>(
        (const unsigned short*)w1b, (unsigned short*)w1t, Dc, 3 * Dc, (long)HD, (long)HD);
    transpose_bf16<<<dim3(8, 8, 1), 256, 0, stream>>>(
        (const unsigned short*)pwb, (unsigned short*)pwt, Dc, Dc, 0, 0);
    qkv_mfma<<<dim3(12, 12, 2), 256, 0, stream>>>(
        xb, w1t, w2t, q1b, k1b, v1b, q2b, k2b, v2b);
    transpose_bf16<<<dim3(1, 12, 2 * BHc), 256, 0, stream>>>(
        (const unsigned short*)v1b, (unsigned short*)v1t, Nc, DKc, HSTR, HSTR);

    // 2. S = scale * q @ k^T — SINGLE launch over 32 (set x head) batches:
    //    q2b = q1b + 16*HSTR, k2b = k1b + 16*HSTR, S2 = S1 + 16*MAT.
    gemm_nt_mfma<0, float><<<dim3(6, 6, 2 * BHc), 256, 0, stream>>>(
        q1b, k1b, S1, Nc, Nc, DKc, HSTR, HSTR, (long)MAT, SCALE);

    // 3. merged softmax S1|S2 -> A1b|A2b; merged transposes -> A1tb|A2tb
    softmax_rows<bf16><<<2 * BHc * Nc, 256, 0, stream>>>(S1, A1b);
    transpose_bf16<<<dim3(12, 12, 2 * BHc), 256, 0, stream>>>(
        (const unsigned short*)A1b, (unsigned short*)A1tb, Nc, Nc, (long)MAT, (long)MAT);

    // 4. Cr/Cl via bf16 MFMA + log epilogue
    gemm_nt_mfma<1, bf16><<<dim3(6, 6, BHc), 256, 0, stream>>>(
        A1b, A2tb, Crb, Nc, Nc, Nc, (long)MAT, (long)MAT, (long)MAT, 1.f);
    gemm_nt_mfma<1, bf16><<<dim3(6, 6, BHc), 256, 0, stream>>>(
        A2b, A1tb, Clb, Nc, Nc, Nc, (long)MAT, (long)MAT, (long)MAT, 1.f);

    // 5. gates + Smix (1 elem/thread structure + fast math)
    gates_smix<<<dim3(48, 48, BHc), 256, 0, stream>>>(S1, S2, Crb, Clb, Smix, smallf);

    // 6. A = softmax(Smix) -> bf16 (into S1 alias)
    softmax_rows<bf16><<<BHc * Nc, 256, 0, stream>>>(Smix, Ab);

    // 7. transport = A2 @ v2, transpose for next NT GEMM
    gemm_nt_n64<bf16><<<dim3(1, 6, BHc), 256, 0, stream>>>(
        A2b, v2t, trb, Nc, Nc, (long)MAT, HSTR, HSTR);
    transpose_bf16<<<dim3(1, 12, BHc), 256, 0, stream>>>(
        (const unsigned short*)trb, (unsigned short*)trt, Nc, DKc, HSTR, HSTR);

    // 8. y_base = A @ v1 ; y_chain = A1 @ transport (bf16 out)
    gemm_nt_n64<bf16><<<dim3(1, 6, BHc), 256, 0, stream>>>(
        Ab, v1t, yb1, Nc, Nc, (long)MAT, HSTR, HSTR);
    gemm_nt_n64<bf16><<<dim3(1, 6, BHc), 256, 0, stream>>>(
        A1b, trt, yb2, Nc, Nc, (long)MAT, HSTR, HSTR);

    // 9. combine + layout (bf16)
    combine_y<<<dim3(3072), 256, 0, stream>>>(yb1, yb2, smallf, yc);

    // 10. proj via MFMA + dtype-aware store
    proj_mfma<<<dim3(4, 12, 1), 256, 0, stream>>>(yc, pwt, d_in[0], d_out);
}

// Round 9
// 464.147 us; speedup vs baseline: 1.4533x; 1.1900x over previous
//
#include <hip/hip_runtime.h>
#include <hip/hip_bf16.h>
#include <math.h>

typedef __hip_bfloat16 bf16;
typedef __attribute__((ext_vector_type(8))) short short8;   // 8 bf16 (4 VGPRs)
typedef __attribute__((ext_vector_type(4))) float f32x4;
#define DEVINL __device__ __forceinline__

constexpr int Bc  = 2;
constexpr int Nc  = 768;
constexpr int Dc  = 512;
constexpr int Hc  = 8;
constexpr int DKc = 64;
constexpr int BHc = Bc * Hc;
constexpr float SCALE    = 0.125f;   // 1/sqrt(64)
constexpr float EPSF     = 1e-6f;
constexpr float BETA_NOT = 0.5f;

DEVINL float ldf(const float* p, long i) { return p[i]; }
DEVINL float ldf(const bf16* p, long i) { return __bfloat162float(p[i]); }
DEVINL void stf(float* p, long i, float v) { p[i] = v; }
DEVINL void stf(bf16* p, long i, float v) { p[i] = __float2bfloat16(v); }

DEVINL float sigf(float x) { return __fdividef(1.f, 1.f + __expf(-x)); }

// async global->LDS, 16B per lane; LDS dest = wave-uniform base + lane*16.
DEVINL void gl_lds16(const void* g, void* l) {
    __builtin_amdgcn_global_load_lds(
        (const __attribute__((address_space(1))) void*)g,
        (__attribute__((address_space(3))) void*)l, 16, 0, 0);
}

// ---------------------------------------------------------------------------
// Dtype sniffer — vectorized (16 x uint4 loads + unrolled VALU; the old
// 128-iteration scalar-load loop was a real cost in convert_all).
// ---------------------------------------------------------------------------
DEVINL int sniff_is_fp32(const void* xraw) {
    const uint4* p4 = (const uint4*)xraw;
    float mx = 0.f;
#pragma unroll
    for (int j = 0; j < 16; ++j) {
        const uint4 u = p4[j];
        const unsigned w[4] = {u.x, u.y, u.z, u.w};
#pragma unroll
        for (int t = 0; t < 4; ++t) {
            mx = fmaxf(mx, fabsf(__uint_as_float((w[t] & 0xffffu) << 16)));
            mx = fmaxf(mx, fabsf(__uint_as_float(w[t] & 0xffff0000u)));
        }
    }
    return mx > 1000.f ? 1 : 0;
}

DEVINL float cvt_elem(const void* s, long j, int is32) {
    return is32 ? ((const float*)s)[j]
                : __bfloat162float(((const bf16*)s)[j]);
}

__global__ __launch_bounds__(256) void convert_all(
    const void* x, const void* w1, const void* w2, const void* pw,
    const void* c1w, const void* c1b, const void* c2w, const void* c2b,
    const void* ch,
    bf16* xb, bf16* w1b, bf16* w2b, bf16* pwb, float* smallf)
{
    __shared__ int is32s;
    if (threadIdx.x == 0) is32s = sniff_is_fp32(x);
    __syncthreads();
    const int is32 = is32s;
    const long i = (long)blockIdx.x * 256 + threadIdx.x;
    if (i < (long)Bc * Nc * Dc) {
        xb[i]  = __float2bfloat16(cvt_elem(x,  i, is32));
        w1b[i] = __float2bfloat16(cvt_elem(w1, i, is32));
        w2b[i] = __float2bfloat16(cvt_elem(w2, i, is32));
    }
    if (i < (long)Dc * Dc) pwb[i] = __float2bfloat16(cvt_elem(pw, i, is32));
    if (i < 96)       smallf[i] = cvt_elem(c1w, i,        is32);
    else if (i < 112) smallf[i] = cvt_elem(c1b, i - 96,   is32);
    else if (i < 176) smallf[i] = cvt_elem(c2w, i - 112,  is32);
    else if (i < 180) smallf[i] = cvt_elem(c2b, i - 176,  is32);
    else if (i == 180) smallf[180] = cvt_elem(ch, 0, is32);
}

__global__ __launch_bounds__(256) void fill_sentinel(unsigned short* o) {
    const long i = (long)blockIdx.x * 256 + threadIdx.x;
    if (i < (long)Bc * Nc * Dc) o[i] = 0x40E0;  // bf16 7.0
}

// ---------------------------------------------------------------------------
// Generic bf16 transpose, 64x64 tiles: dst[c][r] = src[r][c]; src is (R,C).
// ---------------------------------------------------------------------------
__global__ __launch_bounds__(256) void transpose_bf16(
    const unsigned short* __restrict__ src, unsigned short* __restrict__ dst,
    int R, int C, long sS, long sD)
{
    __shared__ unsigned short tile[64][68];
    const unsigned short* s = src + (long)blockIdx.z * sS;
    unsigned short* d = dst + (long)blockIdx.z * sD;
    const int r0 = blockIdx.y * 64, c0 = blockIdx.x * 64;
    const int t = threadIdx.x;
    const int lr = t >> 4, lc4 = (t & 15) * 4;
#pragma unroll
    for (int i = 0; i < 4; ++i) {
        int r = lr + i * 16;
        *(uint2*)&tile[r][lc4] = *(const uint2*)&s[(long)(r0 + r) * C + c0 + lc4];
    }
    __syncthreads();
#pragma unroll
    for (int i = 0; i < 4; ++i) {
        int r = lr + i * 16;
        unsigned short v[4];
#pragma unroll
        for (int j = 0; j < 4; ++j) v[j] = tile[lc4 + j][r];
        *(uint2*)&d[(long)(c0 + r) * R + r0 + lc4] = *(uint2*)v;
    }
}

// ---------------------------------------------------------------------------
// MFMA bf16 NT GEMM with global_load_lds staging (validated round 6-8):
// C = A(M,K) @ Bt(N,K)^T. 128x128 tile, BK=32.
// XORB: B batch index = z^16 (merged Cr/Cl trick; adjacency-dependent).
// ---------------------------------------------------------------------------
template <int EPI, typename TC, int XORB = 0>
__global__ __launch_bounds__(256) void gemm_nt_mfma(
    const bf16* __restrict__ Ag, const bf16* __restrict__ Btg,
    TC* __restrict__ Cg, int M, int N, int K,
    long sA, long sB, long sC, float alpha)
{
    __shared__ unsigned short Asm[128 * 32];
    __shared__ unsigned short Bsm[128 * 32];

    const int tid  = threadIdx.x;
    const int wv   = tid >> 6;
    const int lane = tid & 63;
    const int q    = lane >> 4;
    const int ln   = lane & 15;
    const int wm   = wv & 1;
    const int wn   = wv >> 1;

    const int zb = XORB ? ((int)blockIdx.z ^ 16) : (int)blockIdx.z;
    const bf16* A  = Ag  + (long)blockIdx.z * sA + (long)(blockIdx.y * 128) * K;
    const bf16* Bt = Btg + (long)zb * sB + (long)(blockIdx.x * 128) * K;
    TC*         C  = Cg  + (long)blockIdx.z * sC;

    const int sr = lane >> 2, sc = lane & 3;
    const bf16* gA0 = A  + (long)(wv * 32 + sr)      * K + sc * 8;
    const bf16* gA1 = A  + (long)(wv * 32 + 16 + sr) * K + sc * 8;
    const bf16* gB0 = Bt + (long)(wv * 32 + sr)      * K + sc * 8;
    const bf16* gB1 = Bt + (long)(wv * 32 + 16 + sr) * K + sc * 8;
    unsigned short* lA0 = &Asm[(wv * 32)      * 32];
    unsigned short* lA1 = &Asm[(wv * 32 + 16) * 32];
    unsigned short* lB0 = &Bsm[(wv * 32)      * 32];
    unsigned short* lB1 = &Bsm[(wv * 32 + 16) * 32];

    f32x4 acc[4][4];
#pragma unroll
    for (int i = 0; i < 4; ++i)
#pragma unroll
        for (int j = 0; j < 4; ++j)
            acc[i][j] = (f32x4){0.f, 0.f, 0.f, 0.f};

    for (int k0 = 0; k0 < K; k0 += 32) {
        __syncthreads();
        gl_lds16(gA0 + k0, lA0);
        gl_lds16(gA1 + k0, lA1);
        gl_lds16(gB0 + k0, lB0);
        gl_lds16(gB1 + k0, lB1);
        __syncthreads();

        short8 af[4], bfr[4];
#pragma unroll
        for (int mt = 0; mt < 4; ++mt) {
            int m = wm * 64 + mt * 16 + ln;
            af[mt] = *(const short8*)&Asm[m * 32 + q * 8];
        }
#pragma unroll
        for (int nt = 0; nt < 4; ++nt) {
            int n = wn * 64 + nt * 16 + ln;
            bfr[nt] = *(const short8*)&Bsm[n * 32 + q * 8];
        }
#pragma unroll
        for (int mt = 0; mt < 4; ++mt)
#pragma unroll
            for (int nt = 0; nt < 4; ++nt)
                acc[mt][nt] = __builtin_amdgcn_mfma_f32_16x16x32_bf16(
                    af[mt], bfr[nt], acc[mt][nt], 0, 0, 0);
    }

#pragma unroll
    for (int mt = 0; mt < 4; ++mt) {
#pragma unroll
        for (int nt = 0; nt < 4; ++nt) {
            const int col = blockIdx.x * 128 + wn * 64 + nt * 16 + ln;
            const int rowb = blockIdx.y * 128 + wm * 64 + mt * 16 + q * 4;
#pragma unroll
            for (int r = 0; r < 4; ++r) {
                float v = acc[mt][nt][r] * alpha;
                if (EPI == 1) v = __logf(fmaxf(v, 0.f) + EPSF);
                stf(C, (long)(rowb + r) * N + col, v);
            }
        }
    }
}

// ---------------------------------------------------------------------------
// QKV via MFMA, merged sets (validated round 6-8).
// ---------------------------------------------------------------------------
__global__ __launch_bounds__(256) void qkv_mfma(
    const bf16* __restrict__ X,
    const bf16* __restrict__ w1t, const bf16* __restrict__ w2t,
    bf16* __restrict__ q1, bf16* __restrict__ k1, bf16* __restrict__ v1,
    bf16* __restrict__ q2, bf16* __restrict__ k2, bf16* __restrict__ v2)
{
    constexpr int K = Dc;  // 512
    __shared__ unsigned short Asm[128 * 32];
    __shared__ unsigned short Bsm[128 * 32];

    const int tid  = threadIdx.x;
    const int wv   = tid >> 6;
    const int lane = tid & 63;
    const int q    = lane >> 4;
    const int ln   = lane & 15;
    const int wm   = wv & 1;
    const int wn   = wv >> 1;
    const int set  = blockIdx.z;

    const bf16* Wt = set ? w2t : w1t;
    bf16* Q  = set ? q2 : q1;
    bf16* Ko = set ? k2 : k1;
    bf16* V  = set ? v2 : v1;

    const bf16* A  = X  + (long)(blockIdx.y * 128) * K;
    const bf16* Bt = Wt + (long)(blockIdx.x * 128) * K;

    const int sr = lane >> 2, sc = lane & 3;
    const bf16* gA0 = A  + (long)(wv * 32 + sr)      * K + sc * 8;
    const bf16* gA1 = A  + (long)(wv * 32 + 16 + sr) * K + sc * 8;
    const bf16* gB0 = Bt + (long)(wv * 32 + sr)      * K + sc * 8;
    const bf16* gB1 = Bt + (long)(wv * 32 + 16 + sr) * K + sc * 8;
    unsigned short* lA0 = &Asm[(wv * 32)      * 32];
    unsigned short* lA1 = &Asm[(wv * 32 + 16) * 32];
    unsigned short* lB0 = &Bsm[(wv * 32)      * 32];
    unsigned short* lB1 = &Bsm[(wv * 32 + 16) * 32];

    f32x4 acc[4][4];
#pragma unroll
    for (int i = 0; i < 4; ++i)
#pragma unroll
        for (int j = 0; j < 4; ++j)
            acc[i][j] = (f32x4){0.f, 0.f, 0.f, 0.f};

    for (int k0 = 0; k0 < K; k0 += 32) {
        __syncthreads();
        gl_lds16(gA0 + k0, lA0);
        gl_lds16(gA1 + k0, lA1);
        gl_lds16(gB0 + k0, lB0);
        gl_lds16(gB1 + k0, lB1);
        __syncthreads();

        short8 af[4], bfr[4];
#pragma unroll
        for (int mt = 0; mt < 4; ++mt) {
            int m = wm * 64 + mt * 16 + ln;
            af[mt] = *(const short8*)&Asm[m * 32 + q * 8];
        }
#pragma unroll
        for (int nt = 0; nt < 4; ++nt) {
            int n = wn * 64 + nt * 16 + ln;
            bfr[nt] = *(const short8*)&Bsm[n * 32 + q * 8];
        }
#pragma unroll
        for (int mt = 0; mt < 4; ++mt)
#pragma unroll
            for (int nt = 0; nt < 4; ++nt)
                acc[mt][nt] = __builtin_amdgcn_mfma_f32_16x16x32_bf16(
                    af[mt], bfr[nt], acc[mt][nt], 0, 0, 0);
    }

#pragma unroll
    for (int mt = 0; mt < 4; ++mt) {
#pragma unroll
        for (int nt = 0; nt < 4; ++nt) {
            const int col  = blockIdx.x * 128 + wn * 64 + nt * 16 + ln;
            const int rowb = blockIdx.y * 128 + wm * 64 + mt * 16 + q * 4;
            const int t = col >> 9;
            const int h = (col >> 6) & 7;
            const int dk = col & 63;
            bf16* dst = (t == 0) ? Q : (t == 1) ? Ko : V;
#pragma unroll
            for (int r = 0; r < 4; ++r) {
                const int row = rowb + r;
                const int b = row >= Nc ? 1 : 0;
                const int n = row - b * Nc;
                dst[(((long)b * Hc + h) * Nc + n) * DKc + dk] =
                    __float2bfloat16(acc[mt][nt][r]);
            }
        }
    }
}

// ---------------------------------------------------------------------------
// MFMA bf16 NT narrow GEMM core (validated): acc = A(128,K) @ Bt(64,K)^T.
// ---------------------------------------------------------------------------
struct N64Acc { f32x4 acc[2][4]; };

template <typename DUMMY = void>
DEVINL void n64_core(const bf16* A, const bf16* Bt, int K,
                     unsigned short* Asm, unsigned short* Bsm, N64Acc& R)
{
    const int tid  = threadIdx.x;
    const int wave = tid >> 6;
    const int lane = tid & 63;
    const int q    = lane >> 4;
    const int ln   = lane & 15;

    const int sr = tid >> 3, k8 = tid & 7;
    const bf16* pa[4];
    const bf16* pb[2];
    int wa[4], wb[2];
#pragma unroll
    for (int i = 0; i < 4; ++i) {
        pa[i] = A + (long)(sr + i * 32) * K + k8 * 8;
        wa[i] = (sr + i * 32) * 72 + k8 * 8;
    }
#pragma unroll
    for (int i = 0; i < 2; ++i) {
        pb[i] = Bt + (long)(sr + i * 32) * K + k8 * 8;
        wb[i] = (sr + i * 32) * 72 + k8 * 8;
    }

#pragma unroll
    for (int i = 0; i < 2; ++i)
#pragma unroll
        for (int j = 0; j < 4; ++j)
            R.acc[i][j] = (f32x4){0.f, 0.f, 0.f, 0.f};

    for (int k0 = 0; k0 < K; k0 += 64) {
        uint4 va[4], vb[2];
#pragma unroll
        for (int i = 0; i < 4; ++i) va[i] = *(const uint4*)(pa[i] + k0);
#pragma unroll
        for (int i = 0; i < 2; ++i) vb[i] = *(const uint4*)(pb[i] + k0);
        __syncthreads();
#pragma unroll
        for (int i = 0; i < 4; ++i) *(uint4*)&Asm[wa[i]] = va[i];
#pragma unroll
        for (int i = 0; i < 2; ++i) *(uint4*)&Bsm[wb[i]] = vb[i];
        __syncthreads();

#pragma unroll
        for (int kc = 0; kc < 2; ++kc) {
            short8 af[2], bfr[4];
#pragma unroll
            for (int mt = 0; mt < 2; ++mt) {
                int m = wave * 32 + mt * 16 + ln;
                af[mt] = *(const short8*)&Asm[m * 72 + kc * 32 + q * 8];
            }
#pragma unroll
            for (int nt = 0; nt < 4; ++nt) {
                int n = nt * 16 + ln;
                bfr[nt] = *(const short8*)&Bsm[n * 72 + kc * 32 + q * 8];
            }
#pragma unroll
            for (int mt = 0; mt < 2; ++mt)
#pragma unroll
                for (int nt = 0; nt < 4; ++nt)
                    R.acc[mt][nt] = __builtin_amdgcn_mfma_f32_16x16x32_bf16(
                        af[mt], bfr[nt], R.acc[mt][nt], 0, 0, 0);
        }
    }
}

// Merged pair launch: z<16 -> C0 = A0@B0t (transport); z>=16 -> C1 = A1@B1t.
__global__ __launch_bounds__(256) void gemm_n64_pair(
    const bf16* __restrict__ A0g, const bf16* __restrict__ B0g, bf16* __restrict__ C0g,
    const bf16* __restrict__ A1g, const bf16* __restrict__ B1g, bf16* __restrict__ C1g,
    int M, int K, long sA, long sB, long sC)
{
    __shared__ unsigned short Asm[128 * 72];
    __shared__ unsigned short Bsm[64 * 72];

    const int zz = blockIdx.z & 15;
    const int second = blockIdx.z >> 4;
    const bf16* A  = (second ? A1g : A0g) + (long)zz * sA + (long)(blockIdx.y * 128) * K;
    const bf16* Bt = (second ? B1g : B0g) + (long)zz * sB;
    bf16*       C  = (second ? C1g : C0g) + (long)zz * sC;

    N64Acc R;
    n64_core(A, Bt, K, Asm, Bsm, R);

    const int tid = threadIdx.x;
    const int wave = tid >> 6, lane = tid & 63, q = lane >> 4, ln = lane & 15;
#pragma unroll
    for (int mt = 0; mt < 2; ++mt) {
#pragma unroll
        for (int nt = 0; nt < 4; ++nt) {
            const int col  = nt * 16 + ln;
            const int rowb = blockIdx.y * 128 + wave * 32 + mt * 16 + q * 4;
#pragma unroll
            for (int r = 0; r < 4; ++r)
                C[(long)(rowb + r) * 64 + col] = __float2bfloat16(R.acc[mt][nt][r]);
        }
    }
}

// y_chain GEMM with fused combine + permute: yc[(b*Nc+n)*Dc + h*64+dk] =
// yb1[...] + w*acc (kills combine_y launch + yb2 round-trip).
__global__ __launch_bounds__(256) void gemm_n64_combine(
    const bf16* __restrict__ A1b, const bf16* __restrict__ trt,
    const bf16* __restrict__ yb1, const float* __restrict__ smallf,
    bf16* __restrict__ yc, int M, int K, long sA, long sB)
{
    __shared__ unsigned short Asm[128 * 72];
    __shared__ unsigned short Bsm[64 * 72];

    const int bh = blockIdx.z;
    const bf16* A  = A1b + (long)bh * sA + (long)(blockIdx.y * 128) * K;
    const bf16* Bt = trt + (long)bh * sB;

    N64Acc R;
    n64_core(A, Bt, K, Asm, Bsm, R);

    const float w = sigf(smallf[180]);
    const int b = bh >> 3, h = bh & 7;
    const long yb1base = (long)bh * Nc * DKc;

    const int tid = threadIdx.x;
    const int wave = tid >> 6, lane = tid & 63, q = lane >> 4, ln = lane & 15;
#pragma unroll
    for (int mt = 0; mt < 2; ++mt) {
#pragma unroll
        for (int nt = 0; nt < 4; ++nt) {
            const int col  = nt * 16 + ln;
            const int rowb = blockIdx.y * 128 + wave * 32 + mt * 16 + q * 4;
#pragma unroll
            for (int r = 0; r < 4; ++r) {
                const int n = rowb + r;
                const float base = __bfloat162float(yb1[yb1base + (long)n * 64 + col]);
                yc[((long)(b * Nc + n)) * Dc + h * DKc + col] =
                    __float2bfloat16(base + w * R.acc[mt][nt][r]);
            }
        }
    }
}

// ---------------------------------------------------------------------------
// Row softmax over width 768 (validated).
// ---------------------------------------------------------------------------
template <typename TO>
__global__ __launch_bounds__(256) void softmax_rows(const float* src, TO* dst)
{
    __shared__ float red[4];
    const long row = blockIdx.x;
    const float* s = src + row * Nc;
    TO* d = dst + row * Nc;
    const int tid = threadIdx.x;

    float v[3];
    float m = -1e30f;
#pragma unroll
    for (int i = 0; i < 3; ++i) { v[i] = s[tid + i * 256]; m = fmaxf(m, v[i]); }

#pragma unroll
    for (int off = 32; off > 0; off >>= 1) m = fmaxf(m, __shfl_down(m, off, 64));
    if ((tid & 63) == 0) red[tid >> 6] = m;
    __syncthreads();
    if (tid == 0) {
        float mm = red[0];
        for (int w = 1; w < 4; ++w) mm = fmaxf(mm, red[w]);
        red[0] = mm;
    }
    __syncthreads();
    m = red[0];
    __syncthreads();

    float e[3];
    float sum = 0.f;
#pragma unroll
    for (int i = 0; i < 3; ++i) { e[i] = __expf(v[i] - m); sum += e[i]; }
#pragma unroll
    for (int off = 32; off > 0; off >>= 1) sum += __shfl_down(sum, off, 64);
    if ((tid & 63) == 0) red[tid >> 6] = sum;
    __syncthreads();
    if (tid == 0) red[0] = red[0] + red[1] + red[2] + red[3];
    __syncthreads();
    const float inv = 1.f / fmaxf(red[0], 1e-30f);
#pragma unroll
    for (int i = 0; i < 3; ++i) stf(d, tid + i * 256, e[i] * inv);
}

// ---------------------------------------------------------------------------
// Gate network + Smix — 2 elements/thread: keeps VGPR under the 8-wave/SIMD
// cliff (4/thread hit VGPR 100 -> occ 22% -> slower) while doubling exp-chain
// ILP vs 1/thread (140 us, VALU-saturated). Same fast math as round 8.
// ---------------------------------------------------------------------------
__global__ __launch_bounds__(256) void gates_smix(
    const float* __restrict__ S1g, const float* __restrict__ S2g,
    const bf16* __restrict__ Crg, const bf16* __restrict__ Clg,
    float* __restrict__ Smixg, const float* __restrict__ smallf)
{
    __shared__ float t1t[32][17], t2t[32][17];
    __shared__ float cs[192];

    const long mat = (long)blockIdx.z * Nc * Nc;
    const float* S1 = S1g + mat;
    const float* S2 = S2g + mat;
    const unsigned short* Cr = (const unsigned short*)Crg + mat;
    const unsigned short* Cl = (const unsigned short*)Clg + mat;
    float* Smix = Smixg + mat;

    const int tid = threadIdx.x;
    if (tid < 192) cs[tid] = smallf[tid];

    const int n0 = blockIdx.y * 16, m0 = blockIdx.x * 32;
    {   // transposed tiles: S[m0..m0+31][n0..n0+15], coalesced float2 loads
        const int r = tid >> 3, c2 = (tid & 7) * 2;
        const float2 a = *(const float2*)&S1[(long)(m0 + r) * Nc + n0 + c2];
        const float2 b = *(const float2*)&S2[(long)(m0 + r) * Nc + n0 + c2];
        t1t[r][c2] = a.x; t1t[r][c2 + 1] = a.y;
        t2t[r][c2] = b.x; t2t[r][c2 + 1] = b.y;
    }
    __syncthreads();

    const float* cw1 = cs;       const float* cb1 = cs + 96;
    const float* cw2 = cs + 112; const float* cb2 = cs + 176;

    const int tx = tid & 15, ty = tid >> 4;
    const int n = n0 + ty;
    const long idx = (long)n * Nc + m0 + tx * 2;

    const float2 s1v = *(const float2*)&S1[idx];
    const float2 s2v = *(const float2*)&S2[idx];
    const unsigned cru = *(const unsigned*)&Cr[idx];   // idx even -> 4B aligned
    const unsigned clu = *(const unsigned*)&Cl[idx];

    float s1a[2] = {s1v.x, s1v.y};
    float s2a[2] = {s2v.x, s2v.y};
    float cra[2] = {__uint_as_float((cru & 0xffffu) << 16),
                    __uint_as_float(cru & 0xffff0000u)};
    float cla[2] = {__uint_as_float((clu & 0xffffu) << 16),
                    __uint_as_float(clu & 0xffff0000u)};
    float s1t[2], s2t[2];
#pragma unroll
    for (int j = 0; j < 2; ++j) {
        s1t[j] = t1t[tx * 2 + j][ty];
        s2t[j] = t2t[tx * 2 + j][ty];
    }

    float g[4][2];
#pragma unroll
    for (int o = 0; o < 4; ++o)
#pragma unroll
        for (int j = 0; j < 2; ++j) g[o][j] = cb2[o];

#pragma unroll
    for (int u = 0; u < 16; ++u) {
        const float wf0 = cw1[u * 6 + 0], wf1 = cw1[u * 6 + 1], wf2 = cw1[u * 6 + 2];
        const float wf3 = cw1[u * 6 + 3], wf4 = cw1[u * 6 + 4], wf5 = cw1[u * 6 + 5];
        const float bu = cb1[u];
        float hid[2];
#pragma unroll
        for (int j = 0; j < 2; ++j) {
            float h = bu;
            h = fmaf(s1a[j], wf0, h);
            h = fmaf(s2a[j], wf1, h);
            h = fmaf(s1t[j], wf2, h);
            h = fmaf(s2t[j], wf3, h);
            h = fmaf(cra[j], wf4, h);
            h = fmaf(cla[j], wf5, h);
            const float hh = h * h;
            const float z2 = h * fmaf(hh, -0.0713548162f, -1.5957691216f);
            const float e = __expf(z2);
            hid[j] = h * __fdividef(1.f, 1.f + e);
        }
#pragma unroll
        for (int o = 0; o < 4; ++o) {
            const float w2o = cw2[o * 16 + u];
#pragma unroll
            for (int j = 0; j < 2; ++j) g[o][j] = fmaf(hid[j], w2o, g[o][j]);
        }
    }

    float out[2];
#pragma unroll
    for (int j = 0; j < 2; ++j) {
        const float ga = sigf(g[0][j]);
        const float go = sigf(g[1][j]);
        const float gn = sigf(g[2][j]);
        const float gc = sigf(g[3][j]);
        const float s1 = s1a[j], s2 = s2a[j];
        const float mx = fmaxf(s1, s2);
        const float lae = mx + __logf(1.f + __expf(-fabsf(s1 - s2)));
        out[j] = s1 + ga * s2 + go * (lae - s1) - gn * (BETA_NOT * s2) + gc * cra[j];
    }
    *(float2*)&Smix[idx] = (float2){out[0], out[1]};
}

// ---------------------------------------------------------------------------
// Final projection via MFMA (validated round 7-8).
// ---------------------------------------------------------------------------
__global__ __launch_bounds__(256) void proj_mfma(
    const bf16* __restrict__ yc, const bf16* __restrict__ pwt,
    const void* __restrict__ xraw, void* __restrict__ out)
{
    constexpr int K = Dc;  // 512
    constexpr int N = Dc;  // 512
    __shared__ unsigned short Asm[128 * 32];
    __shared__ unsigned short Bsm[128 * 32];
    __shared__ int is32s;

    const int tid  = threadIdx.x;
    if (tid == 0) is32s = sniff_is_fp32(xraw);
    const int wv   = tid >> 6;
    const int lane = tid & 63;
    const int q    = lane >> 4;
    const int ln   = lane & 15;
    const int wm   = wv & 1;
    const int wn   = wv >> 1;

    const bf16* A  = yc  + (long)(blockIdx.y * 128) * K;
    const bf16* Bt = pwt + (long)(blockIdx.x * 128) * K;

    const int sr = lane >> 2, sc = lane & 3;
    const bf16* gA0 = A  + (long)(wv * 32 + sr)      * K + sc * 8;
    const bf16* gA1 = A  + (long)(wv * 32 + 16 + sr) * K + sc * 8;
    const bf16* gB0 = Bt + (long)(wv * 32 + sr)      * K + sc * 8;
    const bf16* gB1 = Bt + (long)(wv * 32 + 16 + sr) * K + sc * 8;
    unsigned short* lA0 = &Asm[(wv * 32)      * 32];
    unsigned short* lA1 = &Asm[(wv * 32 + 16) * 32];
    unsigned short* lB0 = &Bsm[(wv * 32)      * 32];
    unsigned short* lB1 = &Bsm[(wv * 32 + 16) * 32];

    f32x4 acc[4][4];
#pragma unroll
    for (int i = 0; i < 4; ++i)
#pragma unroll
        for (int j = 0; j < 4; ++j)
            acc[i][j] = (f32x4){0.f, 0.f, 0.f, 0.f};

    for (int k0 = 0; k0 < K; k0 += 32) {
        __syncthreads();
        gl_lds16(gA0 + k0, lA0);
        gl_lds16(gA1 + k0, lA1);
        gl_lds16(gB0 + k0, lB0);
        gl_lds16(gB1 + k0, lB1);
        __syncthreads();

        short8 af[4], bfr[4];
#pragma unroll
        for (int mt = 0; mt < 4; ++mt) {
            int m = wm * 64 + mt * 16 + ln;
            af[mt] = *(const short8*)&Asm[m * 32 + q * 8];
        }
#pragma unroll
        for (int nt = 0; nt < 4; ++nt) {
            int n = wn * 64 + nt * 16 + ln;
            bfr[nt] = *(const short8*)&Bsm[n * 32 + q * 8];
        }
#pragma unroll
        for (int mt = 0; mt < 4; ++mt)
#pragma unroll
            for (int nt = 0; nt < 4; ++nt)
                acc[mt][nt] = __builtin_amdgcn_mfma_f32_16x16x32_bf16(
                    af[mt], bfr[nt], acc[mt][nt], 0, 0, 0);
    }

    const int is32 = is32s;
#pragma unroll
    for (int mt = 0; mt < 4; ++mt) {
#pragma unroll
        for (int nt = 0; nt < 4; ++nt) {
            const int col = blockIdx.x * 128 + wn * 64 + nt * 16 + ln;
            const int rowb = blockIdx.y * 128 + wm * 64 + mt * 16 + q * 4;
#pragma unroll
            for (int r = 0; r < 4; ++r) {
                const long o = (long)(rowb + r) * N + col;
                if (is32) ((float*)out)[o] = acc[mt][nt][r];
                else      ((bf16*)out)[o] = __float2bfloat16(acc[mt][nt][r]);
            }
        }
    }
}

// ---------------------------------------------------------------------------
extern "C" void kernel_launch(void* const* d_in, const int* in_sizes, int n_in,
                              void* d_out, int out_size, void* d_ws, size_t ws_size,
                              hipStream_t stream)
{
    const size_t HD   = (size_t)BHc * Nc * DKc;   // 786432
    const size_t HDh  = HD / 2;                   // float-slots for HD bf16
    const size_t MAT  = (size_t)Nc * Nc;          // 589824
    const size_t MATS = (size_t)BHc * MAT;        // 9437184
    const long   HSTR = (long)Nc * DKc;           // 49152 per-head stride

    float* ws = (float*)d_ws;
    size_t off = 0;
    auto alloc = [&](size_t n) { float* p = ws + off; off += n; return p; };

    bf16* xb  = (bf16*)alloc(HDh);
    bf16* w1b = (bf16*)alloc(HDh);   // w1b/w2b adjacent -> merged transpose
    bf16* w2b = (bf16*)alloc(HDh);
    bf16* w1t = (bf16*)alloc(HDh);
    bf16* w2t = (bf16*)alloc(HDh);
    bf16* pwb = (bf16*)alloc((size_t)Dc * Dc / 2);
    bf16* pwt = (bf16*)alloc((size_t)Dc * Dc / 2);
    float* smallf = alloc(192);
    // q1|q2 and k1|k2 adjacent -> single merged S-GEMM launch (32 heads)
    bf16* q1b = (bf16*)alloc(HDh); bf16* q2b = (bf16*)alloc(HDh);
    bf16* k1b = (bf16*)alloc(HDh); bf16* k2b = (bf16*)alloc(HDh);
    bf16* v1b = (bf16*)alloc(HDh); bf16* v2b = (bf16*)alloc(HDh);  // adjacent
    bf16* v1t = (bf16*)alloc(HDh); bf16* v2t = (bf16*)alloc(HDh);  // adjacent
    bf16* trb = (bf16*)alloc(HDh);
    bf16* trt = (bf16*)alloc(HDh);
    float* S1   = alloc(MATS);       // S1/S2 adjacent -> merged softmax + S-GEMM
    float* S2   = alloc(MATS);
    float* Smix = alloc(MATS);
    bf16* A1b = (bf16*)alloc(MATS / 2);  // A1b/A2b adjacent
    bf16* A2b = (bf16*)alloc(MATS / 2);
    bf16* Crb = (bf16*)alloc(MATS / 2);  // Crb/Clb adjacent (merged launch)
    bf16* Clb = (bf16*)alloc(MATS / 2);
    bf16* yb1 = (bf16*)alloc(HDh);
    bf16* yc  = (bf16*)alloc(HDh);

    // aliases into dead regions
    bf16* A1tb = (bf16*)Smix;            // dead until gates writes Smix
    bf16* A2tb = ((bf16*)Smix) + MATS;   // A1tb/A2tb adjacent
    bf16* Ab   = (bf16*)S1;              // S1 dead after gates

    const size_t NEED_BYTES = off * sizeof(float);
    if (ws_size < NEED_BYTES) {
        fill_sentinel<<<dim3(3072), 256, 0, stream>>>((unsigned short*)d_out);
        return;
    }

    // 0. normalize inputs
    convert_all<<<dim3(3072), 256, 0, stream>>>(
        d_in[0], d_in[1], d_in[2], d_in[3], d_in[4], d_in[5], d_in[6], d_in[7],
        d_in[8], xb, w1b, w2b, pwb, smallf);

    // 1. merged W transposes; pw transpose; merged QKV; merged v transposes
    transpose_bf16<<<dim3(24, 8, 2), 256, 0, stream>>>(
        (const unsigned short*)w1b, (unsigned short*)w1t, Dc, 3 * Dc, (long)HD, (long)HD);
    transpose_bf16<<<dim3(8, 8, 1), 256, 0, stream>>>(
        (const unsigned short*)pwb, (unsigned short*)pwt, Dc, Dc, 0, 0);
    qkv_mfma<<<dim3(12, 12, 2), 256, 0, stream>>>(
        xb, w1t, w2t, q1b, k1b, v1b, q2b, k2b, v2b);
    transpose_bf16<<<dim3(1, 12, 2 * BHc), 256, 0, stream>>>(
        (const unsigned short*)v1b, (unsigned short*)v1t, Nc, DKc, HSTR, HSTR);

    // 2. S = scale * q @ k^T — single 32-batch launch
    gemm_nt_mfma<0, float><<<dim3(6, 6, 2 * BHc), 256, 0, stream>>>(
        q1b, k1b, S1, Nc, Nc, DKc, HSTR, HSTR, (long)MAT, SCALE);

    // 3. merged softmax S1|S2 -> A1b|A2b; merged transposes -> A1tb|A2tb
    softmax_rows<bf16><<<2 * BHc * Nc, 256, 0, stream>>>(S1, A1b);
    transpose_bf16<<<dim3(12, 12, 2 * BHc), 256, 0, stream>>>(
        (const unsigned short*)A1b, (unsigned short*)A1tb, Nc, Nc, (long)MAT, (long)MAT);

    // 4. Cr|Cl in ONE 32-batch launch: z<16 Cr = A1[z] @ A2t[z] (Bt idx z^16),
    //    z>=16 Cl = A2[z-16] @ A1t[z-16] (A = A1b+z*MAT, Bt idx z^16). C adj.
    gemm_nt_mfma<1, bf16, 1><<<dim3(6, 6, 2 * BHc), 256, 0, stream>>>(
        A1b, A1tb, Crb, Nc, Nc, Nc, (long)MAT, (long)MAT, (long)MAT, 1.f);

    // 5. gates + Smix (2 elem/thread)
    gates_smix<<<dim3(24, 48, BHc), 256, 0, stream>>>(S1, S2, Crb, Clb, Smix, smallf);

    // 6. A = softmax(Smix) -> bf16 (into S1 alias)
    softmax_rows<bf16><<<BHc * Nc, 256, 0, stream>>>(Smix, Ab);

    // 7. merged: transport = A2 @ v2 (z<16) | y_base = A @ v1 (z>=16)
    gemm_n64_pair<<<dim3(1, 6, 2 * BHc), 256, 0, stream>>>(
        A2b, v2t, trb, Ab, v1t, yb1, Nc, Nc, (long)MAT, HSTR, HSTR);
    transpose_bf16<<<dim3(1, 12, BHc), 256, 0, stream>>>(
        (const unsigned short*)trb, (unsigned short*)trt, Nc, DKc, HSTR, HSTR);

    // 8. y_chain GEMM with fused combine + permute -> yc
    gemm_n64_combine<<<dim3(1, 6, BHc), 256, 0, stream>>>(
        A1b, trt, yb1, smallf, yc, Nc, Nc, (long)MAT, HSTR);

    // 9. proj via MFMA + dtype-aware store
    proj_mfma<<<dim3(4, 12, 1), 256, 0, stream>>>(yc, pwt, d_in[0], d_out);
}

// Round 10
// 462.231 us; speedup vs baseline: 1.4593x; 1.0041x over previous
//
#include <hip/hip_runtime.h>
#include <hip/hip_bf16.h>
#include <math.h>

typedef __hip_bfloat16 bf16;
typedef __attribute__((ext_vector_type(8))) short short8;   // 8 bf16 (4 VGPRs)
typedef __attribute__((ext_vector_type(4))) float f32x4;
typedef __attribute__((ext_vector_type(2))) float f32x2;    // -> v_pk_*_f32
#define DEVINL __device__ __forceinline__

constexpr int Bc  = 2;
constexpr int Nc  = 768;
constexpr int Dc  = 512;
constexpr int Hc  = 8;
constexpr int DKc = 64;
constexpr int BHc = Bc * Hc;
constexpr float SCALE    = 0.125f;   // 1/sqrt(64)
constexpr float EPSF     = 1e-6f;
constexpr float BETA_NOT = 0.5f;

DEVINL float ldf(const float* p, long i) { return p[i]; }
DEVINL float ldf(const bf16* p, long i) { return __bfloat162float(p[i]); }
DEVINL void stf(float* p, long i, float v) { p[i] = v; }
DEVINL void stf(bf16* p, long i, float v) { p[i] = __float2bfloat16(v); }

DEVINL float sigf(float x) { return __fdividef(1.f, 1.f + __expf(-x)); }

// async global->LDS, 16B per lane; LDS dest = wave-uniform base + lane*16.
DEVINL void gl_lds16(const void* g, void* l) {
    __builtin_amdgcn_global_load_lds(
        (const __attribute__((address_space(1))) void*)g,
        (__attribute__((address_space(3))) void*)l, 16, 0, 0);
}

// ---------------------------------------------------------------------------
// Dtype sniffer — vectorized (validated round 9).
// ---------------------------------------------------------------------------
DEVINL int sniff_is_fp32(const void* xraw) {
    const uint4* p4 = (const uint4*)xraw;
    float mx = 0.f;
#pragma unroll
    for (int j = 0; j < 16; ++j) {
        const uint4 u = p4[j];
        const unsigned w[4] = {u.x, u.y, u.z, u.w};
#pragma unroll
        for (int t = 0; t < 4; ++t) {
            mx = fmaxf(mx, fabsf(__uint_as_float((w[t] & 0xffffu) << 16)));
            mx = fmaxf(mx, fabsf(__uint_as_float(w[t] & 0xffff0000u)));
        }
    }
    return mx > 1000.f ? 1 : 0;
}

DEVINL float cvt_elem(const void* s, long j, int is32) {
    return is32 ? ((const float*)s)[j]
                : __bfloat162float(((const bf16*)s)[j]);
}

__global__ __launch_bounds__(256) void convert_all(
    const void* x, const void* w1, const void* w2, const void* pw,
    const void* c1w, const void* c1b, const void* c2w, const void* c2b,
    const void* ch,
    bf16* xb, bf16* w1b, bf16* w2b, bf16* pwb, float* smallf)
{
    __shared__ int is32s;
    if (threadIdx.x == 0) is32s = sniff_is_fp32(x);
    __syncthreads();
    const int is32 = is32s;
    const long i = (long)blockIdx.x * 256 + threadIdx.x;
    if (i < (long)Bc * Nc * Dc) {
        xb[i]  = __float2bfloat16(cvt_elem(x,  i, is32));
        w1b[i] = __float2bfloat16(cvt_elem(w1, i, is32));
        w2b[i] = __float2bfloat16(cvt_elem(w2, i, is32));
    }
    if (i < (long)Dc * Dc) pwb[i] = __float2bfloat16(cvt_elem(pw, i, is32));
    if (i < 96)       smallf[i] = cvt_elem(c1w, i,        is32);
    else if (i < 112) smallf[i] = cvt_elem(c1b, i - 96,   is32);
    else if (i < 176) smallf[i] = cvt_elem(c2w, i - 112,  is32);
    else if (i < 180) smallf[i] = cvt_elem(c2b, i - 176,  is32);
    else if (i == 180) smallf[180] = cvt_elem(ch, 0, is32);
}

__global__ __launch_bounds__(256) void fill_sentinel(unsigned short* o) {
    const long i = (long)blockIdx.x * 256 + threadIdx.x;
    if (i < (long)Bc * Nc * Dc) o[i] = 0x40E0;  // bf16 7.0
}

// ---------------------------------------------------------------------------
// Generic bf16 transpose, 64x64 tiles: dst[c][r] = src[r][c]; src is (R,C).
// ---------------------------------------------------------------------------
__global__ __launch_bounds__(256) void transpose_bf16(
    const unsigned short* __restrict__ src, unsigned short* __restrict__ dst,
    int R, int C, long sS, long sD)
{
    __shared__ unsigned short tile[64][68];
    const unsigned short* s = src + (long)blockIdx.z * sS;
    unsigned short* d = dst + (long)blockIdx.z * sD;
    const int r0 = blockIdx.y * 64, c0 = blockIdx.x * 64;
    const int t = threadIdx.x;
    const int lr = t >> 4, lc4 = (t & 15) * 4;
#pragma unroll
    for (int i = 0; i < 4; ++i) {
        int r = lr + i * 16;
        *(uint2*)&tile[r][lc4] = *(const uint2*)&s[(long)(r0 + r) * C + c0 + lc4];
    }
    __syncthreads();
#pragma unroll
    for (int i = 0; i < 4; ++i) {
        int r = lr + i * 16;
        unsigned short v[4];
#pragma unroll
        for (int j = 0; j < 4; ++j) v[j] = tile[lc4 + j][r];
        *(uint2*)&d[(long)(c0 + r) * R + r0 + lc4] = *(uint2*)v;
    }
}

// ---------------------------------------------------------------------------
// MFMA bf16 NT GEMM with global_load_lds staging (validated rounds 6-9):
// C = A(M,K) @ Bt(N,K)^T. 128x128 tile, BK=32.
// XORB: B batch index = z^16 (merged Cr/Cl trick; adjacency-dependent).
// ---------------------------------------------------------------------------
template <int EPI, typename TC, int XORB = 0>
__global__ __launch_bounds__(256) void gemm_nt_mfma(
    const bf16* __restrict__ Ag, const bf16* __restrict__ Btg,
    TC* __restrict__ Cg, int M, int N, int K,
    long sA, long sB, long sC, float alpha)
{
    __shared__ unsigned short Asm[128 * 32];
    __shared__ unsigned short Bsm[128 * 32];

    const int tid  = threadIdx.x;
    const int wv   = tid >> 6;
    const int lane = tid & 63;
    const int q    = lane >> 4;
    const int ln   = lane & 15;
    const int wm   = wv & 1;
    const int wn   = wv >> 1;

    const int zb = XORB ? ((int)blockIdx.z ^ 16) : (int)blockIdx.z;
    const bf16* A  = Ag  + (long)blockIdx.z * sA + (long)(blockIdx.y * 128) * K;
    const bf16* Bt = Btg + (long)zb * sB + (long)(blockIdx.x * 128) * K;
    TC*         C  = Cg  + (long)blockIdx.z * sC;

    const int sr = lane >> 2, sc = lane & 3;
    const bf16* gA0 = A  + (long)(wv * 32 + sr)      * K + sc * 8;
    const bf16* gA1 = A  + (long)(wv * 32 + 16 + sr) * K + sc * 8;
    const bf16* gB0 = Bt + (long)(wv * 32 + sr)      * K + sc * 8;
    const bf16* gB1 = Bt + (long)(wv * 32 + 16 + sr) * K + sc * 8;
    unsigned short* lA0 = &Asm[(wv * 32)      * 32];
    unsigned short* lA1 = &Asm[(wv * 32 + 16) * 32];
    unsigned short* lB0 = &Bsm[(wv * 32)      * 32];
    unsigned short* lB1 = &Bsm[(wv * 32 + 16) * 32];

    f32x4 acc[4][4];
#pragma unroll
    for (int i = 0; i < 4; ++i)
#pragma unroll
        for (int j = 0; j < 4; ++j)
            acc[i][j] = (f32x4){0.f, 0.f, 0.f, 0.f};

    for (int k0 = 0; k0 < K; k0 += 32) {
        __syncthreads();
        gl_lds16(gA0 + k0, lA0);
        gl_lds16(gA1 + k0, lA1);
        gl_lds16(gB0 + k0, lB0);
        gl_lds16(gB1 + k0, lB1);
        __syncthreads();

        short8 af[4], bfr[4];
#pragma unroll
        for (int mt = 0; mt < 4; ++mt) {
            int m = wm * 64 + mt * 16 + ln;
            af[mt] = *(const short8*)&Asm[m * 32 + q * 8];
        }
#pragma unroll
        for (int nt = 0; nt < 4; ++nt) {
            int n = wn * 64 + nt * 16 + ln;
            bfr[nt] = *(const short8*)&Bsm[n * 32 + q * 8];
        }
#pragma unroll
        for (int mt = 0; mt < 4; ++mt)
#pragma unroll
            for (int nt = 0; nt < 4; ++nt)
                acc[mt][nt] = __builtin_amdgcn_mfma_f32_16x16x32_bf16(
                    af[mt], bfr[nt], acc[mt][nt], 0, 0, 0);
    }

#pragma unroll
    for (int mt = 0; mt < 4; ++mt) {
#pragma unroll
        for (int nt = 0; nt < 4; ++nt) {
            const int col = blockIdx.x * 128 + wn * 64 + nt * 16 + ln;
            const int rowb = blockIdx.y * 128 + wm * 64 + mt * 16 + q * 4;
#pragma unroll
            for (int r = 0; r < 4; ++r) {
                float v = acc[mt][nt][r] * alpha;
                if (EPI == 1) v = __logf(fmaxf(v, 0.f) + EPSF);
                stf(C, (long)(rowb + r) * N + col, v);
            }
        }
    }
}

// ---------------------------------------------------------------------------
// QKV via MFMA, merged sets (validated rounds 6-9).
// ---------------------------------------------------------------------------
__global__ __launch_bounds__(256) void qkv_mfma(
    const bf16* __restrict__ X,
    const bf16* __restrict__ w1t, const bf16* __restrict__ w2t,
    bf16* __restrict__ q1, bf16* __restrict__ k1, bf16* __restrict__ v1,
    bf16* __restrict__ q2, bf16* __restrict__ k2, bf16* __restrict__ v2)
{
    constexpr int K = Dc;  // 512
    __shared__ unsigned short Asm[128 * 32];
    __shared__ unsigned short Bsm[128 * 32];

    const int tid  = threadIdx.x;
    const int wv   = tid >> 6;
    const int lane = tid & 63;
    const int q    = lane >> 4;
    const int ln   = lane & 15;
    const int wm   = wv & 1;
    const int wn   = wv >> 1;
    const int set  = blockIdx.z;

    const bf16* Wt = set ? w2t : w1t;
    bf16* Q  = set ? q2 : q1;
    bf16* Ko = set ? k2 : k1;
    bf16* V  = set ? v2 : v1;

    const bf16* A  = X  + (long)(blockIdx.y * 128) * K;
    const bf16* Bt = Wt + (long)(blockIdx.x * 128) * K;

    const int sr = lane >> 2, sc = lane & 3;
    const bf16* gA0 = A  + (long)(wv * 32 + sr)      * K + sc * 8;
    const bf16* gA1 = A  + (long)(wv * 32 + 16 + sr) * K + sc * 8;
    const bf16* gB0 = Bt + (long)(wv * 32 + sr)      * K + sc * 8;
    const bf16* gB1 = Bt + (long)(wv * 32 + 16 + sr) * K + sc * 8;
    unsigned short* lA0 = &Asm[(wv * 32)      * 32];
    unsigned short* lA1 = &Asm[(wv * 32 + 16) * 32];
    unsigned short* lB0 = &Bsm[(wv * 32)      * 32];
    unsigned short* lB1 = &Bsm[(wv * 32 + 16) * 32];

    f32x4 acc[4][4];
#pragma unroll
    for (int i = 0; i < 4; ++i)
#pragma unroll
        for (int j = 0; j < 4; ++j)
            acc[i][j] = (f32x4){0.f, 0.f, 0.f, 0.f};

    for (int k0 = 0; k0 < K; k0 += 32) {
        __syncthreads();
        gl_lds16(gA0 + k0, lA0);
        gl_lds16(gA1 + k0, lA1);
        gl_lds16(gB0 + k0, lB0);
        gl_lds16(gB1 + k0, lB1);
        __syncthreads();

        short8 af[4], bfr[4];
#pragma unroll
        for (int mt = 0; mt < 4; ++mt) {
            int m = wm * 64 + mt * 16 + ln;
            af[mt] = *(const short8*)&Asm[m * 32 + q * 8];
        }
#pragma unroll
        for (int nt = 0; nt < 4; ++nt) {
            int n = wn * 64 + nt * 16 + ln;
            bfr[nt] = *(const short8*)&Bsm[n * 32 + q * 8];
        }
#pragma unroll
        for (int mt = 0; mt < 4; ++mt)
#pragma unroll
            for (int nt = 0; nt < 4; ++nt)
                acc[mt][nt] = __builtin_amdgcn_mfma_f32_16x16x32_bf16(
                    af[mt], bfr[nt], acc[mt][nt], 0, 0, 0);
    }

#pragma unroll
    for (int mt = 0; mt < 4; ++mt) {
#pragma unroll
        for (int nt = 0; nt < 4; ++nt) {
            const int col  = blockIdx.x * 128 + wn * 64 + nt * 16 + ln;
            const int rowb = blockIdx.y * 128 + wm * 64 + mt * 16 + q * 4;
            const int t = col >> 9;
            const int h = (col >> 6) & 7;
            const int dk = col & 63;
            bf16* dst = (t == 0) ? Q : (t == 1) ? Ko : V;
#pragma unroll
            for (int r = 0; r < 4; ++r) {
                const int row = rowb + r;
                const int b = row >= Nc ? 1 : 0;
                const int n = row - b * Nc;
                dst[(((long)b * Hc + h) * Nc + n) * DKc + dk] =
                    __float2bfloat16(acc[mt][nt][r]);
            }
        }
    }
}

// ---------------------------------------------------------------------------
// MFMA bf16 NT narrow GEMM core (validated): acc = A(128,K) @ Bt(64,K)^T.
// ---------------------------------------------------------------------------
struct N64Acc { f32x4 acc[2][4]; };

template <typename DUMMY = void>
DEVINL void n64_core(const bf16* A, const bf16* Bt, int K,
                     unsigned short* Asm, unsigned short* Bsm, N64Acc& R)
{
    const int tid  = threadIdx.x;
    const int wave = tid >> 6;
    const int lane = tid & 63;
    const int q    = lane >> 4;
    const int ln   = lane & 15;

    const int sr = tid >> 3, k8 = tid & 7;
    const bf16* pa[4];
    const bf16* pb[2];
    int wa[4], wb[2];
#pragma unroll
    for (int i = 0; i < 4; ++i) {
        pa[i] = A + (long)(sr + i * 32) * K + k8 * 8;
        wa[i] = (sr + i * 32) * 72 + k8 * 8;
    }
#pragma unroll
    for (int i = 0; i < 2; ++i) {
        pb[i] = Bt + (long)(sr + i * 32) * K + k8 * 8;
        wb[i] = (sr + i * 32) * 72 + k8 * 8;
    }

#pragma unroll
    for (int i = 0; i < 2; ++i)
#pragma unroll
        for (int j = 0; j < 4; ++j)
            R.acc[i][j] = (f32x4){0.f, 0.f, 0.f, 0.f};

    for (int k0 = 0; k0 < K; k0 += 64) {
        uint4 va[4], vb[2];
#pragma unroll
        for (int i = 0; i < 4; ++i) va[i] = *(const uint4*)(pa[i] + k0);
#pragma unroll
        for (int i = 0; i < 2; ++i) vb[i] = *(const uint4*)(pb[i] + k0);
        __syncthreads();
#pragma unroll
        for (int i = 0; i < 4; ++i) *(uint4*)&Asm[wa[i]] = va[i];
#pragma unroll
        for (int i = 0; i < 2; ++i) *(uint4*)&Bsm[wb[i]] = vb[i];
        __syncthreads();

#pragma unroll
        for (int kc = 0; kc < 2; ++kc) {
            short8 af[2], bfr[4];
#pragma unroll
            for (int mt = 0; mt < 2; ++mt) {
                int m = wave * 32 + mt * 16 + ln;
                af[mt] = *(const short8*)&Asm[m * 72 + kc * 32 + q * 8];
            }
#pragma unroll
            for (int nt = 0; nt < 4; ++nt) {
                int n = nt * 16 + ln;
                bfr[nt] = *(const short8*)&Bsm[n * 72 + kc * 32 + q * 8];
            }
#pragma unroll
            for (int mt = 0; mt < 2; ++mt)
#pragma unroll
                for (int nt = 0; nt < 4; ++nt)
                    R.acc[mt][nt] = __builtin_amdgcn_mfma_f32_16x16x32_bf16(
                        af[mt], bfr[nt], R.acc[mt][nt], 0, 0, 0);
        }
    }
}

// Merged pair launch: z<16 -> C0 = A0@B0t (transport); z>=16 -> C1 = A1@B1t.
__global__ __launch_bounds__(256) void gemm_n64_pair(
    const bf16* __restrict__ A0g, const bf16* __restrict__ B0g, bf16* __restrict__ C0g,
    const bf16* __restrict__ A1g, const bf16* __restrict__ B1g, bf16* __restrict__ C1g,
    int M, int K, long sA, long sB, long sC)
{
    __shared__ unsigned short Asm[128 * 72];
    __shared__ unsigned short Bsm[64 * 72];

    const int zz = blockIdx.z & 15;
    const int second = blockIdx.z >> 4;
    const bf16* A  = (second ? A1g : A0g) + (long)zz * sA + (long)(blockIdx.y * 128) * K;
    const bf16* Bt = (second ? B1g : B0g) + (long)zz * sB;
    bf16*       C  = (second ? C1g : C0g) + (long)zz * sC;

    N64Acc R;
    n64_core(A, Bt, K, Asm, Bsm, R);

    const int tid = threadIdx.x;
    const int wave = tid >> 6, lane = tid & 63, q = lane >> 4, ln = lane & 15;
#pragma unroll
    for (int mt = 0; mt < 2; ++mt) {
#pragma unroll
        for (int nt = 0; nt < 4; ++nt) {
            const int col  = nt * 16 + ln;
            const int rowb = blockIdx.y * 128 + wave * 32 + mt * 16 + q * 4;
#pragma unroll
            for (int r = 0; r < 4; ++r)
                C[(long)(rowb + r) * 64 + col] = __float2bfloat16(R.acc[mt][nt][r]);
        }
    }
}

// y_chain GEMM with fused combine + permute (validated round 9).
__global__ __launch_bounds__(256) void gemm_n64_combine(
    const bf16* __restrict__ A1b, const bf16* __restrict__ trt,
    const bf16* __restrict__ yb1, const float* __restrict__ smallf,
    bf16* __restrict__ yc, int M, int K, long sA, long sB)
{
    __shared__ unsigned short Asm[128 * 72];
    __shared__ unsigned short Bsm[64 * 72];

    const int bh = blockIdx.z;
    const bf16* A  = A1b + (long)bh * sA + (long)(blockIdx.y * 128) * K;
    const bf16* Bt = trt + (long)bh * sB;

    N64Acc R;
    n64_core(A, Bt, K, Asm, Bsm, R);

    const float w = sigf(smallf[180]);
    const int b = bh >> 3, h = bh & 7;
    const long yb1base = (long)bh * Nc * DKc;

    const int tid = threadIdx.x;
    const int wave = tid >> 6, lane = tid & 63, q = lane >> 4, ln = lane & 15;
#pragma unroll
    for (int mt = 0; mt < 2; ++mt) {
#pragma unroll
        for (int nt = 0; nt < 4; ++nt) {
            const int col  = nt * 16 + ln;
            const int rowb = blockIdx.y * 128 + wave * 32 + mt * 16 + q * 4;
#pragma unroll
            for (int r = 0; r < 4; ++r) {
                const int n = rowb + r;
                const float base = __bfloat162float(yb1[yb1base + (long)n * 64 + col]);
                yc[((long)(b * Nc + n)) * Dc + h * DKc + col] =
                    __float2bfloat16(base + w * R.acc[mt][nt][r]);
            }
        }
    }
}

// ---------------------------------------------------------------------------
// Row softmax over width 768 (validated).
// ---------------------------------------------------------------------------
template <typename TO>
__global__ __launch_bounds__(256) void softmax_rows(const float* src, TO* dst)
{
    __shared__ float red[4];
    const long row = blockIdx.x;
    const float* s = src + row * Nc;
    TO* d = dst + row * Nc;
    const int tid = threadIdx.x;

    float v[3];
    float m = -1e30f;
#pragma unroll
    for (int i = 0; i < 3; ++i) { v[i] = s[tid + i * 256]; m = fmaxf(m, v[i]); }

#pragma unroll
    for (int off = 32; off > 0; off >>= 1) m = fmaxf(m, __shfl_down(m, off, 64));
    if ((tid & 63) == 0) red[tid >> 6] = m;
    __syncthreads();
    if (tid == 0) {
        float mm = red[0];
        for (int w = 1; w < 4; ++w) mm = fmaxf(mm, red[w]);
        red[0] = mm;
    }
    __syncthreads();
    m = red[0];
    __syncthreads();

    float e[3];
    float sum = 0.f;
#pragma unroll
    for (int i = 0; i < 3; ++i) { e[i] = __expf(v[i] - m); sum += e[i]; }
#pragma unroll
    for (int off = 32; off > 0; off >>= 1) sum += __shfl_down(sum, off, 64);
    if ((tid & 63) == 0) red[tid >> 6] = sum;
    __syncthreads();
    if (tid == 0) red[0] = red[0] + red[1] + red[2] + red[3];
    __syncthreads();
    const float inv = 1.f / fmaxf(red[0], 1e-30f);
#pragma unroll
    for (int i = 0; i < 3; ++i) stf(d, tid + i * 256, e[i] * inv);
}

// ---------------------------------------------------------------------------
// Gate network + Smix — 2 elem/thread with PACKED fp32 math: the element-wise
// FMA chains are written as ext_vector_type(2) float ops so LLVM lowers them
// to v_pk_fma_f32/v_pk_mul_f32/v_pk_add_f32 (2 FMAs per issue slot on CDNA4).
// Round-9 counters showed pure issue-saturation (VALUBusy ~110%, mem 13%) —
// fewer slots is the only lever. Same per-element operations in the same
// order -> bit-identical results.
// ---------------------------------------------------------------------------
__global__ __launch_bounds__(256) void gates_smix(
    const float* __restrict__ S1g, const float* __restrict__ S2g,
    const bf16* __restrict__ Crg, const bf16* __restrict__ Clg,
    float* __restrict__ Smixg, const float* __restrict__ smallf)
{
    __shared__ float t1t[32][17], t2t[32][17];
    __shared__ float cs[192];

    const long mat = (long)blockIdx.z * Nc * Nc;
    const float* S1 = S1g + mat;
    const float* S2 = S2g + mat;
    const unsigned short* Cr = (const unsigned short*)Crg + mat;
    const unsigned short* Cl = (const unsigned short*)Clg + mat;
    float* Smix = Smixg + mat;

    const int tid = threadIdx.x;
    if (tid < 192) cs[tid] = smallf[tid];

    const int n0 = blockIdx.y * 16, m0 = blockIdx.x * 32;
    {   // transposed tiles: S[m0..m0+31][n0..n0+15], coalesced float2 loads
        const int r = tid >> 3, c2 = (tid & 7) * 2;
        const float2 a = *(const float2*)&S1[(long)(m0 + r) * Nc + n0 + c2];
        const float2 b = *(const float2*)&S2[(long)(m0 + r) * Nc + n0 + c2];
        t1t[r][c2] = a.x; t1t[r][c2 + 1] = a.y;
        t2t[r][c2] = b.x; t2t[r][c2 + 1] = b.y;
    }
    __syncthreads();

    const float* cw1 = cs;       const float* cb1 = cs + 96;
    const float* cw2 = cs + 112; const float* cb2 = cs + 176;

    const int tx = tid & 15, ty = tid >> 4;
    const int n = n0 + ty;
    const long idx = (long)n * Nc + m0 + tx * 2;

    const float2 s1v = *(const float2*)&S1[idx];
    const float2 s2v = *(const float2*)&S2[idx];
    const unsigned cru = *(const unsigned*)&Cr[idx];   // idx even -> 4B aligned
    const unsigned clu = *(const unsigned*)&Cl[idx];

    const f32x2 s1p = {s1v.x, s1v.y};
    const f32x2 s2p = {s2v.x, s2v.y};
    const f32x2 crp = {__uint_as_float((cru & 0xffffu) << 16),
                       __uint_as_float(cru & 0xffff0000u)};
    const f32x2 clp = {__uint_as_float((clu & 0xffffu) << 16),
                       __uint_as_float(clu & 0xffff0000u)};
    const f32x2 s1tp = {t1t[tx * 2][ty], t1t[tx * 2 + 1][ty]};
    const f32x2 s2tp = {t2t[tx * 2][ty], t2t[tx * 2 + 1][ty]};

    f32x2 g[4];
#pragma unroll
    for (int o = 0; o < 4; ++o) g[o] = (f32x2){cb2[o], cb2[o]};

#pragma unroll
    for (int u = 0; u < 16; ++u) {
        const float wf0 = cw1[u * 6 + 0], wf1 = cw1[u * 6 + 1], wf2 = cw1[u * 6 + 2];
        const float wf3 = cw1[u * 6 + 3], wf4 = cw1[u * 6 + 4], wf5 = cw1[u * 6 + 5];
        f32x2 h = {cb1[u], cb1[u]};
        h = h + s1p * wf0;          // contracts to v_pk_fma_f32
        h = h + s2p * wf1;
        h = h + s1tp * wf2;
        h = h + s2tp * wf3;
        h = h + crp * wf4;
        h = h + clp * wf5;
        // gelu_tanh(h) = h * sigmoid(2z), z2 = -2z pre-folded
        const f32x2 hh = h * h;
        const f32x2 z2 = h * (hh * -0.0713548162f + -1.5957691216f);
        const f32x2 e = {__expf(z2.x), __expf(z2.y)};
        const f32x2 rcp = {__fdividef(1.f, 1.f + e.x), __fdividef(1.f, 1.f + e.y)};
        const f32x2 hid = h * rcp;
#pragma unroll
        for (int o = 0; o < 4; ++o) g[o] = g[o] + hid * cw2[o * 16 + u];
    }

    float out[2];
#pragma unroll
    for (int j = 0; j < 2; ++j) {
        const float ga = sigf(g[0][j]);
        const float go = sigf(g[1][j]);
        const float gn = sigf(g[2][j]);
        const float gc = sigf(g[3][j]);
        const float s1 = s1p[j], s2 = s2p[j];
        const float mx = fmaxf(s1, s2);
        const float lae = mx + __logf(1.f + __expf(-fabsf(s1 - s2)));
        out[j] = s1 + ga * s2 + go * (lae - s1) - gn * (BETA_NOT * s2) + gc * crp[j];
    }
    *(float2*)&Smix[idx] = (float2){out[0], out[1]};
}

// ---------------------------------------------------------------------------
// Final projection via MFMA (validated rounds 7-9).
// ---------------------------------------------------------------------------
__global__ __launch_bounds__(256) void proj_mfma(
    const bf16* __restrict__ yc, const bf16* __restrict__ pwt,
    const void* __restrict__ xraw, void* __restrict__ out)
{
    constexpr int K = Dc;  // 512
    constexpr int N = Dc;  // 512
    __shared__ unsigned short Asm[128 * 32];
    __shared__ unsigned short Bsm[128 * 32];
    __shared__ int is32s;

    const int tid  = threadIdx.x;
    if (tid == 0) is32s = sniff_is_fp32(xraw);
    const int wv   = tid >> 6;
    const int lane = tid & 63;
    const int q    = lane >> 4;
    const int ln   = lane & 15;
    const int wm   = wv & 1;
    const int wn   = wv >> 1;

    const bf16* A  = yc  + (long)(blockIdx.y * 128) * K;
    const bf16* Bt = pwt + (long)(blockIdx.x * 128) * K;

    const int sr = lane >> 2, sc = lane & 3;
    const bf16* gA0 = A  + (long)(wv * 32 + sr)      * K + sc * 8;
    const bf16* gA1 = A  + (long)(wv * 32 + 16 + sr) * K + sc * 8;
    const bf16* gB0 = Bt + (long)(wv * 32 + sr)      * K + sc * 8;
    const bf16* gB1 = Bt + (long)(wv * 32 + 16 + sr) * K + sc * 8;
    unsigned short* lA0 = &Asm[(wv * 32)      * 32];
    unsigned short* lA1 = &Asm[(wv * 32 + 16) * 32];
    unsigned short* lB0 = &Bsm[(wv * 32)      * 32];
    unsigned short* lB1 = &Bsm[(wv * 32 + 16) * 32];

    f32x4 acc[4][4];
#pragma unroll
    for (int i = 0; i < 4; ++i)
#pragma unroll
        for (int j = 0; j < 4; ++j)
            acc[i][j] = (f32x4){0.f, 0.f, 0.f, 0.f};

    for (int k0 = 0; k0 < K; k0 += 32) {
        __syncthreads();
        gl_lds16(gA0 + k0, lA0);
        gl_lds16(gA1 + k0, lA1);
        gl_lds16(gB0 + k0, lB0);
        gl_lds16(gB1 + k0, lB1);
        __syncthreads();

        short8 af[4], bfr[4];
#pragma unroll
        for (int mt = 0; mt < 4; ++mt) {
            int m = wm * 64 + mt * 16 + ln;
            af[mt] = *(const short8*)&Asm[m * 32 + q * 8];
        }
#pragma unroll
        for (int nt = 0; nt < 4; ++nt) {
            int n = wn * 64 + nt * 16 + ln;
            bfr[nt] = *(const short8*)&Bsm[n * 32 + q * 8];
        }
#pragma unroll
        for (int mt = 0; mt < 4; ++mt)
#pragma unroll
            for (int nt = 0; nt < 4; ++nt)
                acc[mt][nt] = __builtin_amdgcn_mfma_f32_16x16x32_bf16(
                    af[mt], bfr[nt], acc[mt][nt], 0, 0, 0);
    }

    const int is32 = is32s;
#pragma unroll
    for (int mt = 0; mt < 4; ++mt) {
#pragma unroll
        for (int nt = 0; nt < 4; ++nt) {
            const int col = blockIdx.x * 128 + wn * 64 + nt * 16 + ln;
            const int rowb = blockIdx.y * 128 + wm * 64 + mt * 16 + q * 4;
#pragma unroll
            for (int r = 0; r < 4; ++r) {
                const long o = (long)(rowb + r) * N + col;
                if (is32) ((float*)out)[o] = acc[mt][nt][r];
                else      ((bf16*)out)[o] = __float2bfloat16(acc[mt][nt][r]);
            }
        }
    }
}

// ---------------------------------------------------------------------------
extern "C" void kernel_launch(void* const* d_in, const int* in_sizes, int n_in,
                              void* d_out, int out_size, void* d_ws, size_t ws_size,
                              hipStream_t stream)
{
    const size_t HD   = (size_t)BHc * Nc * DKc;   // 786432
    const size_t HDh  = HD / 2;                   // float-slots for HD bf16
    const size_t MAT  = (size_t)Nc * Nc;          // 589824
    const size_t MATS = (size_t)BHc * MAT;        // 9437184
    const long   HSTR = (long)Nc * DKc;           // 49152 per-head stride

    float* ws = (float*)d_ws;
    size_t off = 0;
    auto alloc = [&](size_t n) { float* p = ws + off; off += n; return p; };

    bf16* xb  = (bf16*)alloc(HDh);
    bf16* w1b = (bf16*)alloc(HDh);   // w1b/w2b adjacent -> merged transpose
    bf16* w2b = (bf16*)alloc(HDh);
    bf16* w1t = (bf16*)alloc(HDh);
    bf16* w2t = (bf16*)alloc(HDh);
    bf16* pwb = (bf16*)alloc((size_t)Dc * Dc / 2);
    bf16* pwt = (bf16*)alloc((size_t)Dc * Dc / 2);
    float* smallf = alloc(192);
    // q1|q2 and k1|k2 adjacent -> single merged S-GEMM launch (32 heads)
    bf16* q1b = (bf16*)alloc(HDh); bf16* q2b = (bf16*)alloc(HDh);
    bf16* k1b = (bf16*)alloc(HDh); bf16* k2b = (bf16*)alloc(HDh);
    bf16* v1b = (bf16*)alloc(HDh); bf16* v2b = (bf16*)alloc(HDh);  // adjacent
    bf16* v1t = (bf16*)alloc(HDh); bf16* v2t = (bf16*)alloc(HDh);  // adjacent
    bf16* trb = (bf16*)alloc(HDh);
    bf16* trt = (bf16*)alloc(HDh);
    float* S1   = alloc(MATS);       // S1/S2 adjacent -> merged softmax + S-GEMM
    float* S2   = alloc(MATS);
    float* Smix = alloc(MATS);
    bf16* A1b = (bf16*)alloc(MATS / 2);  // A1b/A2b adjacent
    bf16* A2b = (bf16*)alloc(MATS / 2);
    bf16* Crb = (bf16*)alloc(MATS / 2);  // Crb/Clb adjacent (merged launch)
    bf16* Clb = (bf16*)alloc(MATS / 2);
    bf16* yb1 = (bf16*)alloc(HDh);
    bf16* yc  = (bf16*)alloc(HDh);

    // aliases into dead regions
    bf16* A1tb = (bf16*)Smix;            // dead until gates writes Smix
    bf16* A2tb = ((bf16*)Smix) + MATS;   // A1tb/A2tb adjacent
    bf16* Ab   = (bf16*)S1;              // S1 dead after gates

    const size_t NEED_BYTES = off * sizeof(float);
    if (ws_size < NEED_BYTES) {
        fill_sentinel<<<dim3(3072), 256, 0, stream>>>((unsigned short*)d_out);
        return;
    }

    // 0. normalize inputs
    convert_all<<<dim3(3072), 256, 0, stream>>>(
        d_in[0], d_in[1], d_in[2], d_in[3], d_in[4], d_in[5], d_in[6], d_in[7],
        d_in[8], xb, w1b, w2b, pwb, smallf);

    // 1. merged W transposes; pw transpose; merged QKV; merged v transposes
    transpose_bf16<<<dim3(24, 8, 2), 256, 0, stream>>>(
        (const unsigned short*)w1b, (unsigned short*)w1t, Dc, 3 * Dc, (long)HD, (long)HD);
    transpose_bf16<<<dim3(8, 8, 1), 256, 0, stream>>>(
        (const unsigned short*)pwb, (unsigned short*)pwt, Dc, Dc, 0, 0);
    qkv_mfma<<<dim3(12, 12, 2), 256, 0, stream>>>(
        xb, w1t, w2t, q1b, k1b, v1b, q2b, k2b, v2b);
    transpose_bf16<<<dim3(1, 12, 2 * BHc), 256, 0, stream>>>(
        (const unsigned short*)v1b, (unsigned short*)v1t, Nc, DKc, HSTR, HSTR);

    // 2. S = scale * q @ k^T — single 32-batch launch
    gemm_nt_mfma<0, float><<<dim3(6, 6, 2 * BHc), 256, 0, stream>>>(
        q1b, k1b, S1, Nc, Nc, DKc, HSTR, HSTR, (long)MAT, SCALE);

    // 3. merged softmax S1|S2 -> A1b|A2b; merged transposes -> A1tb|A2tb
    softmax_rows<bf16><<<2 * BHc * Nc, 256, 0, stream>>>(S1, A1b);
    transpose_bf16<<<dim3(12, 12, 2 * BHc), 256, 0, stream>>>(
        (const unsigned short*)A1b, (unsigned short*)A1tb, Nc, Nc, (long)MAT, (long)MAT);

    // 4. Cr|Cl in ONE 32-batch launch (Bt batch = z^16; C regions adjacent)
    gemm_nt_mfma<1, bf16, 1><<<dim3(6, 6, 2 * BHc), 256, 0, stream>>>(
        A1b, A1tb, Crb, Nc, Nc, Nc, (long)MAT, (long)MAT, (long)MAT, 1.f);

    // 5. gates + Smix (2 elem/thread, packed fp32)
    gates_smix<<<dim3(24, 48, BHc), 256, 0, stream>>>(S1, S2, Crb, Clb, Smix, smallf);

    // 6. A = softmax(Smix) -> bf16 (into S1 alias)
    softmax_rows<bf16><<<BHc * Nc, 256, 0, stream>>>(Smix, Ab);

    // 7. merged: transport = A2 @ v2 (z<16) | y_base = A @ v1 (z>=16)
    gemm_n64_pair<<<dim3(1, 6, 2 * BHc), 256, 0, stream>>>(
        A2b, v2t, trb, Ab, v1t, yb1, Nc, Nc, (long)MAT, HSTR, HSTR);
    transpose_bf16<<<dim3(1, 12, BHc), 256, 0, stream>>>(
        (const unsigned short*)trb, (unsigned short*)trt, Nc, DKc, HSTR, HSTR);

    // 8. y_chain GEMM with fused combine + permute -> yc
    gemm_n64_combine<<<dim3(1, 6, BHc), 256, 0, stream>>>(
        A1b, trt, yb1, smallf, yc, Nc, Nc, (long)MAT, HSTR);

    // 9. proj via MFMA + dtype-aware store
    proj_mfma<<<dim3(4, 12, 1), 256, 0, stream>>>(yc, pwt, d_in[0], d_out);
}